// Round 9
// baseline (2237.003 us; speedup 1.0000x reference)
//
#include <hip/hip_runtime.h>
#include <hip/hip_bf16.h>

typedef __bf16 bf16;
typedef __bf16 bf16x8 __attribute__((ext_vector_type(8)));
typedef float floatx4 __attribute__((ext_vector_type(4)));
typedef float floatx16 __attribute__((ext_vector_type(16)));

#define MFMA_BF16(a, b, c) __builtin_amdgcn_mfma_f32_16x16x32_bf16((a), (b), (c), 0, 0, 0)
#define MFMA32(a, b, c) __builtin_amdgcn_mfma_f32_32x32x16_bf16((a), (b), (c), 0, 0, 0)

static constexpr int CH = 256;      // channels
static constexpr int NPIX = 9216;   // 96*96
static constexpr int MTOT = 2 * NPIX; // both batches, n-major rows
static constexpr int NQB3 = 72;     // 256-row attention q-blocks total (2 batches)

// async global->LDS, 16B per lane; LDS dest = wave-uniform base + lane*16
__device__ __forceinline__ void async16(void* lds, const void* g) {
  __builtin_amdgcn_global_load_lds(
      (const __attribute__((address_space(1))) void*)g,
      (__attribute__((address_space(3))) void*)lds, 16, 0, 0);
}

// pack two f32 -> one u32 of 2 bf16 (lo = first arg)
__device__ __forceinline__ unsigned cvtpk(float lo, float hi) {
  unsigned r;
  asm("v_cvt_pk_bf16_f32 %0, %1, %2" : "=v"(r) : "v"(lo), "v"(hi));
  return r;
}

// v_permlane32_swap_b32 a, b  (VALU, gfx950):
//   a'[0:31]=a[0:31], a'[32:63]=b[0:31]; b'[0:31]=a[32:63], b'[32:63]=b[32:63]
__device__ __forceinline__ void plswap(unsigned& a, unsigned& b) {
  asm volatile("v_permlane32_swap_b32 %0, %1" : "+v"(a), "+v"(b));
}
// max/sum with lane^32 partner via permlane (replaces ds_bpermute shfl_xor)
__device__ __forceinline__ float xmax32(float v) {
  unsigned a = __builtin_bit_cast(unsigned, v), b = a;
  plswap(a, b);
  return fmaxf(__builtin_bit_cast(float, a), __builtin_bit_cast(float, b));
}
__device__ __forceinline__ float xsum32(float v) {
  unsigned a = __builtin_bit_cast(unsigned, v), b = a;
  plswap(a, b);
  return __builtin_bit_cast(float, a) + __builtin_bit_cast(float, b);
}

// ---------------------------------------------------------------------------
// Weight split (fp32 -> bf16 hi/lo) + folded BN scale/bias
// ---------------------------------------------------------------------------
__global__ void prep_weights(const float* __restrict__ W,
                             const float* __restrict__ g, const float* __restrict__ b,
                             const float* __restrict__ m, const float* __restrict__ v,
                             bf16* __restrict__ Wh, bf16* __restrict__ Wl,
                             float* __restrict__ scale, float* __restrict__ bias) {
  int i = blockIdx.x * 256 + threadIdx.x;
  if (i < 6 * CH * CH) {
    float w = W[i];
    bf16 h = (bf16)w;
    Wh[i] = h;
    Wl[i] = (bf16)(w - (float)h);
  }
  if (i < 6 * CH) {
    float s = g[i] * rsqrtf(v[i] + 1e-5f);
    scale[i] = s;
    bias[i] = b[i] - m[i] * s;
  }
}

// ---------------------------------------------------------------------------
// Both inputs: fp32 [B][256][9216] (c-major) -> bf16 hi/lo [B*9216][256]
// bid < 1152 -> x, else fk
// ---------------------------------------------------------------------------
__global__ void split_transpose2(const float* __restrict__ xin, const float* __restrict__ fkin,
                                 bf16* __restrict__ ohx, bf16* __restrict__ olx,
                                 bf16* __restrict__ ohf, bf16* __restrict__ olf) {
  __shared__ float t[64][65];
  int bid = blockIdx.x;
  const float* in; bf16 *oh, *ol;
  if (bid >= 1152) { in = fkin; oh = ohf; ol = olf; bid -= 1152; }
  else             { in = xin;  oh = ohx; ol = olx; }
  int b = bid / 576, rem = bid % 576;
  int ct = rem / 144, nt = rem % 144;
  int c0 = ct * 64, n0 = nt * 64;
  int tid = threadIdx.x;
  int cr = tid >> 4, nc = (tid & 15) * 4;
  for (int rr = 0; rr < 64; rr += 16) {
    int c = cr + rr;
    const float* p = in + ((size_t)(b * CH + c0 + c) * NPIX) + n0 + nc;
    float4 val = *(const float4*)p;
    t[c][nc + 0] = val.x; t[c][nc + 1] = val.y;
    t[c][nc + 2] = val.z; t[c][nc + 3] = val.w;
  }
  __syncthreads();
  int n = tid >> 2, cb = (tid & 3) * 16;
  bf16 hb[16], lb[16];
#pragma unroll
  for (int j = 0; j < 16; j++) {
    float xv = t[cb + j][n];
    bf16 h = (bf16)xv;
    hb[j] = h;
    lb[j] = (bf16)(xv - (float)h);
  }
  size_t idx = (size_t)(b * NPIX + n0 + n) * CH + c0 + cb;
  *(bf16x8*)&oh[idx]     = *(bf16x8*)&hb[0];
  *(bf16x8*)&oh[idx + 8] = *(bf16x8*)&hb[8];
  *(bf16x8*)&ol[idx]     = *(bf16x8*)&lb[0];
  *(bf16x8*)&ol[idx + 8] = *(bf16x8*)&lb[8];
}

// ---------------------------------------------------------------------------
// bf16 [B*9216][256] (n-major) -> bf16 [B][256][9216] (c-major)   (for V)
// ---------------------------------------------------------------------------
__global__ void transpose_bf16(const bf16* __restrict__ in, bf16* __restrict__ out) {
  __shared__ bf16 t[64][72];
  int bid = blockIdx.x;
  int b = bid / 576, rem = bid % 576;
  int ct = rem / 144, nt = rem % 144;
  int c0 = ct * 64, n0 = nt * 64;
  int tid = threadIdx.x;
  int nr = tid >> 4, cc = (tid & 15) * 4;
  for (int rr = 0; rr < 64; rr += 16) {
    int n = nr + rr;
    const bf16* p = in + (size_t)(b * NPIX + n0 + n) * CH + c0 + cc;
#pragma unroll
    for (int j = 0; j < 4; j++) t[cc + j][n] = p[j];
  }
  __syncthreads();
  int c = tid >> 2, nb = (tid & 3) * 16;
  bf16 buf[16];
#pragma unroll
  for (int j = 0; j < 16; j++) buf[j] = t[c][nb + j];
  size_t idx = (size_t)(b * CH + c0 + c) * NPIX + n0 + nb;
  *(bf16x8*)&out[idx]     = *(bf16x8*)&buf[0];
  *(bf16x8*)&out[idx + 8] = *(bf16x8*)&buf[8];
}

// ---------------------------------------------------------------------------
// fp32 [B*9216][256] (n-major) -> fp32 [B][256][9216]   (final output)
// ---------------------------------------------------------------------------
__global__ void transpose_out(const float* __restrict__ in, float* __restrict__ out) {
  __shared__ float t[64][65];
  int bid = blockIdx.x;
  int b = bid / 576, rem = bid % 576;
  int ct = rem / 144, nt = rem % 144;
  int c0 = ct * 64, n0 = nt * 64;
  int tid = threadIdx.x;
  int nr = tid >> 4, cc = (tid & 15) * 4;
  for (int rr = 0; rr < 64; rr += 16) {
    int n = nr + rr;
    float4 v = *(const float4*)&in[(size_t)(b * NPIX + n0 + n) * CH + c0 + cc];
    t[cc + 0][n] = v.x; t[cc + 1][n] = v.y; t[cc + 2][n] = v.z; t[cc + 3][n] = v.w;
  }
  __syncthreads();
  int c = tid >> 2, nb = (tid & 3) * 16;
#pragma unroll
  for (int k = 0; k < 4; k++) {
    float4 o4 = make_float4(t[c][nb + 4 * k + 0], t[c][nb + 4 * k + 1],
                            t[c][nb + 4 * k + 2], t[c][nb + 4 * k + 3]);
    *(float4*)&out[(size_t)(b * CH + c0 + c) * NPIX + n0 + nb + 4 * k] = o4;
  }
}

// ---------------------------------------------------------------------------
// Batched split-bf16 conv-GEMM, 128x128 tiles (288 blocks per job).
// mode: 0 = write hi+lo bf16, 1 = hi only, 2 = fp32
// ---------------------------------------------------------------------------
struct ConvJob {
  const bf16 *Ah, *Al, *Bh, *Bl;
  const float *scale, *bias;
  bf16 *Yh, *Yl; float *Yf;
  int mode;
};

__global__ __launch_bounds__(256, 3) void conv128(ConvJob j0, ConvJob j1, ConvJob j2) {
  __shared__ bf16 lds[4][8 * 512];  // planes: Ah, Al, Bh, Bl
  int jid = blockIdx.x / 288;
  int bid = blockIdx.x % 288;
  ConvJob j = (jid == 0) ? j0 : (jid == 1) ? j1 : j2;

  int tid = threadIdx.x;
  int w = tid >> 6, l = tid & 63;
  int q = l >> 4, c16 = l & 15;
  int m0 = (bid >> 1) * 128;
  int o0 = (bid & 1) * 128;

  const bf16* src = (w == 0) ? j.Ah : (w == 1) ? j.Al : (w == 2) ? j.Bh : j.Bl;
  int rowbase = (w < 2) ? m0 : o0;
  const bf16* gp = src + (size_t)(rowbase + c16) * CH + q * 8;
  bf16* ldst = &lds[w][0];

  const floatx4 zero4 = {0.f, 0.f, 0.f, 0.f};
  floatx4 acc[4][4];
#pragma unroll
  for (int i = 0; i < 4; i++)
#pragma unroll
    for (int jj = 0; jj < 4; jj++) acc[i][jj] = zero4;

  int mo16 = (w & 1) * 4, no16 = (w >> 1) * 4;

  for (int k0 = 0; k0 < CH; k0 += 32) {
#pragma unroll
    for (int f = 0; f < 8; f++)
      async16(ldst + f * 512, gp + (size_t)f * 16 * CH + k0);
    __syncthreads();

    bf16x8 ah[4], al[4], bh[4], bl[4];
#pragma unroll
    for (int i = 0; i < 4; i++) {
      ah[i] = *(const bf16x8*)&lds[0][(mo16 + i) * 512 + l * 8];
      al[i] = *(const bf16x8*)&lds[1][(mo16 + i) * 512 + l * 8];
      bh[i] = *(const bf16x8*)&lds[2][(no16 + i) * 512 + l * 8];
      bl[i] = *(const bf16x8*)&lds[3][(no16 + i) * 512 + l * 8];
    }
#pragma unroll
    for (int i = 0; i < 4; i++)
#pragma unroll
      for (int jj = 0; jj < 4; jj++) {
        acc[i][jj] = MFMA_BF16(ah[i], bh[jj], acc[i][jj]);
        acc[i][jj] = MFMA_BF16(ah[i], bl[jj], acc[i][jj]);
        acc[i][jj] = MFMA_BF16(al[i], bh[jj], acc[i][jj]);
      }
    __syncthreads();
  }

  int mo = (w & 1) * 64, no = (w >> 1) * 64;
  float sc[4], bs[4];
#pragma unroll
  for (int jj = 0; jj < 4; jj++) {
    int o = o0 + no + 16 * jj + c16;
    sc[jj] = j.scale[o];
    bs[jj] = j.bias[o];
  }
#pragma unroll
  for (int i = 0; i < 4; i++) {
    int nrow = m0 + mo + 16 * i + 4 * q;
#pragma unroll
    for (int jj = 0; jj < 4; jj++) {
      int o = o0 + no + 16 * jj + c16;
#pragma unroll
      for (int r = 0; r < 4; r++) {
        float y = acc[i][jj][r] * sc[jj] + bs[jj];
        y = fmaxf(y, 0.f);
        size_t idx = (size_t)(nrow + r) * CH + o;
        if (j.mode == 2) {
          j.Yf[idx] = y;
        } else if (j.mode == 1) {
          j.Yh[idx] = (bf16)y;
        } else {
          bf16 h = (bf16)y;
          j.Yh[idx] = h;
          j.Yl[idx] = (bf16)(y - (float)h);
        }
      }
    }
  }
}

// ---------------------------------------------------------------------------
// 64x128-tile split-bf16 conv-GEMM, fp32 out (f_up). Grid 576, LDS 24 KB.
// ---------------------------------------------------------------------------
__global__ __launch_bounds__(256, 4) void conv64(
    const bf16* __restrict__ Ah, const bf16* __restrict__ Al,
    const bf16* __restrict__ Bh, const bf16* __restrict__ Bl,
    const float* __restrict__ scale, const float* __restrict__ bias,
    float* __restrict__ Yf) {
  __shared__ bf16 lds[24 * 512];  // flat frags: [Ah0-3, Al0-3, Bh0-7, Bl0-7]
  int tid = threadIdx.x;
  int w = tid >> 6, l = tid & 63;
  int q = l >> 4, c16 = l & 15;
  int m0 = (blockIdx.x >> 1) * 64;
  int o0 = (blockIdx.x & 1) * 128;

  const floatx4 zero4 = {0.f, 0.f, 0.f, 0.f};
  floatx4 acc[4][2];
#pragma unroll
  for (int i = 0; i < 4; i++) { acc[i][0] = zero4; acc[i][1] = zero4; }

  for (int k0 = 0; k0 < CH; k0 += 32) {
#pragma unroll
    for (int ff = 0; ff < 6; ff++) {
      int f = w * 6 + ff;
      const bf16* src; int rbase, fl;
      if (f < 4)       { src = Ah; rbase = m0; fl = f; }
      else if (f < 8)  { src = Al; rbase = m0; fl = f - 4; }
      else if (f < 16) { src = Bh; rbase = o0; fl = f - 8; }
      else             { src = Bl; rbase = o0; fl = f - 16; }
      async16(&lds[f * 512], src + (size_t)(rbase + fl * 16 + c16) * CH + k0 + q * 8);
    }
    __syncthreads();

    bf16x8 ah[4], al[4], bh[2], bl[2];
#pragma unroll
    for (int i = 0; i < 4; i++) {
      ah[i] = *(const bf16x8*)&lds[(0 + i) * 512 + l * 8];
      al[i] = *(const bf16x8*)&lds[(4 + i) * 512 + l * 8];
    }
#pragma unroll
    for (int n = 0; n < 2; n++) {
      bh[n] = *(const bf16x8*)&lds[(8 + 2 * w + n) * 512 + l * 8];
      bl[n] = *(const bf16x8*)&lds[(16 + 2 * w + n) * 512 + l * 8];
    }
#pragma unroll
    for (int i = 0; i < 4; i++)
#pragma unroll
      for (int n = 0; n < 2; n++) {
        acc[i][n] = MFMA_BF16(ah[i], bh[n], acc[i][n]);
        acc[i][n] = MFMA_BF16(ah[i], bl[n], acc[i][n]);
        acc[i][n] = MFMA_BF16(al[i], bh[n], acc[i][n]);
      }
    __syncthreads();
  }

  float sc[2], bs[2];
#pragma unroll
  for (int n = 0; n < 2; n++) {
    int o = o0 + 32 * w + 16 * n + c16;
    sc[n] = scale[o];
    bs[n] = bias[o];
  }
#pragma unroll
  for (int i = 0; i < 4; i++) {
    int nrow = m0 + 16 * i + 4 * q;
#pragma unroll
    for (int n = 0; n < 2; n++) {
      int o = o0 + 32 * w + 16 * n + c16;
#pragma unroll
      for (int r = 0; r < 4; r++) {
        float y = acc[i][n][r] * sc[n] + bs[n];
        Yf[(size_t)(nrow + r) * CH + o] = fmaxf(y, 0.f);
      }
    }
  }
}

// ---------------------------------------------------------------------------
// Split-KV flash attention partial, v5. BQ=256 (4 waves x 64 q-rows), BKV=32.
//
// v3 post-mortem: LDS-read-throughput bound -- 8 waves/CU each re-read the
// whole K+V tile (256 KB/CU/iter @ ~85 B/cyc ~= the measured iter time).
// v4 post-mortem: pipeline carry spilled (FETCH/WRITE +28 MB) -> discarded.
// v5: halve LDS bytes per MFMA instead of overlapping:
//  * 2 q-subtiles (2x32 rows) per wave: every K-frag and V-frag ds_read_b128
//    feeds 2 MFMAs (32 reads / 64 MFMAs per wave-iter).
//  * register budget: qf 128 + oacc 256 + 4 QK accs 64 ~= 470 -> needs
//    512 VGPR/wave = 1 wave/SIMD: __launch_bounds__(256,1), 1 block/CU.
//  * fixed softmax cross-lane ops via v_permlane32_swap_b32 (VALU, ~4cy)
//    instead of ds_bpermute (~120cy + LDS pipe): xor32 max/sum reduces and
//    the P-pack half-exchange (1 swap fills 2 frag words).
//  * no sw pipeline, no setprio (1 wave/SIMD: nothing to arbitrate).
// LDS: K dbuf 32K + V dbuf 32K = 64 KB. Grid 72*S (S=3 -> 216), niter=96.
// ---------------------------------------------------------------------------
__global__ __launch_bounds__(256, 1) void attn_part(
    const bf16* __restrict__ Q, const bf16* __restrict__ K, const bf16* __restrict__ Vt,
    float* __restrict__ Opart, float* __restrict__ Mpart, float* __restrict__ Lpart,
    int niter) {
  __shared__ bf16 lK[2][16 * 512];  // frag ks: K[key=l&31][16ks+8hi+i]
  __shared__ bf16 lV[2][16 * 512];  // frag 2c8+half: V[ch=32c8+(l&31)][16half+8hi+i]

  int tid = threadIdx.x;
  int w = tid >> 6, l = tid & 63;
  int ql = l & 31, hi = l >> 5;
  int bid = blockIdx.x;
  int qb = bid % NQB3, s = bid / NQB3;
  int b = qb / 36;
  int n0 = (qb % 36) * 256;
  int kv0 = s * niter * 32;
  size_t qkbase = (size_t)b * NPIX * CH;
  size_t vbase  = (size_t)b * CH * NPIX;

  // Q fragments (B-operand 32x32x16), 2 q-subtiles: rows n0+64w+32qt+ql
  bf16x8 qf[2][16];
#pragma unroll
  for (int qt = 0; qt < 2; qt++) {
    const bf16* qp = Q + qkbase + (size_t)(n0 + 64 * w + 32 * qt + ql) * CH + 8 * hi;
#pragma unroll
    for (int ks = 0; ks < 16; ks++) qf[qt][ks] = *(const bf16x8*)(qp + ks * 16);
  }

  floatx16 oacc[2][8];  // [qt][c8]: O[q=(r&3)+8(r>>2)+4hi][ch=32c8+ql]
#pragma unroll
  for (int qt = 0; qt < 2; qt++)
#pragma unroll
    for (int c8 = 0; c8 < 8; c8++)
#pragma unroll
      for (int r = 0; r < 16; r++) oacc[qt][c8][r] = 0.f;
  float mrow[2] = {-1e30f, -1e30f};  // per-lane q-row = 32qt + ql (dup in hi)
  float lrow[2] = {0.f, 0.f};

  const bf16* gK = K + qkbase + (size_t)kv0 * CH;
  const bf16* gV = Vt + vbase + kv0;

  // wave w stages K frags 4w..4w+3 and V frags 4w..4w+3 (8 async16/iter)
  auto stage = [&](int bi) {
#pragma unroll
    for (int ff = 0; ff < 4; ff++) {
      int f = 4 * w + ff;
      async16(&lK[bi][f * 512], gK + (size_t)ql * CH + f * 16 + 8 * hi);
      async16(&lV[bi][f * 512],
              gV + (size_t)((f >> 1) * 32 + ql) * NPIX + (f & 1) * 16 + 8 * hi);
    }
  };

  stage(0);

  for (int it = 0; it < niter; it++) {
    int cur = it & 1;
    __syncthreads();  // buffers `cur` ready; prev iter's reads retired

    if (it + 1 < niter) {
      gK += 32 * CH; gV += 32;
      stage(cur ^ 1);
    }

    // S^T = K Q^T for both q-subtiles; each kf read feeds 2 MFMAs.
    floatx16 s0A, s0B, s1A, s1B;
#pragma unroll
    for (int r = 0; r < 16; r++) { s0A[r] = 0.f; s0B[r] = 0.f; s1A[r] = 0.f; s1B[r] = 0.f; }
#pragma unroll
    for (int ks = 0; ks < 16; ks += 2) {
      bf16x8 kf0 = *(const bf16x8*)&lK[cur][(ks + 0) * 512 + l * 8];
      bf16x8 kf1 = *(const bf16x8*)&lK[cur][(ks + 1) * 512 + l * 8];
      s0A = MFMA32(kf0, qf[0][ks + 0], s0A);
      s0B = MFMA32(kf1, qf[0][ks + 1], s0B);
      s1A = MFMA32(kf0, qf[1][ks + 0], s1A);
      s1B = MFMA32(kf1, qf[1][ks + 1], s1B);
    }
    // combine chains; s0A/s1A hold S for tile 0/1 (col=q-row=ql, reg=key)
#pragma unroll
    for (int r = 0; r < 16; r++) { s0A[r] += s0B[r]; s1A[r] += s1B[r]; }

    // tile max per q-row (in-lane 16 + permlane partner max)
    float pm[2];
#pragma unroll
    for (int qt = 0; qt < 2; qt++) {
      floatx16& sf = qt ? s1A : s0A;
      float v2 = fmaxf(fmaxf(fmaxf(sf[0], sf[1]), fmaxf(sf[2], sf[3])),
                       fmaxf(fmaxf(sf[4], sf[5]), fmaxf(sf[6], sf[7])));
      float v3 = fmaxf(fmaxf(fmaxf(sf[8], sf[9]), fmaxf(sf[10], sf[11])),
                       fmaxf(fmaxf(sf[12], sf[13]), fmaxf(sf[14], sf[15])));
      pm[qt] = xmax32(fmaxf(v2, v3));
    }

    // defer-max: rescale only when some row's max grew by > 8
    bool need = (pm[0] > mrow[0] + 8.f) | (pm[1] > mrow[1] + 8.f);
    if (__ballot((int)need) != 0ull) {
#pragma unroll
      for (int qt = 0; qt < 2; qt++) {
        float mn = fmaxf(mrow[qt], pm[qt]);
        float alpha = __expf(mrow[qt] - mn);
        mrow[qt] = mn;
        lrow[qt] *= alpha;
        float arow[16];
#pragma unroll
        for (int r = 0; r < 16; r++)
          arow[r] = __shfl(alpha, (r & 3) + 8 * (r >> 2) + 4 * hi);
#pragma unroll
        for (int c8 = 0; c8 < 8; c8++)
#pragma unroll
          for (int r = 0; r < 16; r++) oacc[qt][c8][r] *= arow[r];
      }
    }

    // P = exp(S - m) -> packed PV A-frags (1 permlane swap fills 2 words)
    bf16x8 pa[2][2];
#pragma unroll
    for (int qt = 0; qt < 2; qt++) {
      floatx16& sf = qt ? s1A : s0A;
      float p[16];
      float rs = 0.f;
#pragma unroll
      for (int r = 0; r < 16; r++) {
        p[r] = __expf(sf[r] - mrow[qt]);
        rs += p[r];
      }
      lrow[qt] += xsum32(rs);

      unsigned pk0 = cvtpk(p[0], p[1]),   pk1 = cvtpk(p[2], p[3]);
      unsigned pk2 = cvtpk(p[4], p[5]),   pk3 = cvtpk(p[6], p[7]);
      unsigned pk4 = cvtpk(p[8], p[9]),   pk5 = cvtpk(p[10], p[11]);
      unsigned pk6 = cvtpk(p[12], p[13]), pk7 = cvtpk(p[14], p[15]);
      plswap(pk0, pk2); plswap(pk1, pk3);
      plswap(pk4, pk6); plswap(pk5, pk7);
      uint4 u0, u1;
      u0.x = pk0; u0.y = pk1; u0.z = pk2; u0.w = pk3;  // keys 0..15, k=8hi+i
      u1.x = pk4; u1.y = pk5; u1.z = pk6; u1.w = pk7;  // keys 16..31
      pa[qt][0] = __builtin_bit_cast(bf16x8, u0);
      pa[qt][1] = __builtin_bit_cast(bf16x8, u1);
    }

    // PV: O[q][ch] += P[q][k] V[k][ch]; each vb read feeds 2 MFMAs
#pragma unroll
    for (int c8 = 0; c8 < 8; c8++) {
      bf16x8 vb0 = *(const bf16x8*)&lV[cur][(2 * c8 + 0) * 512 + l * 8];
      bf16x8 vb1 = *(const bf16x8*)&lV[cur][(2 * c8 + 1) * 512 + l * 8];
      oacc[0][c8] = MFMA32(pa[0][0], vb0, oacc[0][c8]);
      oacc[0][c8] = MFMA32(pa[0][1], vb1, oacc[0][c8]);
      oacc[1][c8] = MFMA32(pa[1][0], vb0, oacc[1][c8]);
      oacc[1][c8] = MFMA32(pa[1][1], vb1, oacc[1][c8]);
    }
  }

  // write partials (unnormalized O + m, l)
  if (hi == 0) {
#pragma unroll
    for (int qt = 0; qt < 2; qt++) {
      int row = 64 * w + 32 * qt + ql;
      Mpart[(size_t)bid * 256 + row] = mrow[qt];
      Lpart[(size_t)bid * 256 + row] = lrow[qt];
    }
  }
  float* Ob = Opart + (size_t)bid * 256 * CH;
#pragma unroll
  for (int qt = 0; qt < 2; qt++)
#pragma unroll
    for (int c8 = 0; c8 < 8; c8++)
#pragma unroll
      for (int r = 0; r < 16; r++) {
        int row = 64 * w + 32 * qt + (r & 3) + 8 * (r >> 2) + 4 * hi;
        Ob[(size_t)row * CH + 32 * c8 + ql] = oacc[qt][c8][r];
      }
}

// ---------------------------------------------------------------------------
// Combine S partials -> normalized O, split hi/lo bf16, n-major [MTOT][256]
// grid = NQB3*4 (72 q-blocks x 4 row-quarters of 64 rows), 256 threads
// ---------------------------------------------------------------------------
__global__ __launch_bounds__(256) void attn_combine(
    const float* __restrict__ Opart, const float* __restrict__ Mpart,
    const float* __restrict__ Lpart,
    bf16* __restrict__ Oh, bf16* __restrict__ Ol, int S) {
  __shared__ float wgt[8][64];
  __shared__ float invl[64];
  int qb = blockIdx.x >> 2;
  int r0 = (blockIdx.x & 3) * 64;
  int t = threadIdx.x;
  if (t < 64) {
    int row = r0 + t;
    float m = -1e30f;
    for (int s = 0; s < S; s++)
      m = fmaxf(m, Mpart[(size_t)(s * NQB3 + qb) * 256 + row]);
    float lsum = 0.f;
    for (int s = 0; s < S; s++) {
      float wv = __expf(Mpart[(size_t)(s * NQB3 + qb) * 256 + row] - m);
      wgt[s][t] = wv;
      lsum += wv * Lpart[(size_t)(s * NQB3 + qb) * 256 + row];
    }
    invl[t] = 1.0f / lsum;
  }
  __syncthreads();
  int c = t;  // 256 threads = 256 channels
  for (int rr = 0; rr < 64; rr++) {
    int row = r0 + rr;
    float acc = 0.f;
    for (int s = 0; s < S; s++)
      acc += wgt[s][rr] * Opart[((size_t)(s * NQB3 + qb) * 256 + row) * CH + c];
    float y = acc * invl[rr];
    size_t idx = (size_t)(qb * 256 + row) * CH + c;
    bf16 h = (bf16)y;
    Oh[idx] = h;
    Ol[idx] = (bf16)(y - (float)h);
  }
}

// ---------------------------------------------------------------------------
extern "C" void kernel_launch(void* const* d_in, const int* in_sizes, int n_in,
                              void* d_out, int out_size, void* d_ws, size_t ws_size,
                              hipStream_t stream) {
  const float* x  = (const float*)d_in[0];
  const float* fk = (const float*)d_in[1];
  const float* Ws = (const float*)d_in[2];
  const float* g  = (const float*)d_in[3];
  const float* be = (const float*)d_in[4];
  const float* me = (const float*)d_in[5];
  const float* va = (const float*)d_in[6];
  float* out = (float*)d_out;

  char* p = (char*)d_ws;
  bf16* Wh = (bf16*)p; p += (size_t)6 * CH * CH * 2;
  bf16* Wl = (bf16*)p; p += (size_t)6 * CH * CH * 2;
  float* scale = (float*)p; p += (size_t)6 * CH * 4;
  float* bias  = (float*)p; p += (size_t)6 * CH * 4;
  size_t plane = (size_t)MTOT * CH * 2;  // 9,437,184 B per bf16 plane
  bf16* S0h = (bf16*)p; p += plane;
  bf16* S0l = (bf16*)p; p += plane;
  bf16* Qh  = (bf16*)p; p += plane;
  bf16* Kh  = (bf16*)p; p += plane;
  bf16* Vh  = (bf16*)p; p += plane;
  bf16* Vt  = (bf16*)p; p += plane;
  char* region = p;

  // Overlays inside `region` (all dead before attn_part writes Opart there):
  bf16* S2h = (bf16*)(region);              // fk transposed (hi)
  bf16* S2l = (bf16*)(region + plane);      // fk transposed (lo)
  bf16* P1h = (bf16*)(region + 2 * plane);  // psi1 out (hi)
  bf16* P1l = (bf16*)(region + 3 * plane);  // psi1 out (lo)
  bf16* F1h = (bf16*)(region + 4 * plane);  // phi1 out (hi)
  bf16* F1l = (bf16*)(region + 5 * plane);  // phi1 out (lo)

  size_t base_used = (size_t)(region - (char*)d_ws);
  size_t osz = (size_t)NQB3 * 256 * CH * 4;           // 18.9 MB per split
  size_t per_split = osz + 2 * (size_t)NQB3 * 256 * 4;
  long avail = (long)ws_size - (long)base_used;
  int S = 1;
  {
    // S=3 -> grid 216 fully co-resident at 1 block/CU; 288 % S == 0 required
    int cand[3] = {3, 2, 1};
    for (int i = 0; i < 3; i++)
      if ((long)cand[i] * (long)per_split <= avail) { S = cand[i]; break; }
  }
  float* Opart = (float*)region;
  float* Mpart = (float*)(region + (size_t)S * osz);
  float* Lpart = Mpart + (size_t)S * NQB3 * 256;
  float* Y5 = (float*)region;  // f_up fp32 out, overlays Opart (dead after combine)

  (void)in_sizes; (void)n_in; (void)out_size;

  prep_weights<<<1536, 256, 0, stream>>>(Ws, g, be, me, va, Wh, Wl, scale, bias);
  split_transpose2<<<2304, 256, 0, stream>>>(x, fk, S0h, S0l, S2h, S2l);

  auto W = [&](int layer) { return Wh + (size_t)layer * CH * CH; };
  auto Wlo = [&](int layer) { return Wl + (size_t)layer * CH * CH; };

  ConvJob psi1  {S0h, S0l, W(0), Wlo(0), scale + 0 * CH, bias + 0 * CH, P1h, P1l, nullptr, 0};
  ConvJob phi1  {S2h, S2l, W(2), Wlo(2), scale + 2 * CH, bias + 2 * CH, F1h, F1l, nullptr, 0};
  ConvJob fdown {S2h, S2l, W(4), Wlo(4), scale + 4 * CH, bias + 4 * CH, Vh, nullptr, nullptr, 1};
  ConvJob psi2  {P1h, P1l, W(1), Wlo(1), scale + 1 * CH, bias + 1 * CH, Qh, nullptr, nullptr, 1};
  ConvJob phi2  {F1h, F1l, W(3), Wlo(3), scale + 3 * CH, bias + 3 * CH, Kh, nullptr, nullptr, 1};

  conv128<<<864, 256, 0, stream>>>(psi1, phi1, fdown);
  conv128<<<576, 256, 0, stream>>>(psi2, phi2, phi2);
  transpose_bf16<<<1152, 256, 0, stream>>>(Vh, Vt);
  attn_part<<<NQB3 * S, 256, 0, stream>>>(Qh, Kh, Vt, Opart, Mpart, Lpart, 288 / S);
  attn_combine<<<NQB3 * 4, 256, 0, stream>>>(Opart, Mpart, Lpart, S0h, S0l, S);
  conv64<<<576, 256, 0, stream>>>(S0h, S0l, W(5), Wlo(5), scale + 5 * CH, bias + 5 * CH, Y5);
  transpose_out<<<1152, 256, 0, stream>>>(Y5, out);
}

// Round 13
// 560.391 us; speedup vs baseline: 3.9919x; 3.9919x over previous
//
#include <hip/hip_runtime.h>
#include <hip/hip_bf16.h>

typedef __bf16 bf16;
typedef __bf16 bf16x8 __attribute__((ext_vector_type(8)));
typedef float floatx4 __attribute__((ext_vector_type(4)));
typedef float floatx16 __attribute__((ext_vector_type(16)));

#define MFMA_BF16(a, b, c) __builtin_amdgcn_mfma_f32_16x16x32_bf16((a), (b), (c), 0, 0, 0)
#define MFMA32(a, b, c) __builtin_amdgcn_mfma_f32_32x32x16_bf16((a), (b), (c), 0, 0, 0)

static constexpr int CH = 256;      // channels
static constexpr int NPIX = 9216;   // 96*96
static constexpr int MTOT = 2 * NPIX; // both batches, n-major rows
static constexpr int NQB2 = 144;    // 128-row attention q-blocks total (2 batches)

// async global->LDS, 16B per lane; LDS dest = wave-uniform base + lane*16
__device__ __forceinline__ void async16(void* lds, const void* g) {
  __builtin_amdgcn_global_load_lds(
      (const __attribute__((address_space(1))) void*)g,
      (__attribute__((address_space(3))) void*)lds, 16, 0, 0);
}

// pack two f32 -> one u32 of 2 bf16 (lo = first arg)
__device__ __forceinline__ unsigned cvtpk(float lo, float hi) {
  unsigned r;
  asm("v_cvt_pk_bf16_f32 %0, %1, %2" : "=v"(r) : "v"(lo), "v"(hi));
  return r;
}

// v_permlane32_swap_b32 a, b  (VALU, gfx950, correctness-verified in v5 run):
//   a'[0:31]=a[0:31], a'[32:63]=b[0:31]; b'[0:31]=a[32:63], b'[32:63]=b[32:63]
__device__ __forceinline__ void plswap(unsigned& a, unsigned& b) {
  asm volatile("v_permlane32_swap_b32 %0, %1" : "+v"(a), "+v"(b));
}
// max/sum with lane^32 partner via permlane (VALU ~4cy vs ds_bpermute ~120cy)
__device__ __forceinline__ float xmax32(float v) {
  unsigned a = __builtin_bit_cast(unsigned, v), b = a;
  plswap(a, b);
  return fmaxf(__builtin_bit_cast(float, a), __builtin_bit_cast(float, b));
}
__device__ __forceinline__ float xsum32(float v) {
  unsigned a = __builtin_bit_cast(unsigned, v), b = a;
  plswap(a, b);
  return __builtin_bit_cast(float, a) + __builtin_bit_cast(float, b);
}

// ---------------------------------------------------------------------------
// Weight split (fp32 -> bf16 hi/lo) + folded BN scale/bias
// ---------------------------------------------------------------------------
__global__ void prep_weights(const float* __restrict__ W,
                             const float* __restrict__ g, const float* __restrict__ b,
                             const float* __restrict__ m, const float* __restrict__ v,
                             bf16* __restrict__ Wh, bf16* __restrict__ Wl,
                             float* __restrict__ scale, float* __restrict__ bias) {
  int i = blockIdx.x * 256 + threadIdx.x;
  if (i < 6 * CH * CH) {
    float w = W[i];
    bf16 h = (bf16)w;
    Wh[i] = h;
    Wl[i] = (bf16)(w - (float)h);
  }
  if (i < 6 * CH) {
    float s = g[i] * rsqrtf(v[i] + 1e-5f);
    scale[i] = s;
    bias[i] = b[i] - m[i] * s;
  }
}

// ---------------------------------------------------------------------------
// Both inputs: fp32 [B][256][9216] (c-major) -> bf16 hi/lo [B*9216][256]
// bid < 1152 -> x, else fk
// ---------------------------------------------------------------------------
__global__ void split_transpose2(const float* __restrict__ xin, const float* __restrict__ fkin,
                                 bf16* __restrict__ ohx, bf16* __restrict__ olx,
                                 bf16* __restrict__ ohf, bf16* __restrict__ olf) {
  __shared__ float t[64][65];
  int bid = blockIdx.x;
  const float* in; bf16 *oh, *ol;
  if (bid >= 1152) { in = fkin; oh = ohf; ol = olf; bid -= 1152; }
  else             { in = xin;  oh = ohx; ol = olx; }
  int b = bid / 576, rem = bid % 576;
  int ct = rem / 144, nt = rem % 144;
  int c0 = ct * 64, n0 = nt * 64;
  int tid = threadIdx.x;
  int cr = tid >> 4, nc = (tid & 15) * 4;
  for (int rr = 0; rr < 64; rr += 16) {
    int c = cr + rr;
    const float* p = in + ((size_t)(b * CH + c0 + c) * NPIX) + n0 + nc;
    float4 val = *(const float4*)p;
    t[c][nc + 0] = val.x; t[c][nc + 1] = val.y;
    t[c][nc + 2] = val.z; t[c][nc + 3] = val.w;
  }
  __syncthreads();
  int n = tid >> 2, cb = (tid & 3) * 16;
  bf16 hb[16], lb[16];
#pragma unroll
  for (int j = 0; j < 16; j++) {
    float xv = t[cb + j][n];
    bf16 h = (bf16)xv;
    hb[j] = h;
    lb[j] = (bf16)(xv - (float)h);
  }
  size_t idx = (size_t)(b * NPIX + n0 + n) * CH + c0 + cb;
  *(bf16x8*)&oh[idx]     = *(bf16x8*)&hb[0];
  *(bf16x8*)&oh[idx + 8] = *(bf16x8*)&hb[8];
  *(bf16x8*)&ol[idx]     = *(bf16x8*)&lb[0];
  *(bf16x8*)&ol[idx + 8] = *(bf16x8*)&lb[8];
}

// ---------------------------------------------------------------------------
// bf16 [B*9216][256] (n-major) -> bf16 [B][256][9216] (c-major)   (for V)
// ---------------------------------------------------------------------------
__global__ void transpose_bf16(const bf16* __restrict__ in, bf16* __restrict__ out) {
  __shared__ bf16 t[64][72];
  int bid = blockIdx.x;
  int b = bid / 576, rem = bid % 576;
  int ct = rem / 144, nt = rem % 144;
  int c0 = ct * 64, n0 = nt * 64;
  int tid = threadIdx.x;
  int nr = tid >> 4, cc = (tid & 15) * 4;
  for (int rr = 0; rr < 64; rr += 16) {
    int n = nr + rr;
    const bf16* p = in + (size_t)(b * NPIX + n0 + n) * CH + c0 + cc;
#pragma unroll
    for (int j = 0; j < 4; j++) t[cc + j][n] = p[j];
  }
  __syncthreads();
  int c = tid >> 2, nb = (tid & 3) * 16;
  bf16 buf[16];
#pragma unroll
  for (int j = 0; j < 16; j++) buf[j] = t[c][nb + j];
  size_t idx = (size_t)(b * CH + c0 + c) * NPIX + n0 + nb;
  *(bf16x8*)&out[idx]     = *(bf16x8*)&buf[0];
  *(bf16x8*)&out[idx + 8] = *(bf16x8*)&buf[8];
}

// ---------------------------------------------------------------------------
// fp32 [B*9216][256] (n-major) -> fp32 [B][256][9216]   (final output)
// ---------------------------------------------------------------------------
__global__ void transpose_out(const float* __restrict__ in, float* __restrict__ out) {
  __shared__ float t[64][65];
  int bid = blockIdx.x;
  int b = bid / 576, rem = bid % 576;
  int ct = rem / 144, nt = rem % 144;
  int c0 = ct * 64, n0 = nt * 64;
  int tid = threadIdx.x;
  int nr = tid >> 4, cc = (tid & 15) * 4;
  for (int rr = 0; rr < 64; rr += 16) {
    int n = nr + rr;
    float4 v = *(const float4*)&in[(size_t)(b * NPIX + n0 + n) * CH + c0 + cc];
    t[cc + 0][n] = v.x; t[cc + 1][n] = v.y; t[cc + 2][n] = v.z; t[cc + 3][n] = v.w;
  }
  __syncthreads();
  int c = tid >> 2, nb = (tid & 3) * 16;
#pragma unroll
  for (int k = 0; k < 4; k++) {
    float4 o4 = make_float4(t[c][nb + 4 * k + 0], t[c][nb + 4 * k + 1],
                            t[c][nb + 4 * k + 2], t[c][nb + 4 * k + 3]);
    *(float4*)&out[(size_t)(b * CH + c0 + c) * NPIX + n0 + nb + 4 * k] = o4;
  }
}

// ---------------------------------------------------------------------------
// Batched split-bf16 conv-GEMM, 128x128 tiles (288 blocks per job).
// mode: 0 = write hi+lo bf16, 1 = hi only, 2 = fp32
// ---------------------------------------------------------------------------
struct ConvJob {
  const bf16 *Ah, *Al, *Bh, *Bl;
  const float *scale, *bias;
  bf16 *Yh, *Yl; float *Yf;
  int mode;
};

__global__ __launch_bounds__(256, 3) void conv128(ConvJob j0, ConvJob j1, ConvJob j2) {
  __shared__ bf16 lds[4][8 * 512];  // planes: Ah, Al, Bh, Bl
  int jid = blockIdx.x / 288;
  int bid = blockIdx.x % 288;
  ConvJob j = (jid == 0) ? j0 : (jid == 1) ? j1 : j2;

  int tid = threadIdx.x;
  int w = tid >> 6, l = tid & 63;
  int q = l >> 4, c16 = l & 15;
  int m0 = (bid >> 1) * 128;
  int o0 = (bid & 1) * 128;

  const bf16* src = (w == 0) ? j.Ah : (w == 1) ? j.Al : (w == 2) ? j.Bh : j.Bl;
  int rowbase = (w < 2) ? m0 : o0;
  const bf16* gp = src + (size_t)(rowbase + c16) * CH + q * 8;
  bf16* ldst = &lds[w][0];

  const floatx4 zero4 = {0.f, 0.f, 0.f, 0.f};
  floatx4 acc[4][4];
#pragma unroll
  for (int i = 0; i < 4; i++)
#pragma unroll
    for (int jj = 0; jj < 4; jj++) acc[i][jj] = zero4;

  int mo16 = (w & 1) * 4, no16 = (w >> 1) * 4;

  for (int k0 = 0; k0 < CH; k0 += 32) {
#pragma unroll
    for (int f = 0; f < 8; f++)
      async16(ldst + f * 512, gp + (size_t)f * 16 * CH + k0);
    __syncthreads();

    bf16x8 ah[4], al[4], bh[4], bl[4];
#pragma unroll
    for (int i = 0; i < 4; i++) {
      ah[i] = *(const bf16x8*)&lds[0][(mo16 + i) * 512 + l * 8];
      al[i] = *(const bf16x8*)&lds[1][(mo16 + i) * 512 + l * 8];
      bh[i] = *(const bf16x8*)&lds[2][(no16 + i) * 512 + l * 8];
      bl[i] = *(const bf16x8*)&lds[3][(no16 + i) * 512 + l * 8];
    }
#pragma unroll
    for (int i = 0; i < 4; i++)
#pragma unroll
      for (int jj = 0; jj < 4; jj++) {
        acc[i][jj] = MFMA_BF16(ah[i], bh[jj], acc[i][jj]);
        acc[i][jj] = MFMA_BF16(ah[i], bl[jj], acc[i][jj]);
        acc[i][jj] = MFMA_BF16(al[i], bh[jj], acc[i][jj]);
      }
    __syncthreads();
  }

  int mo = (w & 1) * 64, no = (w >> 1) * 64;
  float sc[4], bs[4];
#pragma unroll
  for (int jj = 0; jj < 4; jj++) {
    int o = o0 + no + 16 * jj + c16;
    sc[jj] = j.scale[o];
    bs[jj] = j.bias[o];
  }
#pragma unroll
  for (int i = 0; i < 4; i++) {
    int nrow = m0 + mo + 16 * i + 4 * q;
#pragma unroll
    for (int jj = 0; jj < 4; jj++) {
      int o = o0 + no + 16 * jj + c16;
#pragma unroll
      for (int r = 0; r < 4; r++) {
        float y = acc[i][jj][r] * sc[jj] + bs[jj];
        y = fmaxf(y, 0.f);
        size_t idx = (size_t)(nrow + r) * CH + o;
        if (j.mode == 2) {
          j.Yf[idx] = y;
        } else if (j.mode == 1) {
          j.Yh[idx] = (bf16)y;
        } else {
          bf16 h = (bf16)y;
          j.Yh[idx] = h;
          j.Yl[idx] = (bf16)(y - (float)h);
        }
      }
    }
  }
}

// ---------------------------------------------------------------------------
// 64x128-tile split-bf16 conv-GEMM, fp32 out (f_up). Grid 576, LDS 24 KB.
// ---------------------------------------------------------------------------
__global__ __launch_bounds__(256, 4) void conv64(
    const bf16* __restrict__ Ah, const bf16* __restrict__ Al,
    const bf16* __restrict__ Bh, const bf16* __restrict__ Bl,
    const float* __restrict__ scale, const float* __restrict__ bias,
    float* __restrict__ Yf) {
  __shared__ bf16 lds[24 * 512];  // flat frags: [Ah0-3, Al0-3, Bh0-7, Bl0-7]
  int tid = threadIdx.x;
  int w = tid >> 6, l = tid & 63;
  int q = l >> 4, c16 = l & 15;
  int m0 = (blockIdx.x >> 1) * 64;
  int o0 = (blockIdx.x & 1) * 128;

  const floatx4 zero4 = {0.f, 0.f, 0.f, 0.f};
  floatx4 acc[4][2];
#pragma unroll
  for (int i = 0; i < 4; i++) { acc[i][0] = zero4; acc[i][1] = zero4; }

  for (int k0 = 0; k0 < CH; k0 += 32) {
#pragma unroll
    for (int ff = 0; ff < 6; ff++) {
      int f = w * 6 + ff;
      const bf16* src; int rbase, fl;
      if (f < 4)       { src = Ah; rbase = m0; fl = f; }
      else if (f < 8)  { src = Al; rbase = m0; fl = f - 4; }
      else if (f < 16) { src = Bh; rbase = o0; fl = f - 8; }
      else             { src = Bl; rbase = o0; fl = f - 16; }
      async16(&lds[f * 512], src + (size_t)(rbase + fl * 16 + c16) * CH + k0 + q * 8);
    }
    __syncthreads();

    bf16x8 ah[4], al[4], bh[2], bl[2];
#pragma unroll
    for (int i = 0; i < 4; i++) {
      ah[i] = *(const bf16x8*)&lds[(0 + i) * 512 + l * 8];
      al[i] = *(const bf16x8*)&lds[(4 + i) * 512 + l * 8];
    }
#pragma unroll
    for (int n = 0; n < 2; n++) {
      bh[n] = *(const bf16x8*)&lds[(8 + 2 * w + n) * 512 + l * 8];
      bl[n] = *(const bf16x8*)&lds[(16 + 2 * w + n) * 512 + l * 8];
    }
#pragma unroll
    for (int i = 0; i < 4; i++)
#pragma unroll
      for (int n = 0; n < 2; n++) {
        acc[i][n] = MFMA_BF16(ah[i], bh[n], acc[i][n]);
        acc[i][n] = MFMA_BF16(ah[i], bl[n], acc[i][n]);
        acc[i][n] = MFMA_BF16(al[i], bh[n], acc[i][n]);
      }
    __syncthreads();
  }

  float sc[2], bs[2];
#pragma unroll
  for (int n = 0; n < 2; n++) {
    int o = o0 + 32 * w + 16 * n + c16;
    sc[n] = scale[o];
    bs[n] = bias[o];
  }
#pragma unroll
  for (int i = 0; i < 4; i++) {
    int nrow = m0 + 16 * i + 4 * q;
#pragma unroll
    for (int n = 0; n < 2; n++) {
      int o = o0 + 32 * w + 16 * n + c16;
#pragma unroll
      for (int r = 0; r < 4; r++) {
        float y = acc[i][n][r] * sc[n] + bs[n];
        Yf[(size_t)(nrow + r) * CH + o] = fmaxf(y, 0.f);
      }
    }
  }
}

// ---------------------------------------------------------------------------
// Split-KV flash attention partial, v6 = v3 (proven 296us) + verified deltas.
// BQ=128 (4 waves x 32 q-rows), BKV=32, 32x32x16 MFMAs, in-register P.
//
// v4/v5 post-mortem: both register-heavy restructurings spilled (at 2
// waves/SIMD the unified budget is 256/wave and v3 uses exactly 128+128;
// 1 wave/SIMD with 470+ regs spilled catastrophically). v6 keeps v3's
// structure and applies only register-neutral deltas:
//  * xor-32 softmax max/sum + P-pack half-exchange via
//    v_permlane32_swap_b32 (VALU ~4cy) instead of ds_bpermute (~120cy,
//    LDS pipe) -- removes ~6 DS ops/iter from the bounding DS pipe and
//    the serial softmax chain. Correctness-verified in the v5 run.
//  * s_setprio(1) around MFMA clusters (T5): the 2 blocks/CU are
//    independent (attn regime, m191 +4-7%), not barrier-lockstep.
// VGPR 128 arch + 128 acc; LDS 64 KB -> 2 blocks/CU; S=3, grid 432.
// ---------------------------------------------------------------------------
__global__ __launch_bounds__(256, 2) void attn_part(
    const bf16* __restrict__ Q, const bf16* __restrict__ K, const bf16* __restrict__ Vt,
    float* __restrict__ Opart, float* __restrict__ Mpart, float* __restrict__ Lpart,
    int niter) {
  __shared__ bf16 lK[2][16 * 512];  // frag ks: K[key=l&31][16ks+8hi+i]
  __shared__ bf16 lV[2][16 * 512];  // frag 2ct+ks2: V[ch=32ct+(l&31)][16ks2+8hi+i]

  int tid = threadIdx.x;
  int w = tid >> 6, l = tid & 63;
  int ql = l & 31, hi = l >> 5;
  int bid = blockIdx.x;
  int qb = bid % NQB2, s = bid / NQB2;
  int b = qb / 72;
  int n0 = (qb % 72) * 128;
  int kv0 = s * niter * 32;
  size_t qkbase = (size_t)b * NPIX * CH;
  size_t vbase  = (size_t)b * CH * NPIX;

  // Q fragments (B-operand 32x32x16): col = q-row = ql, k = 8hi+i per 16-ch step
  bf16x8 qf[16];
  {
    const bf16* qp = Q + qkbase + (size_t)(n0 + 32 * w + ql) * CH + 8 * hi;
#pragma unroll
    for (int ks = 0; ks < 16; ks++) qf[ks] = *(const bf16x8*)(qp + ks * 16);
  }

  floatx16 oacc[8];  // [ct]: O[q=(r&3)+8(r>>2)+4hi][ch=32ct+ql]
#pragma unroll
  for (int ct = 0; ct < 8; ct++)
#pragma unroll
    for (int r = 0; r < 16; r++) oacc[ct][r] = 0.f;
  float mrow = -1e30f, lrow = 0.f;

  const bf16* gK = K + qkbase + (size_t)kv0 * CH;
  const bf16* gV = Vt + vbase + kv0;

  // wave w stages K frags 4w..4w+3 and V frags 4w..4w+3 (8 async16/iter)
  auto stage = [&](int bi) {
#pragma unroll
    for (int ff = 0; ff < 4; ff++) {
      int f = 4 * w + ff;
      async16(&lK[bi][f * 512], gK + (size_t)ql * CH + f * 16 + 8 * hi);
      async16(&lV[bi][f * 512],
              gV + (size_t)((f >> 1) * 32 + ql) * NPIX + (f & 1) * 16 + 8 * hi);
    }
  };

  stage(0);

  for (int it = 0; it < niter; it++) {
    int cur = it & 1;
    __syncthreads();  // buffers `cur` ready (vmcnt drained); prev reads retired

    if (it + 1 < niter) {
      gK += 32 * CH; gV += 32;
      stage(cur ^ 1);
    }

    // S^T = K Q^T : D[key][q], two independent accumulator chains
    floatx16 sfA, sfB;
#pragma unroll
    for (int r = 0; r < 16; r++) { sfA[r] = 0.f; sfB[r] = 0.f; }
    __builtin_amdgcn_s_setprio(1);
#pragma unroll
    for (int ks = 0; ks < 16; ks += 2) {
      bf16x8 kf0 = *(const bf16x8*)&lK[cur][(ks + 0) * 512 + l * 8];
      bf16x8 kf1 = *(const bf16x8*)&lK[cur][(ks + 1) * 512 + l * 8];
      sfA = MFMA32(kf0, qf[ks + 0], sfA);
      sfB = MFMA32(kf1, qf[ks + 1], sfB);
    }
    __builtin_amdgcn_s_setprio(0);
    // combine + tile max for this lane's q-row (other 16 keys live in lane^32)
    float pm = -1e30f;
#pragma unroll
    for (int r = 0; r < 16; r++) {
      float sv = sfA[r] + sfB[r];
      sfA[r] = sv;
      pm = fmaxf(pm, sv);
    }
    pm = xmax32(pm);

    // defer-max: rescale only when row max grew by > 8
    bool need = pm > mrow + 8.f;
    if (__ballot((int)need) != 0ull) {
      float mn = fmaxf(mrow, pm);
      float alpha = __expf(mrow - mn);
      mrow = mn;
      lrow *= alpha;
      float arow[16];
#pragma unroll
      for (int r = 0; r < 16; r++)
        arow[r] = __shfl(alpha, (r & 3) + 8 * (r >> 2) + 4 * hi);
#pragma unroll
      for (int ct = 0; ct < 8; ct++)
#pragma unroll
        for (int r = 0; r < 16; r++) oacc[ct][r] *= arow[r];
    }

    // P = exp(S - m) (all 16 values belong to this lane's own q-row)
    float p[16];
    float rs = 0.f;
#pragma unroll
    for (int r = 0; r < 16; r++) {
      p[r] = __expf(sfA[r] - mrow);
      rs += p[r];
    }
    lrow += xsum32(rs);

    // pack to PV A-frags: reg r holds key (r&3)+8(r>>2)+4hi
    // permlane32_swap half-exchange (verified ≡ v3's shfl_xor select form)
    unsigned pk0 = cvtpk(p[0], p[1]),   pk1 = cvtpk(p[2], p[3]);
    unsigned pk2 = cvtpk(p[4], p[5]),   pk3 = cvtpk(p[6], p[7]);
    unsigned pk4 = cvtpk(p[8], p[9]),   pk5 = cvtpk(p[10], p[11]);
    unsigned pk6 = cvtpk(p[12], p[13]), pk7 = cvtpk(p[14], p[15]);
    plswap(pk0, pk2); plswap(pk1, pk3);
    plswap(pk4, pk6); plswap(pk5, pk7);
    uint4 u0, u1;
    u0.x = pk0; u0.y = pk1; u0.z = pk2; u0.w = pk3;  // keys 0..15, k = 8hi+i
    u1.x = pk4; u1.y = pk5; u1.z = pk6; u1.w = pk7;  // keys 16..31
    bf16x8 pa0 = __builtin_bit_cast(bf16x8, u0);
    bf16x8 pa1 = __builtin_bit_cast(bf16x8, u1);

    // PV: O[q][ch] += P[q][k] V[k][ch]
    __builtin_amdgcn_s_setprio(1);
#pragma unroll
    for (int ct = 0; ct < 8; ct++) {
      bf16x8 vb0 = *(const bf16x8*)&lV[cur][(2 * ct + 0) * 512 + l * 8];
      bf16x8 vb1 = *(const bf16x8*)&lV[cur][(2 * ct + 1) * 512 + l * 8];
      oacc[ct] = MFMA32(pa0, vb0, oacc[ct]);
      oacc[ct] = MFMA32(pa1, vb1, oacc[ct]);
    }
    __builtin_amdgcn_s_setprio(0);
  }

  // write partials (unnormalized O + m, l)
  if (hi == 0) {
    Mpart[(size_t)bid * 128 + 32 * w + ql] = mrow;
    Lpart[(size_t)bid * 128 + 32 * w + ql] = lrow;
  }
  float* Ob = Opart + (size_t)bid * 128 * CH;
#pragma unroll
  for (int ct = 0; ct < 8; ct++)
#pragma unroll
    for (int r = 0; r < 16; r++) {
      int row = 32 * w + (r & 3) + 8 * (r >> 2) + 4 * hi;
      Ob[(size_t)row * CH + 32 * ct + ql] = oacc[ct][r];
    }
}

// ---------------------------------------------------------------------------
// Combine S partials -> normalized O, split hi/lo bf16, n-major [MTOT][256]
// grid = NQB2 (144 q-blocks of 128 rows), 256 threads
// ---------------------------------------------------------------------------
__global__ __launch_bounds__(256) void attn_combine(
    const float* __restrict__ Opart, const float* __restrict__ Mpart,
    const float* __restrict__ Lpart,
    bf16* __restrict__ Oh, bf16* __restrict__ Ol, int S) {
  __shared__ float wgt[8][128];
  __shared__ float invl[128];
  int qb = blockIdx.x;
  int t = threadIdx.x;
  if (t < 128) {
    float m = -1e30f;
    for (int s = 0; s < S; s++)
      m = fmaxf(m, Mpart[(size_t)(s * NQB2 + qb) * 128 + t]);
    float lsum = 0.f;
    for (int s = 0; s < S; s++) {
      float wv = __expf(Mpart[(size_t)(s * NQB2 + qb) * 128 + t] - m);
      wgt[s][t] = wv;
      lsum += wv * Lpart[(size_t)(s * NQB2 + qb) * 128 + t];
    }
    invl[t] = 1.0f / lsum;
  }
  __syncthreads();
  int c = t;  // 256 threads = 256 channels
  for (int row = 0; row < 128; row++) {
    float acc = 0.f;
    for (int s = 0; s < S; s++)
      acc += wgt[s][row] * Opart[((size_t)(s * NQB2 + qb) * 128 + row) * CH + c];
    float y = acc * invl[row];
    size_t idx = (size_t)(qb * 128 + row) * CH + c;
    bf16 h = (bf16)y;
    Oh[idx] = h;
    Ol[idx] = (bf16)(y - (float)h);
  }
}

// ---------------------------------------------------------------------------
extern "C" void kernel_launch(void* const* d_in, const int* in_sizes, int n_in,
                              void* d_out, int out_size, void* d_ws, size_t ws_size,
                              hipStream_t stream) {
  const float* x  = (const float*)d_in[0];
  const float* fk = (const float*)d_in[1];
  const float* Ws = (const float*)d_in[2];
  const float* g  = (const float*)d_in[3];
  const float* be = (const float*)d_in[4];
  const float* me = (const float*)d_in[5];
  const float* va = (const float*)d_in[6];
  float* out = (float*)d_out;

  char* p = (char*)d_ws;
  bf16* Wh = (bf16*)p; p += (size_t)6 * CH * CH * 2;
  bf16* Wl = (bf16*)p; p += (size_t)6 * CH * CH * 2;
  float* scale = (float*)p; p += (size_t)6 * CH * 4;
  float* bias  = (float*)p; p += (size_t)6 * CH * 4;
  size_t plane = (size_t)MTOT * CH * 2;  // 9,437,184 B per bf16 plane
  bf16* S0h = (bf16*)p; p += plane;
  bf16* S0l = (bf16*)p; p += plane;
  bf16* Qh  = (bf16*)p; p += plane;
  bf16* Kh  = (bf16*)p; p += plane;
  bf16* Vh  = (bf16*)p; p += plane;
  bf16* Vt  = (bf16*)p; p += plane;
  char* region = p;

  // Overlays inside `region` (all dead before attn_part writes Opart there):
  bf16* S2h = (bf16*)(region);              // fk transposed (hi)
  bf16* S2l = (bf16*)(region + plane);      // fk transposed (lo)
  bf16* P1h = (bf16*)(region + 2 * plane);  // psi1 out (hi)
  bf16* P1l = (bf16*)(region + 3 * plane);  // psi1 out (lo)
  bf16* F1h = (bf16*)(region + 4 * plane);  // phi1 out (hi)
  bf16* F1l = (bf16*)(region + 5 * plane);  // phi1 out (lo)

  size_t base_used = (size_t)(region - (char*)d_ws);
  size_t osz = (size_t)NQB2 * 128 * CH * 4;           // 18.9 MB per split
  size_t per_split = osz + 2 * (size_t)NQB2 * 128 * 4;
  long avail = (long)ws_size - (long)base_used;
  int S = 1;
  {
    // S=3 -> grid 432 fully co-resident at 2 blocks/CU; 288 % S == 0 required
    int cand[3] = {3, 2, 1};
    for (int i = 0; i < 3; i++)
      if ((long)cand[i] * (long)per_split <= avail) { S = cand[i]; break; }
  }
  float* Opart = (float*)region;
  float* Mpart = (float*)(region + (size_t)S * osz);
  float* Lpart = Mpart + (size_t)S * NQB2 * 128;
  float* Y5 = (float*)region;  // f_up fp32 out, overlays Opart (dead after combine)

  (void)in_sizes; (void)n_in; (void)out_size;

  prep_weights<<<1536, 256, 0, stream>>>(Ws, g, be, me, va, Wh, Wl, scale, bias);
  split_transpose2<<<2304, 256, 0, stream>>>(x, fk, S0h, S0l, S2h, S2l);

  auto W = [&](int layer) { return Wh + (size_t)layer * CH * CH; };
  auto Wlo = [&](int layer) { return Wl + (size_t)layer * CH * CH; };

  ConvJob psi1  {S0h, S0l, W(0), Wlo(0), scale + 0 * CH, bias + 0 * CH, P1h, P1l, nullptr, 0};
  ConvJob phi1  {S2h, S2l, W(2), Wlo(2), scale + 2 * CH, bias + 2 * CH, F1h, F1l, nullptr, 0};
  ConvJob fdown {S2h, S2l, W(4), Wlo(4), scale + 4 * CH, bias + 4 * CH, Vh, nullptr, nullptr, 1};
  ConvJob psi2  {P1h, P1l, W(1), Wlo(1), scale + 1 * CH, bias + 1 * CH, Qh, nullptr, nullptr, 1};
  ConvJob phi2  {F1h, F1l, W(3), Wlo(3), scale + 3 * CH, bias + 3 * CH, Kh, nullptr, nullptr, 1};

  conv128<<<864, 256, 0, stream>>>(psi1, phi1, fdown);
  conv128<<<576, 256, 0, stream>>>(psi2, phi2, phi2);
  transpose_bf16<<<1152, 256, 0, stream>>>(Vh, Vt);
  attn_part<<<NQB2 * S, 256, 0, stream>>>(Qh, Kh, Vt, Opart, Mpart, Lpart, 288 / S);
  attn_combine<<<NQB2, 256, 0, stream>>>(Opart, Mpart, Lpart, S0h, S0l, S);
  conv64<<<576, 256, 0, stream>>>(S0h, S0l, W(5), Wlo(5), scale + 5 * CH, bias + 5 * CH, Y5);
  transpose_out<<<1152, 256, 0, stream>>>(Y5, out);
}

// Round 15
// 483.425 us; speedup vs baseline: 4.6274x; 1.1592x over previous
//
#include <hip/hip_runtime.h>
#include <hip/hip_bf16.h>

typedef __bf16 bf16;
typedef __bf16 bf16x8 __attribute__((ext_vector_type(8)));
typedef float floatx4 __attribute__((ext_vector_type(4)));
typedef float floatx16 __attribute__((ext_vector_type(16)));

#define MFMA_BF16(a, b, c) __builtin_amdgcn_mfma_f32_16x16x32_bf16((a), (b), (c), 0, 0, 0)
#define MFMA32(a, b, c) __builtin_amdgcn_mfma_f32_32x32x16_bf16((a), (b), (c), 0, 0, 0)

static constexpr int CH = 256;      // channels
static constexpr int NPIX = 9216;   // 96*96
static constexpr int MTOT = 2 * NPIX; // both batches, n-major rows
static constexpr int NQB2 = 144;    // 128-row attention q-blocks total (2 batches)

// async global->LDS, 16B per lane; LDS dest = wave-uniform base + lane*16
__device__ __forceinline__ void async16(void* lds, const void* g) {
  __builtin_amdgcn_global_load_lds(
      (const __attribute__((address_space(1))) void*)g,
      (__attribute__((address_space(3))) void*)lds, 16, 0, 0);
}

// pack two f32 -> one u32 of 2 bf16 (lo = first arg)
__device__ __forceinline__ unsigned cvtpk(float lo, float hi) {
  unsigned r;
  asm("v_cvt_pk_bf16_f32 %0, %1, %2" : "=v"(r) : "v"(lo), "v"(hi));
  return r;
}

// v_permlane32_swap_b32 a, b  (VALU, gfx950, correctness-verified in v5/v6 runs):
//   a'[0:31]=a[0:31], a'[32:63]=b[0:31]; b'[0:31]=a[32:63], b'[32:63]=b[32:63]
__device__ __forceinline__ void plswap(unsigned& a, unsigned& b) {
  asm volatile("v_permlane32_swap_b32 %0, %1" : "+v"(a), "+v"(b));
}
// max/sum with lane^32 partner via permlane (VALU ~4cy vs ds_bpermute ~120cy)
__device__ __forceinline__ float xmax32(float v) {
  unsigned a = __builtin_bit_cast(unsigned, v), b = a;
  plswap(a, b);
  return fmaxf(__builtin_bit_cast(float, a), __builtin_bit_cast(float, b));
}
__device__ __forceinline__ float xsum32(float v) {
  unsigned a = __builtin_bit_cast(unsigned, v), b = a;
  plswap(a, b);
  return __builtin_bit_cast(float, a) + __builtin_bit_cast(float, b);
}

// ---------------------------------------------------------------------------
// Weight split (fp32 -> bf16 hi/lo) + folded BN scale/bias
// ---------------------------------------------------------------------------
__global__ void prep_weights(const float* __restrict__ W,
                             const float* __restrict__ g, const float* __restrict__ b,
                             const float* __restrict__ m, const float* __restrict__ v,
                             bf16* __restrict__ Wh, bf16* __restrict__ Wl,
                             float* __restrict__ scale, float* __restrict__ bias) {
  int i = blockIdx.x * 256 + threadIdx.x;
  if (i < 6 * CH * CH) {
    float w = W[i];
    bf16 h = (bf16)w;
    Wh[i] = h;
    Wl[i] = (bf16)(w - (float)h);
  }
  if (i < 6 * CH) {
    float s = g[i] * rsqrtf(v[i] + 1e-5f);
    scale[i] = s;
    bias[i] = b[i] - m[i] * s;
  }
}

// ---------------------------------------------------------------------------
// Both inputs: fp32 [B][256][9216] (c-major) -> bf16 hi/lo [B*9216][256]
// bid < 1152 -> x, else fk
// ---------------------------------------------------------------------------
__global__ void split_transpose2(const float* __restrict__ xin, const float* __restrict__ fkin,
                                 bf16* __restrict__ ohx, bf16* __restrict__ olx,
                                 bf16* __restrict__ ohf, bf16* __restrict__ olf) {
  __shared__ float t[64][65];
  int bid = blockIdx.x;
  const float* in; bf16 *oh, *ol;
  if (bid >= 1152) { in = fkin; oh = ohf; ol = olf; bid -= 1152; }
  else             { in = xin;  oh = ohx; ol = olx; }
  int b = bid / 576, rem = bid % 576;
  int ct = rem / 144, nt = rem % 144;
  int c0 = ct * 64, n0 = nt * 64;
  int tid = threadIdx.x;
  int cr = tid >> 4, nc = (tid & 15) * 4;
  for (int rr = 0; rr < 64; rr += 16) {
    int c = cr + rr;
    const float* p = in + ((size_t)(b * CH + c0 + c) * NPIX) + n0 + nc;
    float4 val = *(const float4*)p;
    t[c][nc + 0] = val.x; t[c][nc + 1] = val.y;
    t[c][nc + 2] = val.z; t[c][nc + 3] = val.w;
  }
  __syncthreads();
  int n = tid >> 2, cb = (tid & 3) * 16;
  bf16 hb[16], lb[16];
#pragma unroll
  for (int j = 0; j < 16; j++) {
    float xv = t[cb + j][n];
    bf16 h = (bf16)xv;
    hb[j] = h;
    lb[j] = (bf16)(xv - (float)h);
  }
  size_t idx = (size_t)(b * NPIX + n0 + n) * CH + c0 + cb;
  *(bf16x8*)&oh[idx]     = *(bf16x8*)&hb[0];
  *(bf16x8*)&oh[idx + 8] = *(bf16x8*)&hb[8];
  *(bf16x8*)&ol[idx]     = *(bf16x8*)&lb[0];
  *(bf16x8*)&ol[idx + 8] = *(bf16x8*)&lb[8];
}

// ---------------------------------------------------------------------------
// bf16 [B*9216][256] (n-major) -> bf16 [B][256][9216] (c-major)   (for V)
// ---------------------------------------------------------------------------
__global__ void transpose_bf16(const bf16* __restrict__ in, bf16* __restrict__ out) {
  __shared__ bf16 t[64][72];
  int bid = blockIdx.x;
  int b = bid / 576, rem = bid % 576;
  int ct = rem / 144, nt = rem % 144;
  int c0 = ct * 64, n0 = nt * 64;
  int tid = threadIdx.x;
  int nr = tid >> 4, cc = (tid & 15) * 4;
  for (int rr = 0; rr < 64; rr += 16) {
    int n = nr + rr;
    const bf16* p = in + (size_t)(b * NPIX + n0 + n) * CH + c0 + cc;
#pragma unroll
    for (int j = 0; j < 4; j++) t[cc + j][n] = p[j];
  }
  __syncthreads();
  int c = tid >> 2, nb = (tid & 3) * 16;
  bf16 buf[16];
#pragma unroll
  for (int j = 0; j < 16; j++) buf[j] = t[c][nb + j];
  size_t idx = (size_t)(b * CH + c0 + c) * NPIX + n0 + nb;
  *(bf16x8*)&out[idx]     = *(bf16x8*)&buf[0];
  *(bf16x8*)&out[idx + 8] = *(bf16x8*)&buf[8];
}

// ---------------------------------------------------------------------------
// fp32 [B*9216][256] (n-major) -> fp32 [B][256][9216]   (final output)
// ---------------------------------------------------------------------------
__global__ void transpose_out(const float* __restrict__ in, float* __restrict__ out) {
  __shared__ float t[64][65];
  int bid = blockIdx.x;
  int b = bid / 576, rem = bid % 576;
  int ct = rem / 144, nt = rem % 144;
  int c0 = ct * 64, n0 = nt * 64;
  int tid = threadIdx.x;
  int nr = tid >> 4, cc = (tid & 15) * 4;
  for (int rr = 0; rr < 64; rr += 16) {
    int n = nr + rr;
    float4 v = *(const float4*)&in[(size_t)(b * NPIX + n0 + n) * CH + c0 + cc];
    t[cc + 0][n] = v.x; t[cc + 1][n] = v.y; t[cc + 2][n] = v.z; t[cc + 3][n] = v.w;
  }
  __syncthreads();
  int c = tid >> 2, nb = (tid & 3) * 16;
#pragma unroll
  for (int k = 0; k < 4; k++) {
    float4 o4 = make_float4(t[c][nb + 4 * k + 0], t[c][nb + 4 * k + 1],
                            t[c][nb + 4 * k + 2], t[c][nb + 4 * k + 3]);
    *(float4*)&out[(size_t)(b * CH + c0 + c) * NPIX + n0 + nb + 4 * k] = o4;
  }
}

// ---------------------------------------------------------------------------
// Batched split-bf16 conv-GEMM, 128x128 tiles (288 blocks per job).
// mode: 0 = write hi+lo bf16, 1 = hi only, 2 = fp32
// ---------------------------------------------------------------------------
struct ConvJob {
  const bf16 *Ah, *Al, *Bh, *Bl;
  const float *scale, *bias;
  bf16 *Yh, *Yl; float *Yf;
  int mode;
};

__global__ __launch_bounds__(256, 3) void conv128(ConvJob j0, ConvJob j1, ConvJob j2) {
  __shared__ bf16 lds[4][8 * 512];  // planes: Ah, Al, Bh, Bl
  int jid = blockIdx.x / 288;
  int bid = blockIdx.x % 288;
  ConvJob j = (jid == 0) ? j0 : (jid == 1) ? j1 : j2;

  int tid = threadIdx.x;
  int w = tid >> 6, l = tid & 63;
  int q = l >> 4, c16 = l & 15;
  int m0 = (bid >> 1) * 128;
  int o0 = (bid & 1) * 128;

  const bf16* src = (w == 0) ? j.Ah : (w == 1) ? j.Al : (w == 2) ? j.Bh : j.Bl;
  int rowbase = (w < 2) ? m0 : o0;
  const bf16* gp = src + (size_t)(rowbase + c16) * CH + q * 8;
  bf16* ldst = &lds[w][0];

  const floatx4 zero4 = {0.f, 0.f, 0.f, 0.f};
  floatx4 acc[4][4];
#pragma unroll
  for (int i = 0; i < 4; i++)
#pragma unroll
    for (int jj = 0; jj < 4; jj++) acc[i][jj] = zero4;

  int mo16 = (w & 1) * 4, no16 = (w >> 1) * 4;

  for (int k0 = 0; k0 < CH; k0 += 32) {
#pragma unroll
    for (int f = 0; f < 8; f++)
      async16(ldst + f * 512, gp + (size_t)f * 16 * CH + k0);
    __syncthreads();

    bf16x8 ah[4], al[4], bh[4], bl[4];
#pragma unroll
    for (int i = 0; i < 4; i++) {
      ah[i] = *(const bf16x8*)&lds[0][(mo16 + i) * 512 + l * 8];
      al[i] = *(const bf16x8*)&lds[1][(mo16 + i) * 512 + l * 8];
      bh[i] = *(const bf16x8*)&lds[2][(no16 + i) * 512 + l * 8];
      bl[i] = *(const bf16x8*)&lds[3][(no16 + i) * 512 + l * 8];
    }
#pragma unroll
    for (int i = 0; i < 4; i++)
#pragma unroll
      for (int jj = 0; jj < 4; jj++) {
        acc[i][jj] = MFMA_BF16(ah[i], bh[jj], acc[i][jj]);
        acc[i][jj] = MFMA_BF16(ah[i], bl[jj], acc[i][jj]);
        acc[i][jj] = MFMA_BF16(al[i], bh[jj], acc[i][jj]);
      }
    __syncthreads();
  }

  int mo = (w & 1) * 64, no = (w >> 1) * 64;
  float sc[4], bs[4];
#pragma unroll
  for (int jj = 0; jj < 4; jj++) {
    int o = o0 + no + 16 * jj + c16;
    sc[jj] = j.scale[o];
    bs[jj] = j.bias[o];
  }
#pragma unroll
  for (int i = 0; i < 4; i++) {
    int nrow = m0 + mo + 16 * i + 4 * q;
#pragma unroll
    for (int jj = 0; jj < 4; jj++) {
      int o = o0 + no + 16 * jj + c16;
#pragma unroll
      for (int r = 0; r < 4; r++) {
        float y = acc[i][jj][r] * sc[jj] + bs[jj];
        y = fmaxf(y, 0.f);
        size_t idx = (size_t)(nrow + r) * CH + o;
        if (j.mode == 2) {
          j.Yf[idx] = y;
        } else if (j.mode == 1) {
          j.Yh[idx] = (bf16)y;
        } else {
          bf16 h = (bf16)y;
          j.Yh[idx] = h;
          j.Yl[idx] = (bf16)(y - (float)h);
        }
      }
    }
  }
}

// ---------------------------------------------------------------------------
// 64x128-tile split-bf16 conv-GEMM, fp32 out (f_up). Grid 576, LDS 24 KB.
// ---------------------------------------------------------------------------
__global__ __launch_bounds__(256, 4) void conv64(
    const bf16* __restrict__ Ah, const bf16* __restrict__ Al,
    const bf16* __restrict__ Bh, const bf16* __restrict__ Bl,
    const float* __restrict__ scale, const float* __restrict__ bias,
    float* __restrict__ Yf) {
  __shared__ bf16 lds[24 * 512];  // flat frags: [Ah0-3, Al0-3, Bh0-7, Bl0-7]
  int tid = threadIdx.x;
  int w = tid >> 6, l = tid & 63;
  int q = l >> 4, c16 = l & 15;
  int m0 = (blockIdx.x >> 1) * 64;
  int o0 = (blockIdx.x & 1) * 128;

  const floatx4 zero4 = {0.f, 0.f, 0.f, 0.f};
  floatx4 acc[4][2];
#pragma unroll
  for (int i = 0; i < 4; i++) { acc[i][0] = zero4; acc[i][1] = zero4; }

  for (int k0 = 0; k0 < CH; k0 += 32) {
#pragma unroll
    for (int ff = 0; ff < 6; ff++) {
      int f = w * 6 + ff;
      const bf16* src; int rbase, fl;
      if (f < 4)       { src = Ah; rbase = m0; fl = f; }
      else if (f < 8)  { src = Al; rbase = m0; fl = f - 4; }
      else if (f < 16) { src = Bh; rbase = o0; fl = f - 8; }
      else             { src = Bl; rbase = o0; fl = f - 16; }
      async16(&lds[f * 512], src + (size_t)(rbase + fl * 16 + c16) * CH + k0 + q * 8);
    }
    __syncthreads();

    bf16x8 ah[4], al[4], bh[2], bl[2];
#pragma unroll
    for (int i = 0; i < 4; i++) {
      ah[i] = *(const bf16x8*)&lds[(0 + i) * 512 + l * 8];
      al[i] = *(const bf16x8*)&lds[(4 + i) * 512 + l * 8];
    }
#pragma unroll
    for (int n = 0; n < 2; n++) {
      bh[n] = *(const bf16x8*)&lds[(8 + 2 * w + n) * 512 + l * 8];
      bl[n] = *(const bf16x8*)&lds[(16 + 2 * w + n) * 512 + l * 8];
    }
#pragma unroll
    for (int i = 0; i < 4; i++)
#pragma unroll
      for (int n = 0; n < 2; n++) {
        acc[i][n] = MFMA_BF16(ah[i], bh[n], acc[i][n]);
        acc[i][n] = MFMA_BF16(ah[i], bl[n], acc[i][n]);
        acc[i][n] = MFMA_BF16(al[i], bh[n], acc[i][n]);
      }
    __syncthreads();
  }

  float sc[2], bs[2];
#pragma unroll
  for (int n = 0; n < 2; n++) {
    int o = o0 + 32 * w + 16 * n + c16;
    sc[n] = scale[o];
    bs[n] = bias[o];
  }
#pragma unroll
  for (int i = 0; i < 4; i++) {
    int nrow = m0 + 16 * i + 4 * q;
#pragma unroll
    for (int n = 0; n < 2; n++) {
      int o = o0 + 32 * w + 16 * n + c16;
#pragma unroll
      for (int r = 0; r < 4; r++) {
        float y = acc[i][n][r] * sc[n] + bs[n];
        Yf[(size_t)(nrow + r) * CH + o] = fmaxf(y, 0.f);
      }
    }
  }
}

// ---------------------------------------------------------------------------
// Split-KV flash attention partial, v6 (proven 268us, UNCHANGED in v7).
// BQ=128 (4 waves x 32 q-rows), BKV=32, 32x32x16 MFMAs, in-register P,
// permlane32_swap softmax reduces + P-pack, setprio around MFMA clusters.
// VGPR 128 arch + 128 acc; LDS 64 KB -> 2 blocks/CU; S=3, grid 432.
// ---------------------------------------------------------------------------
__global__ __launch_bounds__(256, 2) void attn_part(
    const bf16* __restrict__ Q, const bf16* __restrict__ K, const bf16* __restrict__ Vt,
    float* __restrict__ Opart, float* __restrict__ Mpart, float* __restrict__ Lpart,
    int niter) {
  __shared__ bf16 lK[2][16 * 512];  // frag ks: K[key=l&31][16ks+8hi+i]
  __shared__ bf16 lV[2][16 * 512];  // frag 2ct+ks2: V[ch=32ct+(l&31)][16ks2+8hi+i]

  int tid = threadIdx.x;
  int w = tid >> 6, l = tid & 63;
  int ql = l & 31, hi = l >> 5;
  int bid = blockIdx.x;
  int qb = bid % NQB2, s = bid / NQB2;
  int b = qb / 72;
  int n0 = (qb % 72) * 128;
  int kv0 = s * niter * 32;
  size_t qkbase = (size_t)b * NPIX * CH;
  size_t vbase  = (size_t)b * CH * NPIX;

  // Q fragments (B-operand 32x32x16): col = q-row = ql, k = 8hi+i per 16-ch step
  bf16x8 qf[16];
  {
    const bf16* qp = Q + qkbase + (size_t)(n0 + 32 * w + ql) * CH + 8 * hi;
#pragma unroll
    for (int ks = 0; ks < 16; ks++) qf[ks] = *(const bf16x8*)(qp + ks * 16);
  }

  floatx16 oacc[8];  // [ct]: O[q=(r&3)+8(r>>2)+4hi][ch=32ct+ql]
#pragma unroll
  for (int ct = 0; ct < 8; ct++)
#pragma unroll
    for (int r = 0; r < 16; r++) oacc[ct][r] = 0.f;
  float mrow = -1e30f, lrow = 0.f;

  const bf16* gK = K + qkbase + (size_t)kv0 * CH;
  const bf16* gV = Vt + vbase + kv0;

  // wave w stages K frags 4w..4w+3 and V frags 4w..4w+3 (8 async16/iter)
  auto stage = [&](int bi) {
#pragma unroll
    for (int ff = 0; ff < 4; ff++) {
      int f = 4 * w + ff;
      async16(&lK[bi][f * 512], gK + (size_t)ql * CH + f * 16 + 8 * hi);
      async16(&lV[bi][f * 512],
              gV + (size_t)((f >> 1) * 32 + ql) * NPIX + (f & 1) * 16 + 8 * hi);
    }
  };

  stage(0);

  for (int it = 0; it < niter; it++) {
    int cur = it & 1;
    __syncthreads();  // buffers `cur` ready (vmcnt drained); prev reads retired

    if (it + 1 < niter) {
      gK += 32 * CH; gV += 32;
      stage(cur ^ 1);
    }

    // S^T = K Q^T : D[key][q], two independent accumulator chains
    floatx16 sfA, sfB;
#pragma unroll
    for (int r = 0; r < 16; r++) { sfA[r] = 0.f; sfB[r] = 0.f; }
    __builtin_amdgcn_s_setprio(1);
#pragma unroll
    for (int ks = 0; ks < 16; ks += 2) {
      bf16x8 kf0 = *(const bf16x8*)&lK[cur][(ks + 0) * 512 + l * 8];
      bf16x8 kf1 = *(const bf16x8*)&lK[cur][(ks + 1) * 512 + l * 8];
      sfA = MFMA32(kf0, qf[ks + 0], sfA);
      sfB = MFMA32(kf1, qf[ks + 1], sfB);
    }
    __builtin_amdgcn_s_setprio(0);
    // combine + tile max for this lane's q-row (other 16 keys live in lane^32)
    float pm = -1e30f;
#pragma unroll
    for (int r = 0; r < 16; r++) {
      float sv = sfA[r] + sfB[r];
      sfA[r] = sv;
      pm = fmaxf(pm, sv);
    }
    pm = xmax32(pm);

    // defer-max: rescale only when row max grew by > 8
    bool need = pm > mrow + 8.f;
    if (__ballot((int)need) != 0ull) {
      float mn = fmaxf(mrow, pm);
      float alpha = __expf(mrow - mn);
      mrow = mn;
      lrow *= alpha;
      float arow[16];
#pragma unroll
      for (int r = 0; r < 16; r++)
        arow[r] = __shfl(alpha, (r & 3) + 8 * (r >> 2) + 4 * hi);
#pragma unroll
      for (int ct = 0; ct < 8; ct++)
#pragma unroll
        for (int r = 0; r < 16; r++) oacc[ct][r] *= arow[r];
    }

    // P = exp(S - m) (all 16 values belong to this lane's own q-row)
    float p[16];
    float rs = 0.f;
#pragma unroll
    for (int r = 0; r < 16; r++) {
      p[r] = __expf(sfA[r] - mrow);
      rs += p[r];
    }
    lrow += xsum32(rs);

    // pack to PV A-frags: reg r holds key (r&3)+8(r>>2)+4hi
    unsigned pk0 = cvtpk(p[0], p[1]),   pk1 = cvtpk(p[2], p[3]);
    unsigned pk2 = cvtpk(p[4], p[5]),   pk3 = cvtpk(p[6], p[7]);
    unsigned pk4 = cvtpk(p[8], p[9]),   pk5 = cvtpk(p[10], p[11]);
    unsigned pk6 = cvtpk(p[12], p[13]), pk7 = cvtpk(p[14], p[15]);
    plswap(pk0, pk2); plswap(pk1, pk3);
    plswap(pk4, pk6); plswap(pk5, pk7);
    uint4 u0, u1;
    u0.x = pk0; u0.y = pk1; u0.z = pk2; u0.w = pk3;  // keys 0..15, k = 8hi+i
    u1.x = pk4; u1.y = pk5; u1.z = pk6; u1.w = pk7;  // keys 16..31
    bf16x8 pa0 = __builtin_bit_cast(bf16x8, u0);
    bf16x8 pa1 = __builtin_bit_cast(bf16x8, u1);

    // PV: O[q][ch] += P[q][k] V[k][ch]
    __builtin_amdgcn_s_setprio(1);
#pragma unroll
    for (int ct = 0; ct < 8; ct++) {
      bf16x8 vb0 = *(const bf16x8*)&lV[cur][(2 * ct + 0) * 512 + l * 8];
      bf16x8 vb1 = *(const bf16x8*)&lV[cur][(2 * ct + 1) * 512 + l * 8];
      oacc[ct] = MFMA32(pa0, vb0, oacc[ct]);
      oacc[ct] = MFMA32(pa1, vb1, oacc[ct]);
    }
    __builtin_amdgcn_s_setprio(0);
  }

  // write partials (unnormalized O + m, l)
  if (hi == 0) {
    Mpart[(size_t)bid * 128 + 32 * w + ql] = mrow;
    Lpart[(size_t)bid * 128 + 32 * w + ql] = lrow;
  }
  float* Ob = Opart + (size_t)bid * 128 * CH;
#pragma unroll
  for (int ct = 0; ct < 8; ct++)
#pragma unroll
    for (int r = 0; r < 16; r++) {
      int row = 32 * w + (r & 3) + 8 * (r >> 2) + 4 * hi;
      Ob[(size_t)row * CH + 32 * ct + ql] = oacc[ct][r];
    }
}

// ---------------------------------------------------------------------------
// Combine S partials -> normalized O, split hi/lo bf16, n-major [MTOT][256]
// v7: grid NQB2*4 = 576 blocks x 32-row quarters (v6's 144x128-row form was
// latency-bound: 1 block/CU on 56% of CUs, 128 serial dependent HBM loads).
// 576 blocks -> 2.25 blocks/CU, 4x shorter row loop; loads overlap across
// co-resident blocks.
// ---------------------------------------------------------------------------
__global__ __launch_bounds__(256) void attn_combine(
    const float* __restrict__ Opart, const float* __restrict__ Mpart,
    const float* __restrict__ Lpart,
    bf16* __restrict__ Oh, bf16* __restrict__ Ol, int S) {
  __shared__ float wgt[8][32];
  __shared__ float invl[32];
  int qb = blockIdx.x >> 2;
  int r0 = (blockIdx.x & 3) * 32;
  int t = threadIdx.x;
  if (t < 32) {
    int row = r0 + t;
    float m = -1e30f;
    for (int s = 0; s < S; s++)
      m = fmaxf(m, Mpart[(size_t)(s * NQB2 + qb) * 128 + row]);
    float lsum = 0.f;
    for (int s = 0; s < S; s++) {
      float wv = __expf(Mpart[(size_t)(s * NQB2 + qb) * 128 + row] - m);
      wgt[s][t] = wv;
      lsum += wv * Lpart[(size_t)(s * NQB2 + qb) * 128 + row];
    }
    invl[t] = 1.0f / lsum;
  }
  __syncthreads();
  int c = t;  // 256 threads = 256 channels
  for (int rr = 0; rr < 32; rr++) {
    int row = r0 + rr;
    float acc = 0.f;
    for (int s = 0; s < S; s++)
      acc += wgt[s][rr] * Opart[((size_t)(s * NQB2 + qb) * 128 + row) * CH + c];
    float y = acc * invl[rr];
    size_t idx = (size_t)(qb * 128 + row) * CH + c;
    bf16 h = (bf16)y;
    Oh[idx] = h;
    Ol[idx] = (bf16)(y - (float)h);
  }
}

// ---------------------------------------------------------------------------
extern "C" void kernel_launch(void* const* d_in, const int* in_sizes, int n_in,
                              void* d_out, int out_size, void* d_ws, size_t ws_size,
                              hipStream_t stream) {
  const float* x  = (const float*)d_in[0];
  const float* fk = (const float*)d_in[1];
  const float* Ws = (const float*)d_in[2];
  const float* g  = (const float*)d_in[3];
  const float* be = (const float*)d_in[4];
  const float* me = (const float*)d_in[5];
  const float* va = (const float*)d_in[6];
  float* out = (float*)d_out;

  char* p = (char*)d_ws;
  bf16* Wh = (bf16*)p; p += (size_t)6 * CH * CH * 2;
  bf16* Wl = (bf16*)p; p += (size_t)6 * CH * CH * 2;
  float* scale = (float*)p; p += (size_t)6 * CH * 4;
  float* bias  = (float*)p; p += (size_t)6 * CH * 4;
  size_t plane = (size_t)MTOT * CH * 2;  // 9,437,184 B per bf16 plane
  bf16* S0h = (bf16*)p; p += plane;
  bf16* S0l = (bf16*)p; p += plane;
  bf16* Qh  = (bf16*)p; p += plane;
  bf16* Kh  = (bf16*)p; p += plane;
  bf16* Vh  = (bf16*)p; p += plane;
  bf16* Vt  = (bf16*)p; p += plane;
  char* region = p;

  // Overlays inside `region` (all dead before attn_part writes Opart there):
  bf16* S2h = (bf16*)(region);              // fk transposed (hi)
  bf16* S2l = (bf16*)(region + plane);      // fk transposed (lo)
  bf16* P1h = (bf16*)(region + 2 * plane);  // psi1 out (hi)
  bf16* P1l = (bf16*)(region + 3 * plane);  // psi1 out (lo)
  bf16* F1h = (bf16*)(region + 4 * plane);  // phi1 out (hi)
  bf16* F1l = (bf16*)(region + 5 * plane);  // phi1 out (lo)

  size_t base_used = (size_t)(region - (char*)d_ws);
  size_t osz = (size_t)NQB2 * 128 * CH * 4;           // 18.9 MB per split
  size_t per_split = osz + 2 * (size_t)NQB2 * 128 * 4;
  long avail = (long)ws_size - (long)base_used;
  int S = 1;
  {
    // S=3 -> grid 432 fully co-resident at 2 blocks/CU; 288 % S == 0 required
    int cand[3] = {3, 2, 1};
    for (int i = 0; i < 3; i++)
      if ((long)cand[i] * (long)per_split <= avail) { S = cand[i]; break; }
  }
  float* Opart = (float*)region;
  float* Mpart = (float*)(region + (size_t)S * osz);
  float* Lpart = Mpart + (size_t)S * NQB2 * 128;
  float* Y5 = (float*)region;  // f_up fp32 out, overlays Opart (dead after combine)

  (void)in_sizes; (void)n_in; (void)out_size;

  prep_weights<<<1536, 256, 0, stream>>>(Ws, g, be, me, va, Wh, Wl, scale, bias);
  split_transpose2<<<2304, 256, 0, stream>>>(x, fk, S0h, S0l, S2h, S2l);

  auto W = [&](int layer) { return Wh + (size_t)layer * CH * CH; };
  auto Wlo = [&](int layer) { return Wl + (size_t)layer * CH * CH; };

  ConvJob psi1  {S0h, S0l, W(0), Wlo(0), scale + 0 * CH, bias + 0 * CH, P1h, P1l, nullptr, 0};
  ConvJob phi1  {S2h, S2l, W(2), Wlo(2), scale + 2 * CH, bias + 2 * CH, F1h, F1l, nullptr, 0};
  ConvJob fdown {S2h, S2l, W(4), Wlo(4), scale + 4 * CH, bias + 4 * CH, Vh, nullptr, nullptr, 1};
  ConvJob psi2  {P1h, P1l, W(1), Wlo(1), scale + 1 * CH, bias + 1 * CH, Qh, nullptr, nullptr, 1};
  ConvJob phi2  {F1h, F1l, W(3), Wlo(3), scale + 3 * CH, bias + 3 * CH, Kh, nullptr, nullptr, 1};

  conv128<<<864, 256, 0, stream>>>(psi1, phi1, fdown);
  conv128<<<576, 256, 0, stream>>>(psi2, phi2, phi2);
  transpose_bf16<<<1152, 256, 0, stream>>>(Vh, Vt);
  attn_part<<<NQB2 * S, 256, 0, stream>>>(Qh, Kh, Vt, Opart, Mpart, Lpart, 288 / S);
  attn_combine<<<NQB2 * 4, 256, 0, stream>>>(Opart, Mpart, Lpart, S0h, S0l, S);
  conv64<<<576, 256, 0, stream>>>(S0h, S0l, W(5), Wlo(5), scale + 5 * CH, bias + 5 * CH, Y5);
  transpose_out<<<1152, 256, 0, stream>>>(Y5, out);
}

// Round 17
// 466.766 us; speedup vs baseline: 4.7926x; 1.0357x over previous
//
#include <hip/hip_runtime.h>
#include <hip/hip_bf16.h>

typedef __bf16 bf16;
typedef __bf16 bf16x8 __attribute__((ext_vector_type(8)));
typedef float floatx4 __attribute__((ext_vector_type(4)));
typedef float floatx16 __attribute__((ext_vector_type(16)));

#define MFMA_BF16(a, b, c) __builtin_amdgcn_mfma_f32_16x16x32_bf16((a), (b), (c), 0, 0, 0)
#define MFMA32(a, b, c) __builtin_amdgcn_mfma_f32_32x32x16_bf16((a), (b), (c), 0, 0, 0)

static constexpr int CH = 256;      // channels
static constexpr int NPIX = 9216;   // 96*96
static constexpr int MTOT = 2 * NPIX; // both batches, n-major rows
static constexpr int NQB2 = 144;    // 128-row attention q-blocks total (2 batches)

// async global->LDS, 16B per lane; LDS dest = wave-uniform base + lane*16
__device__ __forceinline__ void async16(void* lds, const void* g) {
  __builtin_amdgcn_global_load_lds(
      (const __attribute__((address_space(1))) void*)g,
      (__attribute__((address_space(3))) void*)lds, 16, 0, 0);
}

// pack two f32 -> one u32 of 2 bf16 (lo = first arg)
__device__ __forceinline__ unsigned cvtpk(float lo, float hi) {
  unsigned r;
  asm("v_cvt_pk_bf16_f32 %0, %1, %2" : "=v"(r) : "v"(lo), "v"(hi));
  return r;
}

// v_permlane32_swap_b32 a, b  (VALU, gfx950, correctness-verified in v5/v6 runs):
//   a'[0:31]=a[0:31], a'[32:63]=b[0:31]; b'[0:31]=a[32:63], b'[32:63]=b[32:63]
__device__ __forceinline__ void plswap(unsigned& a, unsigned& b) {
  asm volatile("v_permlane32_swap_b32 %0, %1" : "+v"(a), "+v"(b));
}
// max/sum with lane^32 partner via permlane (VALU ~4cy vs ds_bpermute ~120cy)
__device__ __forceinline__ float xmax32(float v) {
  unsigned a = __builtin_bit_cast(unsigned, v), b = a;
  plswap(a, b);
  return fmaxf(__builtin_bit_cast(float, a), __builtin_bit_cast(float, b));
}
__device__ __forceinline__ float xsum32(float v) {
  unsigned a = __builtin_bit_cast(unsigned, v), b = a;
  plswap(a, b);
  return __builtin_bit_cast(float, a) + __builtin_bit_cast(float, b);
}

// ---------------------------------------------------------------------------
// Weight split (fp32 -> bf16 hi/lo) + folded BN scale/bias
// ---------------------------------------------------------------------------
__global__ void prep_weights(const float* __restrict__ W,
                             const float* __restrict__ g, const float* __restrict__ b,
                             const float* __restrict__ m, const float* __restrict__ v,
                             bf16* __restrict__ Wh, bf16* __restrict__ Wl,
                             float* __restrict__ scale, float* __restrict__ bias) {
  int i = blockIdx.x * 256 + threadIdx.x;
  if (i < 6 * CH * CH) {
    float w = W[i];
    bf16 h = (bf16)w;
    Wh[i] = h;
    Wl[i] = (bf16)(w - (float)h);
  }
  if (i < 6 * CH) {
    float s = g[i] * rsqrtf(v[i] + 1e-5f);
    scale[i] = s;
    bias[i] = b[i] - m[i] * s;
  }
}

// ---------------------------------------------------------------------------
// Both inputs: fp32 [B][256][9216] (c-major) -> bf16 hi/lo [B*9216][256]
// bid < 1152 -> x, else fk
// ---------------------------------------------------------------------------
__global__ void split_transpose2(const float* __restrict__ xin, const float* __restrict__ fkin,
                                 bf16* __restrict__ ohx, bf16* __restrict__ olx,
                                 bf16* __restrict__ ohf, bf16* __restrict__ olf) {
  __shared__ float t[64][65];
  int bid = blockIdx.x;
  const float* in; bf16 *oh, *ol;
  if (bid >= 1152) { in = fkin; oh = ohf; ol = olf; bid -= 1152; }
  else             { in = xin;  oh = ohx; ol = olx; }
  int b = bid / 576, rem = bid % 576;
  int ct = rem / 144, nt = rem % 144;
  int c0 = ct * 64, n0 = nt * 64;
  int tid = threadIdx.x;
  int cr = tid >> 4, nc = (tid & 15) * 4;
  for (int rr = 0; rr < 64; rr += 16) {
    int c = cr + rr;
    const float* p = in + ((size_t)(b * CH + c0 + c) * NPIX) + n0 + nc;
    float4 val = *(const float4*)p;
    t[c][nc + 0] = val.x; t[c][nc + 1] = val.y;
    t[c][nc + 2] = val.z; t[c][nc + 3] = val.w;
  }
  __syncthreads();
  int n = tid >> 2, cb = (tid & 3) * 16;
  bf16 hb[16], lb[16];
#pragma unroll
  for (int j = 0; j < 16; j++) {
    float xv = t[cb + j][n];
    bf16 h = (bf16)xv;
    hb[j] = h;
    lb[j] = (bf16)(xv - (float)h);
  }
  size_t idx = (size_t)(b * NPIX + n0 + n) * CH + c0 + cb;
  *(bf16x8*)&oh[idx]     = *(bf16x8*)&hb[0];
  *(bf16x8*)&oh[idx + 8] = *(bf16x8*)&hb[8];
  *(bf16x8*)&ol[idx]     = *(bf16x8*)&lb[0];
  *(bf16x8*)&ol[idx + 8] = *(bf16x8*)&lb[8];
}

// ---------------------------------------------------------------------------
// Batched split-bf16 conv-GEMM, 128x128 tiles (288 blocks per job).
// mode: 0 = write hi+lo bf16, 1 = hi only, 2 = fp32,
//       3 = bf16 TRANSPOSED to c-major [B][256][9216] (fused transpose_bf16;
//           2-pass 64ch x 128row LDS tile, pad 136 for 16B-aligned b128 reads)
// ---------------------------------------------------------------------------
struct ConvJob {
  const bf16 *Ah, *Al, *Bh, *Bl;
  const float *scale, *bias;
  bf16 *Yh, *Yl; float *Yf;
  int mode;
};

__global__ __launch_bounds__(256, 3) void conv128(ConvJob j0, ConvJob j1, ConvJob j2) {
  __shared__ bf16 lds[4][8 * 512];  // planes: Ah, Al, Bh, Bl
  int jid = blockIdx.x / 288;
  int bid = blockIdx.x % 288;
  ConvJob j = (jid == 0) ? j0 : (jid == 1) ? j1 : j2;

  int tid = threadIdx.x;
  int w = tid >> 6, l = tid & 63;
  int q = l >> 4, c16 = l & 15;
  int m0 = (bid >> 1) * 128;
  int o0 = (bid & 1) * 128;

  const bf16* src = (w == 0) ? j.Ah : (w == 1) ? j.Al : (w == 2) ? j.Bh : j.Bl;
  int rowbase = (w < 2) ? m0 : o0;
  const bf16* gp = src + (size_t)(rowbase + c16) * CH + q * 8;
  bf16* ldst = &lds[w][0];

  const floatx4 zero4 = {0.f, 0.f, 0.f, 0.f};
  floatx4 acc[4][4];
#pragma unroll
  for (int i = 0; i < 4; i++)
#pragma unroll
    for (int jj = 0; jj < 4; jj++) acc[i][jj] = zero4;

  int mo16 = (w & 1) * 4, no16 = (w >> 1) * 4;

  for (int k0 = 0; k0 < CH; k0 += 32) {
#pragma unroll
    for (int f = 0; f < 8; f++)
      async16(ldst + f * 512, gp + (size_t)f * 16 * CH + k0);
    __syncthreads();

    bf16x8 ah[4], al[4], bh[4], bl[4];
#pragma unroll
    for (int i = 0; i < 4; i++) {
      ah[i] = *(const bf16x8*)&lds[0][(mo16 + i) * 512 + l * 8];
      al[i] = *(const bf16x8*)&lds[1][(mo16 + i) * 512 + l * 8];
      bh[i] = *(const bf16x8*)&lds[2][(no16 + i) * 512 + l * 8];
      bl[i] = *(const bf16x8*)&lds[3][(no16 + i) * 512 + l * 8];
    }
#pragma unroll
    for (int i = 0; i < 4; i++)
#pragma unroll
      for (int jj = 0; jj < 4; jj++) {
        acc[i][jj] = MFMA_BF16(ah[i], bh[jj], acc[i][jj]);
        acc[i][jj] = MFMA_BF16(ah[i], bl[jj], acc[i][jj]);
        acc[i][jj] = MFMA_BF16(al[i], bh[jj], acc[i][jj]);
      }
    __syncthreads();
  }

  int mo = (w & 1) * 64, no = (w >> 1) * 64;
  float sc[4], bs[4];
#pragma unroll
  for (int jj = 0; jj < 4; jj++) {
    int o = o0 + no + 16 * jj + c16;
    sc[jj] = j.scale[o];
    bs[jj] = j.bias[o];
  }

  if (j.mode == 3) {
    // fused transpose: write Yh as c-major [b][ch][pixel]
    bf16* tile = &lds[0][0];  // [64][136] bf16, 8704 elems <= 16384
    int b2 = (m0 >= NPIX) ? 1 : 0;
    int nr0 = m0 - b2 * NPIX;
#pragma unroll
    for (int hc = 0; hc < 2; hc++) {
      __syncthreads();
      if ((w >> 1) == hc) {
#pragma unroll
        for (int i = 0; i < 4; i++)
#pragma unroll
          for (int jj = 0; jj < 4; jj++)
#pragma unroll
            for (int r = 0; r < 4; r++) {
              float y = acc[i][jj][r] * sc[jj] + bs[jj];
              y = fmaxf(y, 0.f);
              int chl = no + 16 * jj + c16 - hc * 64;  // 0..63
              int rowl = mo + 16 * i + 4 * q + r;      // 0..127
              tile[chl * 136 + rowl] = (bf16)y;
            }
      }
      __syncthreads();
      int chl = tid >> 2, rseg = (tid & 3) * 32;
      bf16* dst = j.Yh + ((size_t)(b2 * CH + o0 + hc * 64 + chl)) * NPIX + nr0 + rseg;
#pragma unroll
      for (int k = 0; k < 4; k++)
        *(bf16x8*)(dst + 8 * k) = *(bf16x8*)&tile[chl * 136 + rseg + 8 * k];
    }
    return;
  }

#pragma unroll
  for (int i = 0; i < 4; i++) {
    int nrow = m0 + mo + 16 * i + 4 * q;
#pragma unroll
    for (int jj = 0; jj < 4; jj++) {
      int o = o0 + no + 16 * jj + c16;
#pragma unroll
      for (int r = 0; r < 4; r++) {
        float y = acc[i][jj][r] * sc[jj] + bs[jj];
        y = fmaxf(y, 0.f);
        size_t idx = (size_t)(nrow + r) * CH + o;
        if (j.mode == 2) {
          j.Yf[idx] = y;
        } else if (j.mode == 1) {
          j.Yh[idx] = (bf16)y;
        } else {
          bf16 h = (bf16)y;
          j.Yh[idx] = h;
          j.Yl[idx] = (bf16)(y - (float)h);
        }
      }
    }
  }
}

// ---------------------------------------------------------------------------
// 64x128-tile split-bf16 conv-GEMM, fp32 out (f_up), FUSED transposed write
// to final output [B][256][9216] (was: write n-major Y5 + transpose_out).
// 2-pass 64ch x 64row fp32 LDS tile [64][68] = 17.4 KB (reuses 24 KB lds).
// ---------------------------------------------------------------------------
__global__ __launch_bounds__(256, 4) void conv64(
    const bf16* __restrict__ Ah, const bf16* __restrict__ Al,
    const bf16* __restrict__ Bh, const bf16* __restrict__ Bl,
    const float* __restrict__ scale, const float* __restrict__ bias,
    float* __restrict__ Yf) {
  __shared__ bf16 lds[24 * 512];  // flat frags: [Ah0-3, Al0-3, Bh0-7, Bl0-7]
  int tid = threadIdx.x;
  int w = tid >> 6, l = tid & 63;
  int q = l >> 4, c16 = l & 15;
  int m0 = (blockIdx.x >> 1) * 64;
  int o0 = (blockIdx.x & 1) * 128;

  const floatx4 zero4 = {0.f, 0.f, 0.f, 0.f};
  floatx4 acc[4][2];
#pragma unroll
  for (int i = 0; i < 4; i++) { acc[i][0] = zero4; acc[i][1] = zero4; }

  for (int k0 = 0; k0 < CH; k0 += 32) {
#pragma unroll
    for (int ff = 0; ff < 6; ff++) {
      int f = w * 6 + ff;
      const bf16* src; int rbase, fl;
      if (f < 4)       { src = Ah; rbase = m0; fl = f; }
      else if (f < 8)  { src = Al; rbase = m0; fl = f - 4; }
      else if (f < 16) { src = Bh; rbase = o0; fl = f - 8; }
      else             { src = Bl; rbase = o0; fl = f - 16; }
      async16(&lds[f * 512], src + (size_t)(rbase + fl * 16 + c16) * CH + k0 + q * 8);
    }
    __syncthreads();

    bf16x8 ah[4], al[4], bh[2], bl[2];
#pragma unroll
    for (int i = 0; i < 4; i++) {
      ah[i] = *(const bf16x8*)&lds[(0 + i) * 512 + l * 8];
      al[i] = *(const bf16x8*)&lds[(4 + i) * 512 + l * 8];
    }
#pragma unroll
    for (int n = 0; n < 2; n++) {
      bh[n] = *(const bf16x8*)&lds[(8 + 2 * w + n) * 512 + l * 8];
      bl[n] = *(const bf16x8*)&lds[(16 + 2 * w + n) * 512 + l * 8];
    }
#pragma unroll
    for (int i = 0; i < 4; i++)
#pragma unroll
      for (int n = 0; n < 2; n++) {
        acc[i][n] = MFMA_BF16(ah[i], bh[n], acc[i][n]);
        acc[i][n] = MFMA_BF16(ah[i], bl[n], acc[i][n]);
        acc[i][n] = MFMA_BF16(al[i], bh[n], acc[i][n]);
      }
    __syncthreads();
  }

  float sc[2], bs[2];
#pragma unroll
  for (int n = 0; n < 2; n++) {
    int o = o0 + 32 * w + 16 * n + c16;
    sc[n] = scale[o];
    bs[n] = bias[o];
  }

  float* tile = (float*)&lds[0];  // [64][68] fp32, 17408 B <= 24576
  int b2 = (m0 >= NPIX) ? 1 : 0;
  int nr0 = m0 - b2 * NPIX;
#pragma unroll
  for (int hc = 0; hc < 2; hc++) {
    __syncthreads();
    if ((w >> 1) == hc) {
#pragma unroll
      for (int i = 0; i < 4; i++)
#pragma unroll
        for (int n = 0; n < 2; n++)
#pragma unroll
          for (int r = 0; r < 4; r++) {
            float y = acc[i][n][r] * sc[n] + bs[n];
            y = fmaxf(y, 0.f);
            int chl = 32 * (w - 2 * hc) + 16 * n + c16;  // 0..63
            int rowl = 16 * i + 4 * q + r;               // 0..63
            tile[chl * 68 + rowl] = y;
          }
    }
    __syncthreads();
    int chl = tid >> 2, rseg = (tid & 3) * 16;
    float* dst = Yf + ((size_t)(b2 * CH + o0 + hc * 64 + chl)) * NPIX + nr0 + rseg;
#pragma unroll
    for (int k = 0; k < 4; k++)
      *(float4*)(dst + 4 * k) = *(float4*)&tile[chl * 68 + rseg + 4 * k];
  }
}

// ---------------------------------------------------------------------------
// Split-KV flash attention partial, v6 (proven 268us, UNCHANGED).
// BQ=128 (4 waves x 32 q-rows), BKV=32, 32x32x16 MFMAs, in-register P,
// permlane32_swap softmax reduces + P-pack, setprio around MFMA clusters.
// VGPR 128 arch + 128 acc; LDS 64 KB -> 2 blocks/CU; S=3, grid 432.
// ---------------------------------------------------------------------------
__global__ __launch_bounds__(256, 2) void attn_part(
    const bf16* __restrict__ Q, const bf16* __restrict__ K, const bf16* __restrict__ Vt,
    float* __restrict__ Opart, float* __restrict__ Mpart, float* __restrict__ Lpart,
    int niter) {
  __shared__ bf16 lK[2][16 * 512];  // frag ks: K[key=l&31][16ks+8hi+i]
  __shared__ bf16 lV[2][16 * 512];  // frag 2ct+ks2: V[ch=32ct+(l&31)][16ks2+8hi+i]

  int tid = threadIdx.x;
  int w = tid >> 6, l = tid & 63;
  int ql = l & 31, hi = l >> 5;
  int bid = blockIdx.x;
  int qb = bid % NQB2, s = bid / NQB2;
  int b = qb / 72;
  int n0 = (qb % 72) * 128;
  int kv0 = s * niter * 32;
  size_t qkbase = (size_t)b * NPIX * CH;
  size_t vbase  = (size_t)b * CH * NPIX;

  // Q fragments (B-operand 32x32x16): col = q-row = ql, k = 8hi+i per 16-ch step
  bf16x8 qf[16];
  {
    const bf16* qp = Q + qkbase + (size_t)(n0 + 32 * w + ql) * CH + 8 * hi;
#pragma unroll
    for (int ks = 0; ks < 16; ks++) qf[ks] = *(const bf16x8*)(qp + ks * 16);
  }

  floatx16 oacc[8];  // [ct]: O[q=(r&3)+8(r>>2)+4hi][ch=32ct+ql]
#pragma unroll
  for (int ct = 0; ct < 8; ct++)
#pragma unroll
    for (int r = 0; r < 16; r++) oacc[ct][r] = 0.f;
  float mrow = -1e30f, lrow = 0.f;

  const bf16* gK = K + qkbase + (size_t)kv0 * CH;
  const bf16* gV = Vt + vbase + kv0;

  // wave w stages K frags 4w..4w+3 and V frags 4w..4w+3 (8 async16/iter)
  auto stage = [&](int bi) {
#pragma unroll
    for (int ff = 0; ff < 4; ff++) {
      int f = 4 * w + ff;
      async16(&lK[bi][f * 512], gK + (size_t)ql * CH + f * 16 + 8 * hi);
      async16(&lV[bi][f * 512],
              gV + (size_t)((f >> 1) * 32 + ql) * NPIX + (f & 1) * 16 + 8 * hi);
    }
  };

  stage(0);

  for (int it = 0; it < niter; it++) {
    int cur = it & 1;
    __syncthreads();  // buffers `cur` ready (vmcnt drained); prev reads retired

    if (it + 1 < niter) {
      gK += 32 * CH; gV += 32;
      stage(cur ^ 1);
    }

    // S^T = K Q^T : D[key][q], two independent accumulator chains
    floatx16 sfA, sfB;
#pragma unroll
    for (int r = 0; r < 16; r++) { sfA[r] = 0.f; sfB[r] = 0.f; }
    __builtin_amdgcn_s_setprio(1);
#pragma unroll
    for (int ks = 0; ks < 16; ks += 2) {
      bf16x8 kf0 = *(const bf16x8*)&lK[cur][(ks + 0) * 512 + l * 8];
      bf16x8 kf1 = *(const bf16x8*)&lK[cur][(ks + 1) * 512 + l * 8];
      sfA = MFMA32(kf0, qf[ks + 0], sfA);
      sfB = MFMA32(kf1, qf[ks + 1], sfB);
    }
    __builtin_amdgcn_s_setprio(0);
    // combine + tile max for this lane's q-row (other 16 keys live in lane^32)
    float pm = -1e30f;
#pragma unroll
    for (int r = 0; r < 16; r++) {
      float sv = sfA[r] + sfB[r];
      sfA[r] = sv;
      pm = fmaxf(pm, sv);
    }
    pm = xmax32(pm);

    // defer-max: rescale only when row max grew by > 8
    bool need = pm > mrow + 8.f;
    if (__ballot((int)need) != 0ull) {
      float mn = fmaxf(mrow, pm);
      float alpha = __expf(mrow - mn);
      mrow = mn;
      lrow *= alpha;
      float arow[16];
#pragma unroll
      for (int r = 0; r < 16; r++)
        arow[r] = __shfl(alpha, (r & 3) + 8 * (r >> 2) + 4 * hi);
#pragma unroll
      for (int ct = 0; ct < 8; ct++)
#pragma unroll
        for (int r = 0; r < 16; r++) oacc[ct][r] *= arow[r];
    }

    // P = exp(S - m) (all 16 values belong to this lane's own q-row)
    float p[16];
    float rs = 0.f;
#pragma unroll
    for (int r = 0; r < 16; r++) {
      p[r] = __expf(sfA[r] - mrow);
      rs += p[r];
    }
    lrow += xsum32(rs);

    // pack to PV A-frags: reg r holds key (r&3)+8(r>>2)+4hi
    unsigned pk0 = cvtpk(p[0], p[1]),   pk1 = cvtpk(p[2], p[3]);
    unsigned pk2 = cvtpk(p[4], p[5]),   pk3 = cvtpk(p[6], p[7]);
    unsigned pk4 = cvtpk(p[8], p[9]),   pk5 = cvtpk(p[10], p[11]);
    unsigned pk6 = cvtpk(p[12], p[13]), pk7 = cvtpk(p[14], p[15]);
    plswap(pk0, pk2); plswap(pk1, pk3);
    plswap(pk4, pk6); plswap(pk5, pk7);
    uint4 u0, u1;
    u0.x = pk0; u0.y = pk1; u0.z = pk2; u0.w = pk3;  // keys 0..15, k = 8hi+i
    u1.x = pk4; u1.y = pk5; u1.z = pk6; u1.w = pk7;  // keys 16..31
    bf16x8 pa0 = __builtin_bit_cast(bf16x8, u0);
    bf16x8 pa1 = __builtin_bit_cast(bf16x8, u1);

    // PV: O[q][ch] += P[q][k] V[k][ch]
    __builtin_amdgcn_s_setprio(1);
#pragma unroll
    for (int ct = 0; ct < 8; ct++) {
      bf16x8 vb0 = *(const bf16x8*)&lV[cur][(2 * ct + 0) * 512 + l * 8];
      bf16x8 vb1 = *(const bf16x8*)&lV[cur][(2 * ct + 1) * 512 + l * 8];
      oacc[ct] = MFMA32(pa0, vb0, oacc[ct]);
      oacc[ct] = MFMA32(pa1, vb1, oacc[ct]);
    }
    __builtin_amdgcn_s_setprio(0);
  }

  // write partials (unnormalized O + m, l)
  if (hi == 0) {
    Mpart[(size_t)bid * 128 + 32 * w + ql] = mrow;
    Lpart[(size_t)bid * 128 + 32 * w + ql] = lrow;
  }
  float* Ob = Opart + (size_t)bid * 128 * CH;
#pragma unroll
  for (int ct = 0; ct < 8; ct++)
#pragma unroll
    for (int r = 0; r < 16; r++) {
      int row = 32 * w + (r & 3) + 8 * (r >> 2) + 4 * hi;
      Ob[(size_t)row * CH + 32 * ct + ql] = oacc[ct][r];
    }
}

// ---------------------------------------------------------------------------
// Combine S partials -> normalized O, split hi/lo bf16, n-major [MTOT][256]
// grid NQB2*4 = 576 blocks x 32-row quarters (proven v7 form).
// ---------------------------------------------------------------------------
__global__ __launch_bounds__(256) void attn_combine(
    const float* __restrict__ Opart, const float* __restrict__ Mpart,
    const float* __restrict__ Lpart,
    bf16* __restrict__ Oh, bf16* __restrict__ Ol, int S) {
  __shared__ float wgt[8][32];
  __shared__ float invl[32];
  int qb = blockIdx.x >> 2;
  int r0 = (blockIdx.x & 3) * 32;
  int t = threadIdx.x;
  if (t < 32) {
    int row = r0 + t;
    float m = -1e30f;
    for (int s = 0; s < S; s++)
      m = fmaxf(m, Mpart[(size_t)(s * NQB2 + qb) * 128 + row]);
    float lsum = 0.f;
    for (int s = 0; s < S; s++) {
      float wv = __expf(Mpart[(size_t)(s * NQB2 + qb) * 128 + row] - m);
      wgt[s][t] = wv;
      lsum += wv * Lpart[(size_t)(s * NQB2 + qb) * 128 + row];
    }
    invl[t] = 1.0f / lsum;
  }
  __syncthreads();
  int c = t;  // 256 threads = 256 channels
  for (int rr = 0; rr < 32; rr++) {
    int row = r0 + rr;
    float acc = 0.f;
    for (int s = 0; s < S; s++)
      acc += wgt[s][rr] * Opart[((size_t)(s * NQB2 + qb) * 128 + row) * CH + c];
    float y = acc * invl[rr];
    size_t idx = (size_t)(qb * 128 + row) * CH + c;
    bf16 h = (bf16)y;
    Oh[idx] = h;
    Ol[idx] = (bf16)(y - (float)h);
  }
}

// ---------------------------------------------------------------------------
extern "C" void kernel_launch(void* const* d_in, const int* in_sizes, int n_in,
                              void* d_out, int out_size, void* d_ws, size_t ws_size,
                              hipStream_t stream) {
  const float* x  = (const float*)d_in[0];
  const float* fk = (const float*)d_in[1];
  const float* Ws = (const float*)d_in[2];
  const float* g  = (const float*)d_in[3];
  const float* be = (const float*)d_in[4];
  const float* me = (const float*)d_in[5];
  const float* va = (const float*)d_in[6];
  float* out = (float*)d_out;

  char* p = (char*)d_ws;
  bf16* Wh = (bf16*)p; p += (size_t)6 * CH * CH * 2;
  bf16* Wl = (bf16*)p; p += (size_t)6 * CH * CH * 2;
  float* scale = (float*)p; p += (size_t)6 * CH * 4;
  float* bias  = (float*)p; p += (size_t)6 * CH * 4;
  size_t plane = (size_t)MTOT * CH * 2;  // 9,437,184 B per bf16 plane
  bf16* S0h = (bf16*)p; p += plane;
  bf16* S0l = (bf16*)p; p += plane;
  bf16* Qh  = (bf16*)p; p += plane;
  bf16* Kh  = (bf16*)p; p += plane;
  bf16* Vt  = (bf16*)p; p += plane;   // c-major V, written directly by conv128 mode 3
  char* region = p;

  // Overlays inside `region` (all dead before attn_part writes Opart there):
  bf16* S2h = (bf16*)(region);              // fk transposed (hi)
  bf16* S2l = (bf16*)(region + plane);      // fk transposed (lo)
  bf16* P1h = (bf16*)(region + 2 * plane);  // psi1 out (hi)
  bf16* P1l = (bf16*)(region + 3 * plane);  // psi1 out (lo)
  bf16* F1h = (bf16*)(region + 4 * plane);  // phi1 out (hi)
  bf16* F1l = (bf16*)(region + 5 * plane);  // phi1 out (lo)

  size_t base_used = (size_t)(region - (char*)d_ws);
  size_t osz = (size_t)NQB2 * 128 * CH * 4;           // 18.9 MB per split
  size_t per_split = osz + 2 * (size_t)NQB2 * 128 * 4;
  long avail = (long)ws_size - (long)base_used;
  int S = 1;
  {
    // S=3 -> grid 432 fully co-resident at 2 blocks/CU; 288 % S == 0 required
    int cand[3] = {3, 2, 1};
    for (int i = 0; i < 3; i++)
      if ((long)cand[i] * (long)per_split <= avail) { S = cand[i]; break; }
  }
  float* Opart = (float*)region;
  float* Mpart = (float*)(region + (size_t)S * osz);
  float* Lpart = Mpart + (size_t)S * NQB2 * 128;

  (void)in_sizes; (void)n_in; (void)out_size;

  prep_weights<<<1536, 256, 0, stream>>>(Ws, g, be, me, va, Wh, Wl, scale, bias);
  split_transpose2<<<2304, 256, 0, stream>>>(x, fk, S0h, S0l, S2h, S2l);

  auto W = [&](int layer) { return Wh + (size_t)layer * CH * CH; };
  auto Wlo = [&](int layer) { return Wl + (size_t)layer * CH * CH; };

  ConvJob psi1  {S0h, S0l, W(0), Wlo(0), scale + 0 * CH, bias + 0 * CH, P1h, P1l, nullptr, 0};
  ConvJob phi1  {S2h, S2l, W(2), Wlo(2), scale + 2 * CH, bias + 2 * CH, F1h, F1l, nullptr, 0};
  ConvJob fdown {S2h, S2l, W(4), Wlo(4), scale + 4 * CH, bias + 4 * CH, Vt, nullptr, nullptr, 3};
  ConvJob psi2  {P1h, P1l, W(1), Wlo(1), scale + 1 * CH, bias + 1 * CH, Qh, nullptr, nullptr, 1};
  ConvJob phi2  {F1h, F1l, W(3), Wlo(3), scale + 3 * CH, bias + 3 * CH, Kh, nullptr, nullptr, 1};

  conv128<<<864, 256, 0, stream>>>(psi1, phi1, fdown);
  conv128<<<576, 256, 0, stream>>>(psi2, phi2, phi2);
  attn_part<<<NQB2 * S, 256, 0, stream>>>(Qh, Kh, Vt, Opart, Mpart, Lpart, 288 / S);
  attn_combine<<<NQB2 * 4, 256, 0, stream>>>(Opart, Mpart, Lpart, S0h, S0l, S);
  conv64<<<576, 256, 0, stream>>>(S0h, S0l, W(5), Wlo(5), scale + 5 * CH, bias + 5 * CH, out);
}

// Round 19
// 460.998 us; speedup vs baseline: 4.8525x; 1.0125x over previous
//
#include <hip/hip_runtime.h>
#include <hip/hip_bf16.h>

typedef __bf16 bf16;
typedef __bf16 bf16x8 __attribute__((ext_vector_type(8)));
typedef float floatx4 __attribute__((ext_vector_type(4)));
typedef float floatx16 __attribute__((ext_vector_type(16)));

#define MFMA_BF16(a, b, c) __builtin_amdgcn_mfma_f32_16x16x32_bf16((a), (b), (c), 0, 0, 0)
#define MFMA32(a, b, c) __builtin_amdgcn_mfma_f32_32x32x16_bf16((a), (b), (c), 0, 0, 0)

static constexpr int CH = 256;      // channels
static constexpr int NPIX = 9216;   // 96*96
static constexpr int MTOT = 2 * NPIX; // both batches, n-major rows
static constexpr int NQB2 = 144;    // 128-row attention q-blocks total (2 batches)

// async global->LDS, 16B per lane; LDS dest = wave-uniform base + lane*16
__device__ __forceinline__ void async16(void* lds, const void* g) {
  __builtin_amdgcn_global_load_lds(
      (const __attribute__((address_space(1))) void*)g,
      (__attribute__((address_space(3))) void*)lds, 16, 0, 0);
}

// pack two f32 -> one u32 of 2 bf16 (lo = first arg)
__device__ __forceinline__ unsigned cvtpk(float lo, float hi) {
  unsigned r;
  asm("v_cvt_pk_bf16_f32 %0, %1, %2" : "=v"(r) : "v"(lo), "v"(hi));
  return r;
}

// v_permlane32_swap_b32 a, b  (VALU, gfx950, correctness-verified in v5/v6 runs):
//   a'[0:31]=a[0:31], a'[32:63]=b[0:31]; b'[0:31]=a[32:63], b'[32:63]=b[32:63]
__device__ __forceinline__ void plswap(unsigned& a, unsigned& b) {
  asm volatile("v_permlane32_swap_b32 %0, %1" : "+v"(a), "+v"(b));
}
// max/sum with lane^32 partner via permlane (VALU ~4cy vs ds_bpermute ~120cy)
__device__ __forceinline__ float xmax32(float v) {
  unsigned a = __builtin_bit_cast(unsigned, v), b = a;
  plswap(a, b);
  return fmaxf(__builtin_bit_cast(float, a), __builtin_bit_cast(float, b));
}
__device__ __forceinline__ float xsum32(float v) {
  unsigned a = __builtin_bit_cast(unsigned, v), b = a;
  plswap(a, b);
  return __builtin_bit_cast(float, a) + __builtin_bit_cast(float, b);
}

// ---------------------------------------------------------------------------
// Both inputs: fp32 [B][256][9216] (c-major) -> bf16 hi/lo [B*9216][256].
// bid < 1152 -> x, else fk. v9: blocks 0..1535 ALSO split one 256-elem chunk
// of the weights (fp32 -> bf16 hi/lo) + folded BN scale/bias (prep_weights
// folded in; outputs independent of the transpose work).
// ---------------------------------------------------------------------------
__global__ void split_transpose2(const float* __restrict__ xin, const float* __restrict__ fkin,
                                 bf16* __restrict__ ohx, bf16* __restrict__ olx,
                                 bf16* __restrict__ ohf, bf16* __restrict__ olf,
                                 const float* __restrict__ W,
                                 const float* __restrict__ g, const float* __restrict__ b,
                                 const float* __restrict__ m, const float* __restrict__ v,
                                 bf16* __restrict__ Wh, bf16* __restrict__ Wl,
                                 float* __restrict__ scale, float* __restrict__ bias) {
  __shared__ float t[64][65];
  int bid = blockIdx.x;
  int tid = threadIdx.x;

  // folded prep_weights: 1536 blocks x 256 threads cover 6*256*256 weights
  {
    int i = bid * 256 + tid;
    if (i < 6 * CH * CH) {
      float wv = W[i];
      bf16 h = (bf16)wv;
      Wh[i] = h;
      Wl[i] = (bf16)(wv - (float)h);
    }
    if (i < 6 * CH) {
      float s = g[i] * rsqrtf(v[i] + 1e-5f);
      scale[i] = s;
      bias[i] = b[i] - m[i] * s;
    }
  }

  const float* in; bf16 *oh, *ol;
  if (bid >= 1152) { in = fkin; oh = ohf; ol = olf; bid -= 1152; }
  else             { in = xin;  oh = ohx; ol = olx; }
  int bb = bid / 576, rem = bid % 576;
  int ct = rem / 144, nt = rem % 144;
  int c0 = ct * 64, n0 = nt * 64;
  int cr = tid >> 4, nc = (tid & 15) * 4;
  for (int rr = 0; rr < 64; rr += 16) {
    int c = cr + rr;
    const float* p = in + ((size_t)(bb * CH + c0 + c) * NPIX) + n0 + nc;
    float4 val = *(const float4*)p;
    t[c][nc + 0] = val.x; t[c][nc + 1] = val.y;
    t[c][nc + 2] = val.z; t[c][nc + 3] = val.w;
  }
  __syncthreads();
  int n = tid >> 2, cb = (tid & 3) * 16;
  bf16 hb[16], lb[16];
#pragma unroll
  for (int j = 0; j < 16; j++) {
    float xv = t[cb + j][n];
    bf16 h = (bf16)xv;
    hb[j] = h;
    lb[j] = (bf16)(xv - (float)h);
  }
  size_t idx = (size_t)(bb * NPIX + n0 + n) * CH + c0 + cb;
  *(bf16x8*)&oh[idx]     = *(bf16x8*)&hb[0];
  *(bf16x8*)&oh[idx + 8] = *(bf16x8*)&hb[8];
  *(bf16x8*)&ol[idx]     = *(bf16x8*)&lb[0];
  *(bf16x8*)&ol[idx + 8] = *(bf16x8*)&lb[8];
}

// ---------------------------------------------------------------------------
// Batched split-bf16 conv-GEMM, 128x128 tiles.
// v9 grid layout: job0 blocks [0,288), job1 [288,576), job2 [576,576+n2).
// j.bid0 offsets job2's local block id (fdown split 144/144 across the two
// launches -> both launches 720 blocks, single pass at 3 blocks/CU).
// mode: 0 = write hi+lo bf16, 1 = hi only, 2 = fp32,
//       3 = bf16 TRANSPOSED to c-major [B][256][9216] (fused transpose_bf16)
// ---------------------------------------------------------------------------
struct ConvJob {
  const bf16 *Ah, *Al, *Bh, *Bl;
  const float *scale, *bias;
  bf16 *Yh, *Yl; float *Yf;
  int mode;
  int bid0;
};

__global__ __launch_bounds__(256, 3) void conv128(ConvJob j0, ConvJob j1, ConvJob j2) {
  __shared__ bf16 lds[4][8 * 512];  // planes: Ah, Al, Bh, Bl
  int gbid = blockIdx.x;
  ConvJob j; int bid;
  if (gbid < 288)      { j = j0; bid = gbid; }
  else if (gbid < 576) { j = j1; bid = gbid - 288; }
  else                 { j = j2; bid = gbid - 576 + j2.bid0; }

  int tid = threadIdx.x;
  int w = tid >> 6, l = tid & 63;
  int q = l >> 4, c16 = l & 15;
  int m0 = (bid >> 1) * 128;
  int o0 = (bid & 1) * 128;

  const bf16* src = (w == 0) ? j.Ah : (w == 1) ? j.Al : (w == 2) ? j.Bh : j.Bl;
  int rowbase = (w < 2) ? m0 : o0;
  const bf16* gp = src + (size_t)(rowbase + c16) * CH + q * 8;
  bf16* ldst = &lds[w][0];

  const floatx4 zero4 = {0.f, 0.f, 0.f, 0.f};
  floatx4 acc[4][4];
#pragma unroll
  for (int i = 0; i < 4; i++)
#pragma unroll
    for (int jj = 0; jj < 4; jj++) acc[i][jj] = zero4;

  int mo16 = (w & 1) * 4, no16 = (w >> 1) * 4;

  for (int k0 = 0; k0 < CH; k0 += 32) {
#pragma unroll
    for (int f = 0; f < 8; f++)
      async16(ldst + f * 512, gp + (size_t)f * 16 * CH + k0);
    __syncthreads();

    bf16x8 ah[4], al[4], bh[4], bl[4];
#pragma unroll
    for (int i = 0; i < 4; i++) {
      ah[i] = *(const bf16x8*)&lds[0][(mo16 + i) * 512 + l * 8];
      al[i] = *(const bf16x8*)&lds[1][(mo16 + i) * 512 + l * 8];
      bh[i] = *(const bf16x8*)&lds[2][(no16 + i) * 512 + l * 8];
      bl[i] = *(const bf16x8*)&lds[3][(no16 + i) * 512 + l * 8];
    }
#pragma unroll
    for (int i = 0; i < 4; i++)
#pragma unroll
      for (int jj = 0; jj < 4; jj++) {
        acc[i][jj] = MFMA_BF16(ah[i], bh[jj], acc[i][jj]);
        acc[i][jj] = MFMA_BF16(ah[i], bl[jj], acc[i][jj]);
        acc[i][jj] = MFMA_BF16(al[i], bh[jj], acc[i][jj]);
      }
    __syncthreads();
  }

  int mo = (w & 1) * 64, no = (w >> 1) * 64;
  float sc[4], bs[4];
#pragma unroll
  for (int jj = 0; jj < 4; jj++) {
    int o = o0 + no + 16 * jj + c16;
    sc[jj] = j.scale[o];
    bs[jj] = j.bias[o];
  }

  if (j.mode == 3) {
    // fused transpose: write Yh as c-major [b][ch][pixel]
    bf16* tile = &lds[0][0];  // [64][136] bf16, 8704 elems <= 16384
    int b2 = (m0 >= NPIX) ? 1 : 0;
    int nr0 = m0 - b2 * NPIX;
#pragma unroll
    for (int hc = 0; hc < 2; hc++) {
      __syncthreads();
      if ((w >> 1) == hc) {
#pragma unroll
        for (int i = 0; i < 4; i++)
#pragma unroll
          for (int jj = 0; jj < 4; jj++)
#pragma unroll
            for (int r = 0; r < 4; r++) {
              float y = acc[i][jj][r] * sc[jj] + bs[jj];
              y = fmaxf(y, 0.f);
              int chl = no + 16 * jj + c16 - hc * 64;  // 0..63
              int rowl = mo + 16 * i + 4 * q + r;      // 0..127
              tile[chl * 136 + rowl] = (bf16)y;
            }
      }
      __syncthreads();
      int chl = tid >> 2, rseg = (tid & 3) * 32;
      bf16* dst = j.Yh + ((size_t)(b2 * CH + o0 + hc * 64 + chl)) * NPIX + nr0 + rseg;
#pragma unroll
      for (int k = 0; k < 4; k++)
        *(bf16x8*)(dst + 8 * k) = *(bf16x8*)&tile[chl * 136 + rseg + 8 * k];
    }
    return;
  }

#pragma unroll
  for (int i = 0; i < 4; i++) {
    int nrow = m0 + mo + 16 * i + 4 * q;
#pragma unroll
    for (int jj = 0; jj < 4; jj++) {
      int o = o0 + no + 16 * jj + c16;
#pragma unroll
      for (int r = 0; r < 4; r++) {
        float y = acc[i][jj][r] * sc[jj] + bs[jj];
        y = fmaxf(y, 0.f);
        size_t idx = (size_t)(nrow + r) * CH + o;
        if (j.mode == 2) {
          j.Yf[idx] = y;
        } else if (j.mode == 1) {
          j.Yh[idx] = (bf16)y;
        } else {
          bf16 h = (bf16)y;
          j.Yh[idx] = h;
          j.Yl[idx] = (bf16)(y - (float)h);
        }
      }
    }
  }
}

// ---------------------------------------------------------------------------
// 64x128-tile split-bf16 conv-GEMM, fp32 out (f_up), FUSED transposed write
// to final output [B][256][9216]. 2-pass 64ch x 64row fp32 LDS tile [64][68].
// ---------------------------------------------------------------------------
__global__ __launch_bounds__(256, 4) void conv64(
    const bf16* __restrict__ Ah, const bf16* __restrict__ Al,
    const bf16* __restrict__ Bh, const bf16* __restrict__ Bl,
    const float* __restrict__ scale, const float* __restrict__ bias,
    float* __restrict__ Yf) {
  __shared__ bf16 lds[24 * 512];  // flat frags: [Ah0-3, Al0-3, Bh0-7, Bl0-7]
  int tid = threadIdx.x;
  int w = tid >> 6, l = tid & 63;
  int q = l >> 4, c16 = l & 15;
  int m0 = (blockIdx.x >> 1) * 64;
  int o0 = (blockIdx.x & 1) * 128;

  const floatx4 zero4 = {0.f, 0.f, 0.f, 0.f};
  floatx4 acc[4][2];
#pragma unroll
  for (int i = 0; i < 4; i++) { acc[i][0] = zero4; acc[i][1] = zero4; }

  for (int k0 = 0; k0 < CH; k0 += 32) {
#pragma unroll
    for (int ff = 0; ff < 6; ff++) {
      int f = w * 6 + ff;
      const bf16* src; int rbase, fl;
      if (f < 4)       { src = Ah; rbase = m0; fl = f; }
      else if (f < 8)  { src = Al; rbase = m0; fl = f - 4; }
      else if (f < 16) { src = Bh; rbase = o0; fl = f - 8; }
      else             { src = Bl; rbase = o0; fl = f - 16; }
      async16(&lds[f * 512], src + (size_t)(rbase + fl * 16 + c16) * CH + k0 + q * 8);
    }
    __syncthreads();

    bf16x8 ah[4], al[4], bh[2], bl[2];
#pragma unroll
    for (int i = 0; i < 4; i++) {
      ah[i] = *(const bf16x8*)&lds[(0 + i) * 512 + l * 8];
      al[i] = *(const bf16x8*)&lds[(4 + i) * 512 + l * 8];
    }
#pragma unroll
    for (int n = 0; n < 2; n++) {
      bh[n] = *(const bf16x8*)&lds[(8 + 2 * w + n) * 512 + l * 8];
      bl[n] = *(const bf16x8*)&lds[(16 + 2 * w + n) * 512 + l * 8];
    }
#pragma unroll
    for (int i = 0; i < 4; i++)
#pragma unroll
      for (int n = 0; n < 2; n++) {
        acc[i][n] = MFMA_BF16(ah[i], bh[n], acc[i][n]);
        acc[i][n] = MFMA_BF16(ah[i], bl[n], acc[i][n]);
        acc[i][n] = MFMA_BF16(al[i], bh[n], acc[i][n]);
      }
    __syncthreads();
  }

  float sc[2], bs[2];
#pragma unroll
  for (int n = 0; n < 2; n++) {
    int o = o0 + 32 * w + 16 * n + c16;
    sc[n] = scale[o];
    bs[n] = bias[o];
  }

  float* tile = (float*)&lds[0];  // [64][68] fp32, 17408 B <= 24576
  int b2 = (m0 >= NPIX) ? 1 : 0;
  int nr0 = m0 - b2 * NPIX;
#pragma unroll
  for (int hc = 0; hc < 2; hc++) {
    __syncthreads();
    if ((w >> 1) == hc) {
#pragma unroll
      for (int i = 0; i < 4; i++)
#pragma unroll
        for (int n = 0; n < 2; n++)
#pragma unroll
          for (int r = 0; r < 4; r++) {
            float y = acc[i][n][r] * sc[n] + bs[n];
            y = fmaxf(y, 0.f);
            int chl = 32 * (w - 2 * hc) + 16 * n + c16;  // 0..63
            int rowl = 16 * i + 4 * q + r;               // 0..63
            tile[chl * 68 + rowl] = y;
          }
    }
    __syncthreads();
    int chl = tid >> 2, rseg = (tid & 3) * 16;
    float* dst = Yf + ((size_t)(b2 * CH + o0 + hc * 64 + chl)) * NPIX + nr0 + rseg;
#pragma unroll
    for (int k = 0; k < 4; k++)
      *(float4*)(dst + 4 * k) = *(float4*)&tile[chl * 68 + rseg + 4 * k];
  }
}

// ---------------------------------------------------------------------------
// Split-KV flash attention partial, v6 (proven 268us, UNCHANGED).
// BQ=128 (4 waves x 32 q-rows), BKV=32, 32x32x16 MFMAs, in-register P,
// permlane32_swap softmax reduces + P-pack, setprio around MFMA clusters.
// VGPR 128 arch + 128 acc; LDS 64 KB -> 2 blocks/CU; S=3, grid 432.
// ---------------------------------------------------------------------------
__global__ __launch_bounds__(256, 2) void attn_part(
    const bf16* __restrict__ Q, const bf16* __restrict__ K, const bf16* __restrict__ Vt,
    float* __restrict__ Opart, float* __restrict__ Mpart, float* __restrict__ Lpart,
    int niter) {
  __shared__ bf16 lK[2][16 * 512];  // frag ks: K[key=l&31][16ks+8hi+i]
  __shared__ bf16 lV[2][16 * 512];  // frag 2ct+ks2: V[ch=32ct+(l&31)][16ks2+8hi+i]

  int tid = threadIdx.x;
  int w = tid >> 6, l = tid & 63;
  int ql = l & 31, hi = l >> 5;
  int bid = blockIdx.x;
  int qb = bid % NQB2, s = bid / NQB2;
  int b = qb / 72;
  int n0 = (qb % 72) * 128;
  int kv0 = s * niter * 32;
  size_t qkbase = (size_t)b * NPIX * CH;
  size_t vbase  = (size_t)b * CH * NPIX;

  // Q fragments (B-operand 32x32x16): col = q-row = ql, k = 8hi+i per 16-ch step
  bf16x8 qf[16];
  {
    const bf16* qp = Q + qkbase + (size_t)(n0 + 32 * w + ql) * CH + 8 * hi;
#pragma unroll
    for (int ks = 0; ks < 16; ks++) qf[ks] = *(const bf16x8*)(qp + ks * 16);
  }

  floatx16 oacc[8];  // [ct]: O[q=(r&3)+8(r>>2)+4hi][ch=32ct+ql]
#pragma unroll
  for (int ct = 0; ct < 8; ct++)
#pragma unroll
    for (int r = 0; r < 16; r++) oacc[ct][r] = 0.f;
  float mrow = -1e30f, lrow = 0.f;

  const bf16* gK = K + qkbase + (size_t)kv0 * CH;
  const bf16* gV = Vt + vbase + kv0;

  // wave w stages K frags 4w..4w+3 and V frags 4w..4w+3 (8 async16/iter)
  auto stage = [&](int bi) {
#pragma unroll
    for (int ff = 0; ff < 4; ff++) {
      int f = 4 * w + ff;
      async16(&lK[bi][f * 512], gK + (size_t)ql * CH + f * 16 + 8 * hi);
      async16(&lV[bi][f * 512],
              gV + (size_t)((f >> 1) * 32 + ql) * NPIX + (f & 1) * 16 + 8 * hi);
    }
  };

  stage(0);

  for (int it = 0; it < niter; it++) {
    int cur = it & 1;
    __syncthreads();  // buffers `cur` ready (vmcnt drained); prev reads retired

    if (it + 1 < niter) {
      gK += 32 * CH; gV += 32;
      stage(cur ^ 1);
    }

    // S^T = K Q^T : D[key][q], two independent accumulator chains
    floatx16 sfA, sfB;
#pragma unroll
    for (int r = 0; r < 16; r++) { sfA[r] = 0.f; sfB[r] = 0.f; }
    __builtin_amdgcn_s_setprio(1);
#pragma unroll
    for (int ks = 0; ks < 16; ks += 2) {
      bf16x8 kf0 = *(const bf16x8*)&lK[cur][(ks + 0) * 512 + l * 8];
      bf16x8 kf1 = *(const bf16x8*)&lK[cur][(ks + 1) * 512 + l * 8];
      sfA = MFMA32(kf0, qf[ks + 0], sfA);
      sfB = MFMA32(kf1, qf[ks + 1], sfB);
    }
    __builtin_amdgcn_s_setprio(0);
    // combine + tile max for this lane's q-row (other 16 keys live in lane^32)
    float pm = -1e30f;
#pragma unroll
    for (int r = 0; r < 16; r++) {
      float sv = sfA[r] + sfB[r];
      sfA[r] = sv;
      pm = fmaxf(pm, sv);
    }
    pm = xmax32(pm);

    // defer-max: rescale only when row max grew by > 8
    bool need = pm > mrow + 8.f;
    if (__ballot((int)need) != 0ull) {
      float mn = fmaxf(mrow, pm);
      float alpha = __expf(mrow - mn);
      mrow = mn;
      lrow *= alpha;
      float arow[16];
#pragma unroll
      for (int r = 0; r < 16; r++)
        arow[r] = __shfl(alpha, (r & 3) + 8 * (r >> 2) + 4 * hi);
#pragma unroll
      for (int ct = 0; ct < 8; ct++)
#pragma unroll
        for (int r = 0; r < 16; r++) oacc[ct][r] *= arow[r];
    }

    // P = exp(S - m) (all 16 values belong to this lane's own q-row)
    float p[16];
    float rs = 0.f;
#pragma unroll
    for (int r = 0; r < 16; r++) {
      p[r] = __expf(sfA[r] - mrow);
      rs += p[r];
    }
    lrow += xsum32(rs);

    // pack to PV A-frags: reg r holds key (r&3)+8(r>>2)+4hi
    unsigned pk0 = cvtpk(p[0], p[1]),   pk1 = cvtpk(p[2], p[3]);
    unsigned pk2 = cvtpk(p[4], p[5]),   pk3 = cvtpk(p[6], p[7]);
    unsigned pk4 = cvtpk(p[8], p[9]),   pk5 = cvtpk(p[10], p[11]);
    unsigned pk6 = cvtpk(p[12], p[13]), pk7 = cvtpk(p[14], p[15]);
    plswap(pk0, pk2); plswap(pk1, pk3);
    plswap(pk4, pk6); plswap(pk5, pk7);
    uint4 u0, u1;
    u0.x = pk0; u0.y = pk1; u0.z = pk2; u0.w = pk3;  // keys 0..15, k = 8hi+i
    u1.x = pk4; u1.y = pk5; u1.z = pk6; u1.w = pk7;  // keys 16..31
    bf16x8 pa0 = __builtin_bit_cast(bf16x8, u0);
    bf16x8 pa1 = __builtin_bit_cast(bf16x8, u1);

    // PV: O[q][ch] += P[q][k] V[k][ch]
    __builtin_amdgcn_s_setprio(1);
#pragma unroll
    for (int ct = 0; ct < 8; ct++) {
      bf16x8 vb0 = *(const bf16x8*)&lV[cur][(2 * ct + 0) * 512 + l * 8];
      bf16x8 vb1 = *(const bf16x8*)&lV[cur][(2 * ct + 1) * 512 + l * 8];
      oacc[ct] = MFMA32(pa0, vb0, oacc[ct]);
      oacc[ct] = MFMA32(pa1, vb1, oacc[ct]);
    }
    __builtin_amdgcn_s_setprio(0);
  }

  // write partials (unnormalized O + m, l)
  if (hi == 0) {
    Mpart[(size_t)bid * 128 + 32 * w + ql] = mrow;
    Lpart[(size_t)bid * 128 + 32 * w + ql] = lrow;
  }
  float* Ob = Opart + (size_t)bid * 128 * CH;
#pragma unroll
  for (int ct = 0; ct < 8; ct++)
#pragma unroll
    for (int r = 0; r < 16; r++) {
      int row = 32 * w + (r & 3) + 8 * (r >> 2) + 4 * hi;
      Ob[(size_t)row * CH + 32 * ct + ql] = oacc[ct][r];
    }
}

// ---------------------------------------------------------------------------
// Combine S partials -> normalized O, split hi/lo bf16, n-major [MTOT][256]
// grid NQB2*4 = 576 blocks x 32-row quarters (proven v7 form).
// ---------------------------------------------------------------------------
__global__ __launch_bounds__(256) void attn_combine(
    const float* __restrict__ Opart, const float* __restrict__ Mpart,
    const float* __restrict__ Lpart,
    bf16* __restrict__ Oh, bf16* __restrict__ Ol, int S) {
  __shared__ float wgt[8][32];
  __shared__ float invl[32];
  int qb = blockIdx.x >> 2;
  int r0 = (blockIdx.x & 3) * 32;
  int t = threadIdx.x;
  if (t < 32) {
    int row = r0 + t;
    float m = -1e30f;
    for (int s = 0; s < S; s++)
      m = fmaxf(m, Mpart[(size_t)(s * NQB2 + qb) * 128 + row]);
    float lsum = 0.f;
    for (int s = 0; s < S; s++) {
      float wv = __expf(Mpart[(size_t)(s * NQB2 + qb) * 128 + row] - m);
      wgt[s][t] = wv;
      lsum += wv * Lpart[(size_t)(s * NQB2 + qb) * 128 + row];
    }
    invl[t] = 1.0f / lsum;
  }
  __syncthreads();
  int c = t;  // 256 threads = 256 channels
  for (int rr = 0; rr < 32; rr++) {
    int row = r0 + rr;
    float acc = 0.f;
    for (int s = 0; s < S; s++)
      acc += wgt[s][rr] * Opart[((size_t)(s * NQB2 + qb) * 128 + row) * CH + c];
    float y = acc * invl[rr];
    size_t idx = (size_t)(qb * 128 + row) * CH + c;
    bf16 h = (bf16)y;
    Oh[idx] = h;
    Ol[idx] = (bf16)(y - (float)h);
  }
}

// ---------------------------------------------------------------------------
extern "C" void kernel_launch(void* const* d_in, const int* in_sizes, int n_in,
                              void* d_out, int out_size, void* d_ws, size_t ws_size,
                              hipStream_t stream) {
  const float* x  = (const float*)d_in[0];
  const float* fk = (const float*)d_in[1];
  const float* Ws = (const float*)d_in[2];
  const float* g  = (const float*)d_in[3];
  const float* be = (const float*)d_in[4];
  const float* me = (const float*)d_in[5];
  const float* va = (const float*)d_in[6];
  float* out = (float*)d_out;

  char* p = (char*)d_ws;
  bf16* Wh = (bf16*)p; p += (size_t)6 * CH * CH * 2;
  bf16* Wl = (bf16*)p; p += (size_t)6 * CH * CH * 2;
  float* scale = (float*)p; p += (size_t)6 * CH * 4;
  float* bias  = (float*)p; p += (size_t)6 * CH * 4;
  size_t plane = (size_t)MTOT * CH * 2;  // 9,437,184 B per bf16 plane
  bf16* S0h = (bf16*)p; p += plane;
  bf16* S0l = (bf16*)p; p += plane;
  bf16* Qh  = (bf16*)p; p += plane;
  bf16* Kh  = (bf16*)p; p += plane;
  bf16* Vt  = (bf16*)p; p += plane;   // c-major V, written directly by conv128 mode 3
  char* region = p;

  // Overlays inside `region` (all dead before attn_part writes Opart there):
  bf16* S2h = (bf16*)(region);              // fk transposed (hi)
  bf16* S2l = (bf16*)(region + plane);      // fk transposed (lo)
  bf16* P1h = (bf16*)(region + 2 * plane);  // psi1 out (hi)
  bf16* P1l = (bf16*)(region + 3 * plane);  // psi1 out (lo)
  bf16* F1h = (bf16*)(region + 4 * plane);  // phi1 out (hi)
  bf16* F1l = (bf16*)(region + 5 * plane);  // phi1 out (lo)

  size_t base_used = (size_t)(region - (char*)d_ws);
  size_t osz = (size_t)NQB2 * 128 * CH * 4;           // 18.9 MB per split
  size_t per_split = osz + 2 * (size_t)NQB2 * 128 * 4;
  long avail = (long)ws_size - (long)base_used;
  int S = 1;
  {
    // S=3 -> grid 432 fully co-resident at 2 blocks/CU; 288 % S == 0 required
    int cand[3] = {3, 2, 1};
    for (int i = 0; i < 3; i++)
      if ((long)cand[i] * (long)per_split <= avail) { S = cand[i]; break; }
  }
  float* Opart = (float*)region;
  float* Mpart = (float*)(region + (size_t)S * osz);
  float* Lpart = Mpart + (size_t)S * NQB2 * 128;

  (void)in_sizes; (void)n_in; (void)out_size;

  split_transpose2<<<2304, 256, 0, stream>>>(x, fk, S0h, S0l, S2h, S2l,
                                             Ws, g, be, me, va, Wh, Wl, scale, bias);

  auto W = [&](int layer) { return Wh + (size_t)layer * CH * CH; };
  auto Wlo = [&](int layer) { return Wl + (size_t)layer * CH * CH; };

  ConvJob psi1   {S0h, S0l, W(0), Wlo(0), scale + 0 * CH, bias + 0 * CH, P1h, P1l, nullptr, 0, 0};
  ConvJob phi1   {S2h, S2l, W(2), Wlo(2), scale + 2 * CH, bias + 2 * CH, F1h, F1l, nullptr, 0, 0};
  ConvJob fdownA {S2h, S2l, W(4), Wlo(4), scale + 4 * CH, bias + 4 * CH, Vt, nullptr, nullptr, 3, 0};
  ConvJob fdownB {S2h, S2l, W(4), Wlo(4), scale + 4 * CH, bias + 4 * CH, Vt, nullptr, nullptr, 3, 144};
  ConvJob psi2   {P1h, P1l, W(1), Wlo(1), scale + 1 * CH, bias + 1 * CH, Qh, nullptr, nullptr, 1, 0};
  ConvJob phi2   {F1h, F1l, W(3), Wlo(3), scale + 3 * CH, bias + 3 * CH, Kh, nullptr, nullptr, 1, 0};

  // fdown (288 blocks) split 144/144 across both launches -> 720/720 blocks,
  // both single-pass at 3 blocks/CU (was 864+576 with a 96-block tail pass).
  conv128<<<720, 256, 0, stream>>>(psi1, phi1, fdownA);
  conv128<<<720, 256, 0, stream>>>(psi2, phi2, fdownB);
  attn_part<<<NQB2 * S, 256, 0, stream>>>(Qh, Kh, Vt, Opart, Mpart, Lpart, 288 / S);
  attn_combine<<<NQB2 * 4, 256, 0, stream>>>(Opart, Mpart, Lpart, S0h, S0l, S);
  conv64<<<576, 256, 0, stream>>>(S0h, S0l, W(5), Wlo(5), scale + 5 * CH, bias + 5 * CH, out);
}

// Round 20
// 449.668 us; speedup vs baseline: 4.9748x; 1.0252x over previous
//
#include <hip/hip_runtime.h>
#include <hip/hip_bf16.h>

typedef __bf16 bf16;
typedef __bf16 bf16x8 __attribute__((ext_vector_type(8)));
typedef float floatx4 __attribute__((ext_vector_type(4)));
typedef float floatx16 __attribute__((ext_vector_type(16)));

#define MFMA_BF16(a, b, c) __builtin_amdgcn_mfma_f32_16x16x32_bf16((a), (b), (c), 0, 0, 0)
#define MFMA32(a, b, c) __builtin_amdgcn_mfma_f32_32x32x16_bf16((a), (b), (c), 0, 0, 0)

static constexpr int CH = 256;      // channels
static constexpr int NPIX = 9216;   // 96*96
static constexpr int MTOT = 2 * NPIX; // both batches, n-major rows
static constexpr int NQB2 = 144;    // 128-row attention q-blocks total (2 batches)

// async global->LDS, 16B per lane; LDS dest = wave-uniform base + lane*16
__device__ __forceinline__ void async16(void* lds, const void* g) {
  __builtin_amdgcn_global_load_lds(
      (const __attribute__((address_space(1))) void*)g,
      (__attribute__((address_space(3))) void*)lds, 16, 0, 0);
}

// pack two f32 -> one u32 of 2 bf16 (lo = first arg)
__device__ __forceinline__ unsigned cvtpk(float lo, float hi) {
  unsigned r;
  asm("v_cvt_pk_bf16_f32 %0, %1, %2" : "=v"(r) : "v"(lo), "v"(hi));
  return r;
}

// v_permlane32_swap_b32 a, b  (VALU, gfx950, correctness-verified in v5/v6 runs):
//   a'[0:31]=a[0:31], a'[32:63]=b[0:31]; b'[0:31]=a[32:63], b'[32:63]=b[32:63]
__device__ __forceinline__ void plswap(unsigned& a, unsigned& b) {
  asm volatile("v_permlane32_swap_b32 %0, %1" : "+v"(a), "+v"(b));
}
// max/sum with lane^32 partner via permlane (VALU ~4cy vs ds_bpermute ~120cy)
__device__ __forceinline__ float xmax32(float v) {
  unsigned a = __builtin_bit_cast(unsigned, v), b = a;
  plswap(a, b);
  return fmaxf(__builtin_bit_cast(float, a), __builtin_bit_cast(float, b));
}
__device__ __forceinline__ float xsum32(float v) {
  unsigned a = __builtin_bit_cast(unsigned, v), b = a;
  plswap(a, b);
  return __builtin_bit_cast(float, a) + __builtin_bit_cast(float, b);
}

// ---------------------------------------------------------------------------
// fk only: fp32 [B][256][9216] (c-major) -> bf16 hi/lo [B*9216][256].
// grid 1536: blocks 0..1151 transpose fk; ALL blocks split one 256-elem
// weight chunk (prep_weights folded). x is no longer pre-transposed -- psi1
// (conv128 mode 4) reads fp32 x c-major directly and transposes in-kernel.
// ---------------------------------------------------------------------------
__global__ void split_fk(const float* __restrict__ fkin,
                         bf16* __restrict__ ohf, bf16* __restrict__ olf,
                         const float* __restrict__ W,
                         const float* __restrict__ g, const float* __restrict__ b,
                         const float* __restrict__ m, const float* __restrict__ v,
                         bf16* __restrict__ Wh, bf16* __restrict__ Wl,
                         float* __restrict__ scale, float* __restrict__ bias) {
  __shared__ float t[64][65];
  int bid = blockIdx.x;
  int tid = threadIdx.x;

  // folded prep_weights: 1536 blocks x 256 threads cover 6*256*256 weights
  {
    int i = bid * 256 + tid;
    if (i < 6 * CH * CH) {
      float wv = W[i];
      bf16 h = (bf16)wv;
      Wh[i] = h;
      Wl[i] = (bf16)(wv - (float)h);
    }
    if (i < 6 * CH) {
      float s = g[i] * rsqrtf(v[i] + 1e-5f);
      scale[i] = s;
      bias[i] = b[i] - m[i] * s;
    }
  }
  if (bid >= 1152) return;

  int bb = bid / 576, rem = bid % 576;
  int ct = rem / 144, nt = rem % 144;
  int c0 = ct * 64, n0 = nt * 64;
  int cr = tid >> 4, nc = (tid & 15) * 4;
  for (int rr = 0; rr < 64; rr += 16) {
    int c = cr + rr;
    const float* p = fkin + ((size_t)(bb * CH + c0 + c) * NPIX) + n0 + nc;
    float4 val = *(const float4*)p;
    t[c][nc + 0] = val.x; t[c][nc + 1] = val.y;
    t[c][nc + 2] = val.z; t[c][nc + 3] = val.w;
  }
  __syncthreads();
  int n = tid >> 2, cb = (tid & 3) * 16;
  bf16 hb[16], lb[16];
#pragma unroll
  for (int j = 0; j < 16; j++) {
    float xv = t[cb + j][n];
    bf16 h = (bf16)xv;
    hb[j] = h;
    lb[j] = (bf16)(xv - (float)h);
  }
  size_t idx = (size_t)(bb * NPIX + n0 + n) * CH + c0 + cb;
  *(bf16x8*)&ohf[idx]     = *(bf16x8*)&hb[0];
  *(bf16x8*)&ohf[idx + 8] = *(bf16x8*)&hb[8];
  *(bf16x8*)&olf[idx]     = *(bf16x8*)&lb[0];
  *(bf16x8*)&olf[idx + 8] = *(bf16x8*)&lb[8];
}

// ---------------------------------------------------------------------------
// Batched split-bf16 conv-GEMM, 128x128 tiles.
// grid layout: job0 blocks [0,288), job1 [288,576), job2 [576,576+n2);
// j.bid0 offsets job2's local bid (fdown split 144/144 across launches).
// mode: 0 = write hi+lo bf16, 1 = hi only,
//       3 = bf16 TRANSPOSED out to c-major [B][256][9216] (fused transpose)
//       4 = A-operand is fp32 c-major x: transpose+split in-kernel (psi1);
//           j.Ah carries the fp32 pointer (cast), j.Al unused.
// ---------------------------------------------------------------------------
struct ConvJob {
  const bf16 *Ah, *Al, *Bh, *Bl;
  const float *scale, *bias;
  bf16 *Yh, *Yl; float *Yf;
  int mode;
  int bid0;
};

__global__ __launch_bounds__(256, 3) void conv128(ConvJob j0, ConvJob j1, ConvJob j2) {
  __shared__ bf16 lds[4][8 * 512];  // planes: Ah, Al, Bh, Bl
  __shared__ float scr[32][132];    // mode-4 fp32 x-tile scratch (16.5 KB)
  int gbid = blockIdx.x;
  ConvJob j; int bid;
  if (gbid < 288)      { j = j0; bid = gbid; }
  else if (gbid < 576) { j = j1; bid = gbid - 288; }
  else                 { j = j2; bid = gbid - 576 + j2.bid0; }

  int tid = threadIdx.x;
  int w = tid >> 6, l = tid & 63;
  int q = l >> 4, c16 = l & 15;
  int m0 = (bid >> 1) * 128;
  int o0 = (bid & 1) * 128;

  const bf16* src = (w == 0) ? j.Ah : (w == 1) ? j.Al : (w == 2) ? j.Bh : j.Bl;
  int rowbase = (w < 2) ? m0 : o0;
  const bf16* gp = src + (size_t)(rowbase + c16) * CH + q * 8;
  bf16* ldst = &lds[w][0];

  const floatx4 zero4 = {0.f, 0.f, 0.f, 0.f};
  floatx4 acc[4][4];
#pragma unroll
  for (int i = 0; i < 4; i++)
#pragma unroll
    for (int jj = 0; jj < 4; jj++) acc[i][jj] = zero4;

  int mo16 = (w & 1) * 4, no16 = (w >> 1) * 4;
  bool m4 = (j.mode == 4);
  const float* xsrc = (const float*)j.Ah;
  int b2m = (m0 >= NPIX) ? 1 : 0;
  int nr0m = m0 - b2m * NPIX;

  for (int k0 = 0; k0 < CH; k0 += 32) {
    if (m4) {
      // B-planes via async16 (waves 2,3 as usual)
      if (w >= 2) {
#pragma unroll
        for (int f = 0; f < 8; f++)
          async16(ldst + f * 512, gp + (size_t)f * 16 * CH + k0);
      }
      // fp32 x c-major tile: thread -> ch k0+(tid>>3), rows nr0m+(tid&7)*16..+15
      {
        const float* xp = xsrc + ((size_t)(b2m * CH + k0 + (tid >> 3))) * NPIX
                          + nr0m + (tid & 7) * 16;
        float4 v0 = ((const float4*)xp)[0];
        float4 v1 = ((const float4*)xp)[1];
        float4 v2 = ((const float4*)xp)[2];
        float4 v3 = ((const float4*)xp)[3];
        float* srow = &scr[tid >> 3][(tid & 7) * 16];
        *(float4*)(srow + 0) = v0;  *(float4*)(srow + 4) = v1;
        *(float4*)(srow + 8) = v2;  *(float4*)(srow + 12) = v3;
      }
      __syncthreads();
      // transpose + hi/lo split into A planes (exact async16 frag layout):
      // lds[0][f*512 + l*8 + jj] = hi(A[m0 + f*16 + (l&15)][k0 + (l>>4)*8 + jj])
#pragma unroll
      for (int half = 0; half < 2; half++) {
        int f = tid >> 5;                      // 0..7
        int l2 = (tid & 31) + half * 32;       // 0..63
        int qq = l2 >> 4, cc = l2 & 15;
        int row = f * 16 + cc;
        bf16 hb[8], lb[8];
#pragma unroll
        for (int jj2 = 0; jj2 < 8; jj2++) {
          float xv = scr[qq * 8 + jj2][row];
          bf16 h = (bf16)xv;
          hb[jj2] = h;
          lb[jj2] = (bf16)(xv - (float)h);
        }
        *(bf16x8*)&lds[0][f * 512 + l2 * 8] = *(bf16x8*)&hb[0];
        *(bf16x8*)&lds[1][f * 512 + l2 * 8] = *(bf16x8*)&lb[0];
      }
    } else {
#pragma unroll
      for (int f = 0; f < 8; f++)
        async16(ldst + f * 512, gp + (size_t)f * 16 * CH + k0);
    }
    __syncthreads();

    bf16x8 ah[4], al[4], bh[4], bl[4];
#pragma unroll
    for (int i = 0; i < 4; i++) {
      ah[i] = *(const bf16x8*)&lds[0][(mo16 + i) * 512 + l * 8];
      al[i] = *(const bf16x8*)&lds[1][(mo16 + i) * 512 + l * 8];
      bh[i] = *(const bf16x8*)&lds[2][(no16 + i) * 512 + l * 8];
      bl[i] = *(const bf16x8*)&lds[3][(no16 + i) * 512 + l * 8];
    }
#pragma unroll
    for (int i = 0; i < 4; i++)
#pragma unroll
      for (int jj = 0; jj < 4; jj++) {
        acc[i][jj] = MFMA_BF16(ah[i], bh[jj], acc[i][jj]);
        acc[i][jj] = MFMA_BF16(ah[i], bl[jj], acc[i][jj]);
        acc[i][jj] = MFMA_BF16(al[i], bh[jj], acc[i][jj]);
      }
    __syncthreads();
  }

  int mo = (w & 1) * 64, no = (w >> 1) * 64;
  float sc[4], bs[4];
#pragma unroll
  for (int jj = 0; jj < 4; jj++) {
    int o = o0 + no + 16 * jj + c16;
    sc[jj] = j.scale[o];
    bs[jj] = j.bias[o];
  }

  if (j.mode == 3) {
    // fused transpose: write Yh as c-major [b][ch][pixel]
    bf16* tile = &lds[0][0];  // [64][136] bf16, 8704 elems <= 16384
    int b2 = (m0 >= NPIX) ? 1 : 0;
    int nr0 = m0 - b2 * NPIX;
#pragma unroll
    for (int hc = 0; hc < 2; hc++) {
      __syncthreads();
      if ((w >> 1) == hc) {
#pragma unroll
        for (int i = 0; i < 4; i++)
#pragma unroll
          for (int jj = 0; jj < 4; jj++)
#pragma unroll
            for (int r = 0; r < 4; r++) {
              float y = acc[i][jj][r] * sc[jj] + bs[jj];
              y = fmaxf(y, 0.f);
              int chl = no + 16 * jj + c16 - hc * 64;  // 0..63
              int rowl = mo + 16 * i + 4 * q + r;      // 0..127
              tile[chl * 136 + rowl] = (bf16)y;
            }
      }
      __syncthreads();
      int chl = tid >> 2, rseg = (tid & 3) * 32;
      bf16* dst = j.Yh + ((size_t)(b2 * CH + o0 + hc * 64 + chl)) * NPIX + nr0 + rseg;
#pragma unroll
      for (int k = 0; k < 4; k++)
        *(bf16x8*)(dst + 8 * k) = *(bf16x8*)&tile[chl * 136 + rseg + 8 * k];
    }
    return;
  }

#pragma unroll
  for (int i = 0; i < 4; i++) {
    int nrow = m0 + mo + 16 * i + 4 * q;
#pragma unroll
    for (int jj = 0; jj < 4; jj++) {
      int o = o0 + no + 16 * jj + c16;
#pragma unroll
      for (int r = 0; r < 4; r++) {
        float y = acc[i][jj][r] * sc[jj] + bs[jj];
        y = fmaxf(y, 0.f);
        size_t idx = (size_t)(nrow + r) * CH + o;
        if (j.mode == 1) {
          j.Yh[idx] = (bf16)y;
        } else {
          bf16 h = (bf16)y;
          j.Yh[idx] = h;
          j.Yl[idx] = (bf16)(y - (float)h);
        }
      }
    }
  }
}

// ---------------------------------------------------------------------------
// 64x128-tile split-bf16 conv-GEMM, fp32 out (f_up), FUSED transposed write
// to final output [B][256][9216]. 2-pass 64ch x 64row fp32 LDS tile [64][68].
// ---------------------------------------------------------------------------
__global__ __launch_bounds__(256, 4) void conv64(
    const bf16* __restrict__ Ah, const bf16* __restrict__ Al,
    const bf16* __restrict__ Bh, const bf16* __restrict__ Bl,
    const float* __restrict__ scale, const float* __restrict__ bias,
    float* __restrict__ Yf) {
  __shared__ bf16 lds[24 * 512];  // flat frags: [Ah0-3, Al0-3, Bh0-7, Bl0-7]
  int tid = threadIdx.x;
  int w = tid >> 6, l = tid & 63;
  int q = l >> 4, c16 = l & 15;
  int m0 = (blockIdx.x >> 1) * 64;
  int o0 = (blockIdx.x & 1) * 128;

  const floatx4 zero4 = {0.f, 0.f, 0.f, 0.f};
  floatx4 acc[4][2];
#pragma unroll
  for (int i = 0; i < 4; i++) { acc[i][0] = zero4; acc[i][1] = zero4; }

  for (int k0 = 0; k0 < CH; k0 += 32) {
#pragma unroll
    for (int ff = 0; ff < 6; ff++) {
      int f = w * 6 + ff;
      const bf16* src; int rbase, fl;
      if (f < 4)       { src = Ah; rbase = m0; fl = f; }
      else if (f < 8)  { src = Al; rbase = m0; fl = f - 4; }
      else if (f < 16) { src = Bh; rbase = o0; fl = f - 8; }
      else             { src = Bl; rbase = o0; fl = f - 16; }
      async16(&lds[f * 512], src + (size_t)(rbase + fl * 16 + c16) * CH + k0 + q * 8);
    }
    __syncthreads();

    bf16x8 ah[4], al[4], bh[2], bl[2];
#pragma unroll
    for (int i = 0; i < 4; i++) {
      ah[i] = *(const bf16x8*)&lds[(0 + i) * 512 + l * 8];
      al[i] = *(const bf16x8*)&lds[(4 + i) * 512 + l * 8];
    }
#pragma unroll
    for (int n = 0; n < 2; n++) {
      bh[n] = *(const bf16x8*)&lds[(8 + 2 * w + n) * 512 + l * 8];
      bl[n] = *(const bf16x8*)&lds[(16 + 2 * w + n) * 512 + l * 8];
    }
#pragma unroll
    for (int i = 0; i < 4; i++)
#pragma unroll
      for (int n = 0; n < 2; n++) {
        acc[i][n] = MFMA_BF16(ah[i], bh[n], acc[i][n]);
        acc[i][n] = MFMA_BF16(ah[i], bl[n], acc[i][n]);
        acc[i][n] = MFMA_BF16(al[i], bh[n], acc[i][n]);
      }
    __syncthreads();
  }

  float sc[2], bs[2];
#pragma unroll
  for (int n = 0; n < 2; n++) {
    int o = o0 + 32 * w + 16 * n + c16;
    sc[n] = scale[o];
    bs[n] = bias[o];
  }

  float* tile = (float*)&lds[0];  // [64][68] fp32, 17408 B <= 24576
  int b2 = (m0 >= NPIX) ? 1 : 0;
  int nr0 = m0 - b2 * NPIX;
#pragma unroll
  for (int hc = 0; hc < 2; hc++) {
    __syncthreads();
    if ((w >> 1) == hc) {
#pragma unroll
      for (int i = 0; i < 4; i++)
#pragma unroll
        for (int n = 0; n < 2; n++)
#pragma unroll
          for (int r = 0; r < 4; r++) {
            float y = acc[i][n][r] * sc[n] + bs[n];
            y = fmaxf(y, 0.f);
            int chl = 32 * (w - 2 * hc) + 16 * n + c16;  // 0..63
            int rowl = 16 * i + 4 * q + r;               // 0..63
            tile[chl * 68 + rowl] = y;
          }
    }
    __syncthreads();
    int chl = tid >> 2, rseg = (tid & 3) * 16;
    float* dst = Yf + ((size_t)(b2 * CH + o0 + hc * 64 + chl)) * NPIX + nr0 + rseg;
#pragma unroll
    for (int k = 0; k < 4; k++)
      *(float4*)(dst + 4 * k) = *(float4*)&tile[chl * 68 + rseg + 4 * k];
  }
}

// ---------------------------------------------------------------------------
// Split-KV flash attention partial, v6 (proven 268us, UNCHANGED).
// BQ=128 (4 waves x 32 q-rows), BKV=32, 32x32x16 MFMAs, in-register P,
// permlane32_swap softmax reduces + P-pack, setprio around MFMA clusters.
// VGPR 128 arch + 128 acc; LDS 64 KB -> 2 blocks/CU; S=3, grid 432.
// ---------------------------------------------------------------------------
__global__ __launch_bounds__(256, 2) void attn_part(
    const bf16* __restrict__ Q, const bf16* __restrict__ K, const bf16* __restrict__ Vt,
    float* __restrict__ Opart, float* __restrict__ Mpart, float* __restrict__ Lpart,
    int niter) {
  __shared__ bf16 lK[2][16 * 512];  // frag ks: K[key=l&31][16ks+8hi+i]
  __shared__ bf16 lV[2][16 * 512];  // frag 2ct+ks2: V[ch=32ct+(l&31)][16ks2+8hi+i]

  int tid = threadIdx.x;
  int w = tid >> 6, l = tid & 63;
  int ql = l & 31, hi = l >> 5;
  int bid = blockIdx.x;
  int qb = bid % NQB2, s = bid / NQB2;
  int b = qb / 72;
  int n0 = (qb % 72) * 128;
  int kv0 = s * niter * 32;
  size_t qkbase = (size_t)b * NPIX * CH;
  size_t vbase  = (size_t)b * CH * NPIX;

  // Q fragments (B-operand 32x32x16): col = q-row = ql, k = 8hi+i per 16-ch step
  bf16x8 qf[16];
  {
    const bf16* qp = Q + qkbase + (size_t)(n0 + 32 * w + ql) * CH + 8 * hi;
#pragma unroll
    for (int ks = 0; ks < 16; ks++) qf[ks] = *(const bf16x8*)(qp + ks * 16);
  }

  floatx16 oacc[8];  // [ct]: O[q=(r&3)+8(r>>2)+4hi][ch=32ct+ql]
#pragma unroll
  for (int ct = 0; ct < 8; ct++)
#pragma unroll
    for (int r = 0; r < 16; r++) oacc[ct][r] = 0.f;
  float mrow = -1e30f, lrow = 0.f;

  const bf16* gK = K + qkbase + (size_t)kv0 * CH;
  const bf16* gV = Vt + vbase + kv0;

  // wave w stages K frags 4w..4w+3 and V frags 4w..4w+3 (8 async16/iter)
  auto stage = [&](int bi) {
#pragma unroll
    for (int ff = 0; ff < 4; ff++) {
      int f = 4 * w + ff;
      async16(&lK[bi][f * 512], gK + (size_t)ql * CH + f * 16 + 8 * hi);
      async16(&lV[bi][f * 512],
              gV + (size_t)((f >> 1) * 32 + ql) * NPIX + (f & 1) * 16 + 8 * hi);
    }
  };

  stage(0);

  for (int it = 0; it < niter; it++) {
    int cur = it & 1;
    __syncthreads();  // buffers `cur` ready (vmcnt drained); prev reads retired

    if (it + 1 < niter) {
      gK += 32 * CH; gV += 32;
      stage(cur ^ 1);
    }

    // S^T = K Q^T : D[key][q], two independent accumulator chains
    floatx16 sfA, sfB;
#pragma unroll
    for (int r = 0; r < 16; r++) { sfA[r] = 0.f; sfB[r] = 0.f; }
    __builtin_amdgcn_s_setprio(1);
#pragma unroll
    for (int ks = 0; ks < 16; ks += 2) {
      bf16x8 kf0 = *(const bf16x8*)&lK[cur][(ks + 0) * 512 + l * 8];
      bf16x8 kf1 = *(const bf16x8*)&lK[cur][(ks + 1) * 512 + l * 8];
      sfA = MFMA32(kf0, qf[ks + 0], sfA);
      sfB = MFMA32(kf1, qf[ks + 1], sfB);
    }
    __builtin_amdgcn_s_setprio(0);
    // combine + tile max for this lane's q-row (other 16 keys live in lane^32)
    float pm = -1e30f;
#pragma unroll
    for (int r = 0; r < 16; r++) {
      float sv = sfA[r] + sfB[r];
      sfA[r] = sv;
      pm = fmaxf(pm, sv);
    }
    pm = xmax32(pm);

    // defer-max: rescale only when row max grew by > 8
    bool need = pm > mrow + 8.f;
    if (__ballot((int)need) != 0ull) {
      float mn = fmaxf(mrow, pm);
      float alpha = __expf(mrow - mn);
      mrow = mn;
      lrow *= alpha;
      float arow[16];
#pragma unroll
      for (int r = 0; r < 16; r++)
        arow[r] = __shfl(alpha, (r & 3) + 8 * (r >> 2) + 4 * hi);
#pragma unroll
      for (int ct = 0; ct < 8; ct++)
#pragma unroll
        for (int r = 0; r < 16; r++) oacc[ct][r] *= arow[r];
    }

    // P = exp(S - m) (all 16 values belong to this lane's own q-row)
    float p[16];
    float rs = 0.f;
#pragma unroll
    for (int r = 0; r < 16; r++) {
      p[r] = __expf(sfA[r] - mrow);
      rs += p[r];
    }
    lrow += xsum32(rs);

    // pack to PV A-frags: reg r holds key (r&3)+8(r>>2)+4hi
    unsigned pk0 = cvtpk(p[0], p[1]),   pk1 = cvtpk(p[2], p[3]);
    unsigned pk2 = cvtpk(p[4], p[5]),   pk3 = cvtpk(p[6], p[7]);
    unsigned pk4 = cvtpk(p[8], p[9]),   pk5 = cvtpk(p[10], p[11]);
    unsigned pk6 = cvtpk(p[12], p[13]), pk7 = cvtpk(p[14], p[15]);
    plswap(pk0, pk2); plswap(pk1, pk3);
    plswap(pk4, pk6); plswap(pk5, pk7);
    uint4 u0, u1;
    u0.x = pk0; u0.y = pk1; u0.z = pk2; u0.w = pk3;  // keys 0..15, k = 8hi+i
    u1.x = pk4; u1.y = pk5; u1.z = pk6; u1.w = pk7;  // keys 16..31
    bf16x8 pa0 = __builtin_bit_cast(bf16x8, u0);
    bf16x8 pa1 = __builtin_bit_cast(bf16x8, u1);

    // PV: O[q][ch] += P[q][k] V[k][ch]
    __builtin_amdgcn_s_setprio(1);
#pragma unroll
    for (int ct = 0; ct < 8; ct++) {
      bf16x8 vb0 = *(const bf16x8*)&lV[cur][(2 * ct + 0) * 512 + l * 8];
      bf16x8 vb1 = *(const bf16x8*)&lV[cur][(2 * ct + 1) * 512 + l * 8];
      oacc[ct] = MFMA32(pa0, vb0, oacc[ct]);
      oacc[ct] = MFMA32(pa1, vb1, oacc[ct]);
    }
    __builtin_amdgcn_s_setprio(0);
  }

  // write partials (unnormalized O + m, l)
  if (hi == 0) {
    Mpart[(size_t)bid * 128 + 32 * w + ql] = mrow;
    Lpart[(size_t)bid * 128 + 32 * w + ql] = lrow;
  }
  float* Ob = Opart + (size_t)bid * 128 * CH;
#pragma unroll
  for (int ct = 0; ct < 8; ct++)
#pragma unroll
    for (int r = 0; r < 16; r++) {
      int row = 32 * w + (r & 3) + 8 * (r >> 2) + 4 * hi;
      Ob[(size_t)row * CH + 32 * ct + ql] = oacc[ct][r];
    }
}

// ---------------------------------------------------------------------------
// Combine S partials -> normalized O, split hi/lo bf16, n-major [MTOT][256]
// grid NQB2*4 = 576 blocks x 32-row quarters (proven v7 form).
// ---------------------------------------------------------------------------
__global__ __launch_bounds__(256) void attn_combine(
    const float* __restrict__ Opart, const float* __restrict__ Mpart,
    const float* __restrict__ Lpart,
    bf16* __restrict__ Oh, bf16* __restrict__ Ol, int S) {
  __shared__ float wgt[8][32];
  __shared__ float invl[32];
  int qb = blockIdx.x >> 2;
  int r0 = (blockIdx.x & 3) * 32;
  int t = threadIdx.x;
  if (t < 32) {
    int row = r0 + t;
    float m = -1e30f;
    for (int s = 0; s < S; s++)
      m = fmaxf(m, Mpart[(size_t)(s * NQB2 + qb) * 128 + row]);
    float lsum = 0.f;
    for (int s = 0; s < S; s++) {
      float wv = __expf(Mpart[(size_t)(s * NQB2 + qb) * 128 + row] - m);
      wgt[s][t] = wv;
      lsum += wv * Lpart[(size_t)(s * NQB2 + qb) * 128 + row];
    }
    invl[t] = 1.0f / lsum;
  }
  __syncthreads();
  int c = t;  // 256 threads = 256 channels
  for (int rr = 0; rr < 32; rr++) {
    int row = r0 + rr;
    float acc = 0.f;
    for (int s = 0; s < S; s++)
      acc += wgt[s][rr] * Opart[((size_t)(s * NQB2 + qb) * 128 + row) * CH + c];
    float y = acc * invl[rr];
    size_t idx = (size_t)(qb * 128 + row) * CH + c;
    bf16 h = (bf16)y;
    Oh[idx] = h;
    Ol[idx] = (bf16)(y - (float)h);
  }
}

// ---------------------------------------------------------------------------
extern "C" void kernel_launch(void* const* d_in, const int* in_sizes, int n_in,
                              void* d_out, int out_size, void* d_ws, size_t ws_size,
                              hipStream_t stream) {
  const float* x  = (const float*)d_in[0];
  const float* fk = (const float*)d_in[1];
  const float* Ws = (const float*)d_in[2];
  const float* g  = (const float*)d_in[3];
  const float* be = (const float*)d_in[4];
  const float* me = (const float*)d_in[5];
  const float* va = (const float*)d_in[6];
  float* out = (float*)d_out;

  char* p = (char*)d_ws;
  bf16* Wh = (bf16*)p; p += (size_t)6 * CH * CH * 2;
  bf16* Wl = (bf16*)p; p += (size_t)6 * CH * CH * 2;
  float* scale = (float*)p; p += (size_t)6 * CH * 4;
  float* bias  = (float*)p; p += (size_t)6 * CH * 4;
  size_t plane = (size_t)MTOT * CH * 2;  // 9,437,184 B per bf16 plane
  bf16* S0h = (bf16*)p; p += plane;      // attn_combine out (hi) -> conv64 A
  bf16* S0l = (bf16*)p; p += plane;      // attn_combine out (lo)
  bf16* Qh  = (bf16*)p; p += plane;
  bf16* Kh  = (bf16*)p; p += plane;
  bf16* Vt  = (bf16*)p; p += plane;   // c-major V, written directly by conv128 mode 3
  char* region = p;

  // Overlays inside `region` (all dead before attn_part writes Opart there):
  bf16* S2h = (bf16*)(region);              // fk transposed (hi)
  bf16* S2l = (bf16*)(region + plane);      // fk transposed (lo)
  bf16* P1h = (bf16*)(region + 2 * plane);  // psi1 out (hi)
  bf16* P1l = (bf16*)(region + 3 * plane);  // psi1 out (lo)
  bf16* F1h = (bf16*)(region + 4 * plane);  // phi1 out (hi)
  bf16* F1l = (bf16*)(region + 5 * plane);  // phi1 out (lo)

  size_t base_used = (size_t)(region - (char*)d_ws);
  size_t osz = (size_t)NQB2 * 128 * CH * 4;           // 18.9 MB per split
  size_t per_split = osz + 2 * (size_t)NQB2 * 128 * 4;
  long avail = (long)ws_size - (long)base_used;
  int S = 1;
  {
    // S=3 -> grid 432 fully co-resident at 2 blocks/CU; 288 % S == 0 required
    int cand[3] = {3, 2, 1};
    for (int i = 0; i < 3; i++)
      if ((long)cand[i] * (long)per_split <= avail) { S = cand[i]; break; }
  }
  float* Opart = (float*)region;
  float* Mpart = (float*)(region + (size_t)S * osz);
  float* Lpart = Mpart + (size_t)S * NQB2 * 128;

  (void)in_sizes; (void)n_in; (void)out_size;

  split_fk<<<1536, 256, 0, stream>>>(fk, S2h, S2l,
                                     Ws, g, be, me, va, Wh, Wl, scale, bias);

  auto W = [&](int layer) { return Wh + (size_t)layer * CH * CH; };
  auto Wlo = [&](int layer) { return Wl + (size_t)layer * CH * CH; };

  // psi1: mode 4 -- A operand is fp32 c-major x (transpose+split in-kernel)
  ConvJob psi1   {(const bf16*)x, nullptr, W(0), Wlo(0), scale + 0 * CH, bias + 0 * CH, P1h, P1l, nullptr, 4, 0};
  ConvJob phi1   {S2h, S2l, W(2), Wlo(2), scale + 2 * CH, bias + 2 * CH, F1h, F1l, nullptr, 0, 0};
  ConvJob fdownA {S2h, S2l, W(4), Wlo(4), scale + 4 * CH, bias + 4 * CH, Vt, nullptr, nullptr, 3, 0};
  ConvJob fdownB {S2h, S2l, W(4), Wlo(4), scale + 4 * CH, bias + 4 * CH, Vt, nullptr, nullptr, 3, 144};
  ConvJob psi2   {P1h, P1l, W(1), Wlo(1), scale + 1 * CH, bias + 1 * CH, Qh, nullptr, nullptr, 1, 0};
  ConvJob phi2   {F1h, F1l, W(3), Wlo(3), scale + 3 * CH, bias + 3 * CH, Kh, nullptr, nullptr, 1, 0};

  conv128<<<720, 256, 0, stream>>>(psi1, phi1, fdownA);
  conv128<<<720, 256, 0, stream>>>(psi2, phi2, fdownB);
  attn_part<<<NQB2 * S, 256, 0, stream>>>(Qh, Kh, Vt, Opart, Mpart, Lpart, 288 / S);
  attn_combine<<<NQB2 * 4, 256, 0, stream>>>(Opart, Mpart, Lpart, S0h, S0l, S);
  conv64<<<576, 256, 0, stream>>>(S0h, S0l, W(5), Wlo(5), scale + 5 * CH, bias + 5 * CH, out);
}

// Round 22
// 441.576 us; speedup vs baseline: 5.0659x; 1.0183x over previous
//
#include <hip/hip_runtime.h>
#include <hip/hip_bf16.h>

typedef __bf16 bf16;
typedef __bf16 bf16x8 __attribute__((ext_vector_type(8)));
typedef float floatx4 __attribute__((ext_vector_type(4)));
typedef float floatx16 __attribute__((ext_vector_type(16)));

#define MFMA_BF16(a, b, c) __builtin_amdgcn_mfma_f32_16x16x32_bf16((a), (b), (c), 0, 0, 0)
#define MFMA32(a, b, c) __builtin_amdgcn_mfma_f32_32x32x16_bf16((a), (b), (c), 0, 0, 0)

static constexpr int CH = 256;      // channels
static constexpr int NPIX = 9216;   // 96*96
static constexpr int MTOT = 2 * NPIX; // both batches, n-major rows
static constexpr int NQB2 = 144;    // 128-row attention q-blocks total (2 batches)

// async global->LDS, 16B per lane; LDS dest = wave-uniform base + lane*16
__device__ __forceinline__ void async16(void* lds, const void* g) {
  __builtin_amdgcn_global_load_lds(
      (const __attribute__((address_space(1))) void*)g,
      (__attribute__((address_space(3))) void*)lds, 16, 0, 0);
}

// pack two f32 -> one u32 of 2 bf16 (lo = first arg)
__device__ __forceinline__ unsigned cvtpk(float lo, float hi) {
  unsigned r;
  asm("v_cvt_pk_bf16_f32 %0, %1, %2" : "=v"(r) : "v"(lo), "v"(hi));
  return r;
}

// v_permlane32_swap_b32 a, b  (VALU, gfx950, correctness-verified in v5/v6 runs):
//   a'[0:31]=a[0:31], a'[32:63]=b[0:31]; b'[0:31]=a[32:63], b'[32:63]=b[32:63]
__device__ __forceinline__ void plswap(unsigned& a, unsigned& b) {
  asm volatile("v_permlane32_swap_b32 %0, %1" : "+v"(a), "+v"(b));
}
// max/sum with lane^32 partner via permlane (VALU ~4cy vs ds_bpermute ~120cy)
__device__ __forceinline__ float xmax32(float v) {
  unsigned a = __builtin_bit_cast(unsigned, v), b = a;
  plswap(a, b);
  return fmaxf(__builtin_bit_cast(float, a), __builtin_bit_cast(float, b));
}
__device__ __forceinline__ float xsum32(float v) {
  unsigned a = __builtin_bit_cast(unsigned, v), b = a;
  plswap(a, b);
  return __builtin_bit_cast(float, a) + __builtin_bit_cast(float, b);
}

// ---------------------------------------------------------------------------
// Weight split (fp32 -> bf16 hi/lo) + folded BN scale/bias (tiny, ~3us).
// fk/x are no longer pre-transposed: all conv consumers read fp32 c-major
// directly via conv128 mode bit 2 (in-kernel transpose+split, proven in v10).
// ---------------------------------------------------------------------------
__global__ void prep_weights(const float* __restrict__ W,
                             const float* __restrict__ g, const float* __restrict__ b,
                             const float* __restrict__ m, const float* __restrict__ v,
                             bf16* __restrict__ Wh, bf16* __restrict__ Wl,
                             float* __restrict__ scale, float* __restrict__ bias) {
  int i = blockIdx.x * 256 + threadIdx.x;
  if (i < 6 * CH * CH) {
    float w = W[i];
    bf16 h = (bf16)w;
    Wh[i] = h;
    Wl[i] = (bf16)(w - (float)h);
  }
  if (i < 6 * CH) {
    float s = g[i] * rsqrtf(v[i] + 1e-5f);
    scale[i] = s;
    bias[i] = b[i] - m[i] * s;
  }
}

// ---------------------------------------------------------------------------
// Batched split-bf16 conv-GEMM, 128x128 tiles.
// grid layout: job0 blocks [0,288), job1 [288,576), job2 [576,576+n2);
// j.bid0 offsets job2's local bid (fdown split 144/144 across launches).
// mode bitfield: bit2 (4) = A-operand is fp32 c-major (transpose+split
//   in-kernel; j.Ah carries the fp32 pointer, j.Al unused);
//   low 2 bits = output: 0 = hi+lo bf16 n-major, 1 = hi only n-major,
//   3 = bf16 TRANSPOSED to c-major [B][256][9216] (fused transpose).
// ---------------------------------------------------------------------------
struct ConvJob {
  const bf16 *Ah, *Al, *Bh, *Bl;
  const float *scale, *bias;
  bf16 *Yh, *Yl; float *Yf;
  int mode;
  int bid0;
};

__global__ __launch_bounds__(256, 3) void conv128(ConvJob j0, ConvJob j1, ConvJob j2) {
  __shared__ bf16 lds[4][8 * 512];  // planes: Ah, Al, Bh, Bl
  __shared__ float scr[32][132];    // mode-4 fp32 tile scratch (16.5 KB)
  int gbid = blockIdx.x;
  ConvJob j; int bid;
  if (gbid < 288)      { j = j0; bid = gbid; }
  else if (gbid < 576) { j = j1; bid = gbid - 288; }
  else                 { j = j2; bid = gbid - 576 + j2.bid0; }

  int tid = threadIdx.x;
  int w = tid >> 6, l = tid & 63;
  int q = l >> 4, c16 = l & 15;
  int m0 = (bid >> 1) * 128;
  int o0 = (bid & 1) * 128;

  const bf16* src = (w == 0) ? j.Ah : (w == 1) ? j.Al : (w == 2) ? j.Bh : j.Bl;
  int rowbase = (w < 2) ? m0 : o0;
  const bf16* gp = src + (size_t)(rowbase + c16) * CH + q * 8;
  bf16* ldst = &lds[w][0];

  const floatx4 zero4 = {0.f, 0.f, 0.f, 0.f};
  floatx4 acc[4][4];
#pragma unroll
  for (int i = 0; i < 4; i++)
#pragma unroll
    for (int jj = 0; jj < 4; jj++) acc[i][jj] = zero4;

  int mo16 = (w & 1) * 4, no16 = (w >> 1) * 4;
  bool m4 = (j.mode & 4) != 0;
  int omode = j.mode & 3;
  const float* xsrc = (const float*)j.Ah;
  int b2m = (m0 >= NPIX) ? 1 : 0;
  int nr0m = m0 - b2m * NPIX;

  for (int k0 = 0; k0 < CH; k0 += 32) {
    if (m4) {
      // B-planes via async16 (waves 2,3 as usual)
      if (w >= 2) {
#pragma unroll
        for (int f = 0; f < 8; f++)
          async16(ldst + f * 512, gp + (size_t)f * 16 * CH + k0);
      }
      // fp32 c-major tile: thread -> ch k0+(tid>>3), rows nr0m+(tid&7)*16..+15
      {
        const float* xp = xsrc + ((size_t)(b2m * CH + k0 + (tid >> 3))) * NPIX
                          + nr0m + (tid & 7) * 16;
        float4 v0 = ((const float4*)xp)[0];
        float4 v1 = ((const float4*)xp)[1];
        float4 v2 = ((const float4*)xp)[2];
        float4 v3 = ((const float4*)xp)[3];
        float* srow = &scr[tid >> 3][(tid & 7) * 16];
        *(float4*)(srow + 0) = v0;  *(float4*)(srow + 4) = v1;
        *(float4*)(srow + 8) = v2;  *(float4*)(srow + 12) = v3;
      }
      __syncthreads();
      // transpose + hi/lo split into A planes (exact async16 frag layout):
      // lds[0][f*512 + l*8 + jj] = hi(A[m0 + f*16 + (l&15)][k0 + (l>>4)*8 + jj])
#pragma unroll
      for (int half = 0; half < 2; half++) {
        int f = tid >> 5;                      // 0..7
        int l2 = (tid & 31) + half * 32;       // 0..63
        int qq = l2 >> 4, cc = l2 & 15;
        int row = f * 16 + cc;
        bf16 hb[8], lb[8];
#pragma unroll
        for (int jj2 = 0; jj2 < 8; jj2++) {
          float xv = scr[qq * 8 + jj2][row];
          bf16 h = (bf16)xv;
          hb[jj2] = h;
          lb[jj2] = (bf16)(xv - (float)h);
        }
        *(bf16x8*)&lds[0][f * 512 + l2 * 8] = *(bf16x8*)&hb[0];
        *(bf16x8*)&lds[1][f * 512 + l2 * 8] = *(bf16x8*)&lb[0];
      }
    } else {
#pragma unroll
      for (int f = 0; f < 8; f++)
        async16(ldst + f * 512, gp + (size_t)f * 16 * CH + k0);
    }
    __syncthreads();

    bf16x8 ah[4], al[4], bh[4], bl[4];
#pragma unroll
    for (int i = 0; i < 4; i++) {
      ah[i] = *(const bf16x8*)&lds[0][(mo16 + i) * 512 + l * 8];
      al[i] = *(const bf16x8*)&lds[1][(mo16 + i) * 512 + l * 8];
      bh[i] = *(const bf16x8*)&lds[2][(no16 + i) * 512 + l * 8];
      bl[i] = *(const bf16x8*)&lds[3][(no16 + i) * 512 + l * 8];
    }
#pragma unroll
    for (int i = 0; i < 4; i++)
#pragma unroll
      for (int jj = 0; jj < 4; jj++) {
        acc[i][jj] = MFMA_BF16(ah[i], bh[jj], acc[i][jj]);
        acc[i][jj] = MFMA_BF16(ah[i], bl[jj], acc[i][jj]);
        acc[i][jj] = MFMA_BF16(al[i], bh[jj], acc[i][jj]);
      }
    __syncthreads();
  }

  int mo = (w & 1) * 64, no = (w >> 1) * 64;
  float sc[4], bs[4];
#pragma unroll
  for (int jj = 0; jj < 4; jj++) {
    int o = o0 + no + 16 * jj + c16;
    sc[jj] = j.scale[o];
    bs[jj] = j.bias[o];
  }

  if (omode == 3) {
    // fused transpose: write Yh as c-major [b][ch][pixel]
    bf16* tile = &lds[0][0];  // [64][136] bf16, 8704 elems <= 16384
    int b2 = b2m;
    int nr0 = nr0m;
#pragma unroll
    for (int hc = 0; hc < 2; hc++) {
      __syncthreads();
      if ((w >> 1) == hc) {
#pragma unroll
        for (int i = 0; i < 4; i++)
#pragma unroll
          for (int jj = 0; jj < 4; jj++)
#pragma unroll
            for (int r = 0; r < 4; r++) {
              float y = acc[i][jj][r] * sc[jj] + bs[jj];
              y = fmaxf(y, 0.f);
              int chl = no + 16 * jj + c16 - hc * 64;  // 0..63
              int rowl = mo + 16 * i + 4 * q + r;      // 0..127
              tile[chl * 136 + rowl] = (bf16)y;
            }
      }
      __syncthreads();
      int chl = tid >> 2, rseg = (tid & 3) * 32;
      bf16* dst = j.Yh + ((size_t)(b2 * CH + o0 + hc * 64 + chl)) * NPIX + nr0 + rseg;
#pragma unroll
      for (int k = 0; k < 4; k++)
        *(bf16x8*)(dst + 8 * k) = *(bf16x8*)&tile[chl * 136 + rseg + 8 * k];
    }
    return;
  }

#pragma unroll
  for (int i = 0; i < 4; i++) {
    int nrow = m0 + mo + 16 * i + 4 * q;
#pragma unroll
    for (int jj = 0; jj < 4; jj++) {
      int o = o0 + no + 16 * jj + c16;
#pragma unroll
      for (int r = 0; r < 4; r++) {
        float y = acc[i][jj][r] * sc[jj] + bs[jj];
        y = fmaxf(y, 0.f);
        size_t idx = (size_t)(nrow + r) * CH + o;
        if (omode == 1) {
          j.Yh[idx] = (bf16)y;
        } else {
          bf16 h = (bf16)y;
          j.Yh[idx] = h;
          j.Yl[idx] = (bf16)(y - (float)h);
        }
      }
    }
  }
}

// ---------------------------------------------------------------------------
// 64x128-tile split-bf16 conv-GEMM, fp32 out (f_up), FUSED transposed write
// to final output [B][256][9216]. 2-pass 64ch x 64row fp32 LDS tile [64][68].
// ---------------------------------------------------------------------------
__global__ __launch_bounds__(256, 4) void conv64(
    const bf16* __restrict__ Ah, const bf16* __restrict__ Al,
    const bf16* __restrict__ Bh, const bf16* __restrict__ Bl,
    const float* __restrict__ scale, const float* __restrict__ bias,
    float* __restrict__ Yf) {
  __shared__ bf16 lds[24 * 512];  // flat frags: [Ah0-3, Al0-3, Bh0-7, Bl0-7]
  int tid = threadIdx.x;
  int w = tid >> 6, l = tid & 63;
  int q = l >> 4, c16 = l & 15;
  int m0 = (blockIdx.x >> 1) * 64;
  int o0 = (blockIdx.x & 1) * 128;

  const floatx4 zero4 = {0.f, 0.f, 0.f, 0.f};
  floatx4 acc[4][2];
#pragma unroll
  for (int i = 0; i < 4; i++) { acc[i][0] = zero4; acc[i][1] = zero4; }

  for (int k0 = 0; k0 < CH; k0 += 32) {
#pragma unroll
    for (int ff = 0; ff < 6; ff++) {
      int f = w * 6 + ff;
      const bf16* src; int rbase, fl;
      if (f < 4)       { src = Ah; rbase = m0; fl = f; }
      else if (f < 8)  { src = Al; rbase = m0; fl = f - 4; }
      else if (f < 16) { src = Bh; rbase = o0; fl = f - 8; }
      else             { src = Bl; rbase = o0; fl = f - 16; }
      async16(&lds[f * 512], src + (size_t)(rbase + fl * 16 + c16) * CH + k0 + q * 8);
    }
    __syncthreads();

    bf16x8 ah[4], al[4], bh[2], bl[2];
#pragma unroll
    for (int i = 0; i < 4; i++) {
      ah[i] = *(const bf16x8*)&lds[(0 + i) * 512 + l * 8];
      al[i] = *(const bf16x8*)&lds[(4 + i) * 512 + l * 8];
    }
#pragma unroll
    for (int n = 0; n < 2; n++) {
      bh[n] = *(const bf16x8*)&lds[(8 + 2 * w + n) * 512 + l * 8];
      bl[n] = *(const bf16x8*)&lds[(16 + 2 * w + n) * 512 + l * 8];
    }
#pragma unroll
    for (int i = 0; i < 4; i++)
#pragma unroll
      for (int n = 0; n < 2; n++) {
        acc[i][n] = MFMA_BF16(ah[i], bh[n], acc[i][n]);
        acc[i][n] = MFMA_BF16(ah[i], bl[n], acc[i][n]);
        acc[i][n] = MFMA_BF16(al[i], bh[n], acc[i][n]);
      }
    __syncthreads();
  }

  float sc[2], bs[2];
#pragma unroll
  for (int n = 0; n < 2; n++) {
    int o = o0 + 32 * w + 16 * n + c16;
    sc[n] = scale[o];
    bs[n] = bias[o];
  }

  float* tile = (float*)&lds[0];  // [64][68] fp32, 17408 B <= 24576
  int b2 = (m0 >= NPIX) ? 1 : 0;
  int nr0 = m0 - b2 * NPIX;
#pragma unroll
  for (int hc = 0; hc < 2; hc++) {
    __syncthreads();
    if ((w >> 1) == hc) {
#pragma unroll
      for (int i = 0; i < 4; i++)
#pragma unroll
        for (int n = 0; n < 2; n++)
#pragma unroll
          for (int r = 0; r < 4; r++) {
            float y = acc[i][n][r] * sc[n] + bs[n];
            y = fmaxf(y, 0.f);
            int chl = 32 * (w - 2 * hc) + 16 * n + c16;  // 0..63
            int rowl = 16 * i + 4 * q + r;               // 0..63
            tile[chl * 68 + rowl] = y;
          }
    }
    __syncthreads();
    int chl = tid >> 2, rseg = (tid & 3) * 16;
    float* dst = Yf + ((size_t)(b2 * CH + o0 + hc * 64 + chl)) * NPIX + nr0 + rseg;
#pragma unroll
    for (int k = 0; k < 4; k++)
      *(float4*)(dst + 4 * k) = *(float4*)&tile[chl * 68 + rseg + 4 * k];
  }
}

// ---------------------------------------------------------------------------
// Split-KV flash attention partial, v6 (proven 268us, UNCHANGED).
// BQ=128 (4 waves x 32 q-rows), BKV=32, 32x32x16 MFMAs, in-register P,
// permlane32_swap softmax reduces + P-pack, setprio around MFMA clusters.
// VGPR 128 arch + 128 acc; LDS 64 KB -> 2 blocks/CU; S=3, grid 432.
// ---------------------------------------------------------------------------
__global__ __launch_bounds__(256, 2) void attn_part(
    const bf16* __restrict__ Q, const bf16* __restrict__ K, const bf16* __restrict__ Vt,
    float* __restrict__ Opart, float* __restrict__ Mpart, float* __restrict__ Lpart,
    int niter) {
  __shared__ bf16 lK[2][16 * 512];  // frag ks: K[key=l&31][16ks+8hi+i]
  __shared__ bf16 lV[2][16 * 512];  // frag 2ct+ks2: V[ch=32ct+(l&31)][16ks2+8hi+i]

  int tid = threadIdx.x;
  int w = tid >> 6, l = tid & 63;
  int ql = l & 31, hi = l >> 5;
  int bid = blockIdx.x;
  int qb = bid % NQB2, s = bid / NQB2;
  int b = qb / 72;
  int n0 = (qb % 72) * 128;
  int kv0 = s * niter * 32;
  size_t qkbase = (size_t)b * NPIX * CH;
  size_t vbase  = (size_t)b * CH * NPIX;

  // Q fragments (B-operand 32x32x16): col = q-row = ql, k = 8hi+i per 16-ch step
  bf16x8 qf[16];
  {
    const bf16* qp = Q + qkbase + (size_t)(n0 + 32 * w + ql) * CH + 8 * hi;
#pragma unroll
    for (int ks = 0; ks < 16; ks++) qf[ks] = *(const bf16x8*)(qp + ks * 16);
  }

  floatx16 oacc[8];  // [ct]: O[q=(r&3)+8(r>>2)+4hi][ch=32ct+ql]
#pragma unroll
  for (int ct = 0; ct < 8; ct++)
#pragma unroll
    for (int r = 0; r < 16; r++) oacc[ct][r] = 0.f;
  float mrow = -1e30f, lrow = 0.f;

  const bf16* gK = K + qkbase + (size_t)kv0 * CH;
  const bf16* gV = Vt + vbase + kv0;

  // wave w stages K frags 4w..4w+3 and V frags 4w..4w+3 (8 async16/iter)
  auto stage = [&](int bi) {
#pragma unroll
    for (int ff = 0; ff < 4; ff++) {
      int f = 4 * w + ff;
      async16(&lK[bi][f * 512], gK + (size_t)ql * CH + f * 16 + 8 * hi);
      async16(&lV[bi][f * 512],
              gV + (size_t)((f >> 1) * 32 + ql) * NPIX + (f & 1) * 16 + 8 * hi);
    }
  };

  stage(0);

  for (int it = 0; it < niter; it++) {
    int cur = it & 1;
    __syncthreads();  // buffers `cur` ready (vmcnt drained); prev reads retired

    if (it + 1 < niter) {
      gK += 32 * CH; gV += 32;
      stage(cur ^ 1);
    }

    // S^T = K Q^T : D[key][q], two independent accumulator chains
    floatx16 sfA, sfB;
#pragma unroll
    for (int r = 0; r < 16; r++) { sfA[r] = 0.f; sfB[r] = 0.f; }
    __builtin_amdgcn_s_setprio(1);
#pragma unroll
    for (int ks = 0; ks < 16; ks += 2) {
      bf16x8 kf0 = *(const bf16x8*)&lK[cur][(ks + 0) * 512 + l * 8];
      bf16x8 kf1 = *(const bf16x8*)&lK[cur][(ks + 1) * 512 + l * 8];
      sfA = MFMA32(kf0, qf[ks + 0], sfA);
      sfB = MFMA32(kf1, qf[ks + 1], sfB);
    }
    __builtin_amdgcn_s_setprio(0);
    // combine + tile max for this lane's q-row (other 16 keys live in lane^32)
    float pm = -1e30f;
#pragma unroll
    for (int r = 0; r < 16; r++) {
      float sv = sfA[r] + sfB[r];
      sfA[r] = sv;
      pm = fmaxf(pm, sv);
    }
    pm = xmax32(pm);

    // defer-max: rescale only when row max grew by > 8
    bool need = pm > mrow + 8.f;
    if (__ballot((int)need) != 0ull) {
      float mn = fmaxf(mrow, pm);
      float alpha = __expf(mrow - mn);
      mrow = mn;
      lrow *= alpha;
      float arow[16];
#pragma unroll
      for (int r = 0; r < 16; r++)
        arow[r] = __shfl(alpha, (r & 3) + 8 * (r >> 2) + 4 * hi);
#pragma unroll
      for (int ct = 0; ct < 8; ct++)
#pragma unroll
        for (int r = 0; r < 16; r++) oacc[ct][r] *= arow[r];
    }

    // P = exp(S - m) (all 16 values belong to this lane's own q-row)
    float p[16];
    float rs = 0.f;
#pragma unroll
    for (int r = 0; r < 16; r++) {
      p[r] = __expf(sfA[r] - mrow);
      rs += p[r];
    }
    lrow += xsum32(rs);

    // pack to PV A-frags: reg r holds key (r&3)+8(r>>2)+4hi
    unsigned pk0 = cvtpk(p[0], p[1]),   pk1 = cvtpk(p[2], p[3]);
    unsigned pk2 = cvtpk(p[4], p[5]),   pk3 = cvtpk(p[6], p[7]);
    unsigned pk4 = cvtpk(p[8], p[9]),   pk5 = cvtpk(p[10], p[11]);
    unsigned pk6 = cvtpk(p[12], p[13]), pk7 = cvtpk(p[14], p[15]);
    plswap(pk0, pk2); plswap(pk1, pk3);
    plswap(pk4, pk6); plswap(pk5, pk7);
    uint4 u0, u1;
    u0.x = pk0; u0.y = pk1; u0.z = pk2; u0.w = pk3;  // keys 0..15, k = 8hi+i
    u1.x = pk4; u1.y = pk5; u1.z = pk6; u1.w = pk7;  // keys 16..31
    bf16x8 pa0 = __builtin_bit_cast(bf16x8, u0);
    bf16x8 pa1 = __builtin_bit_cast(bf16x8, u1);

    // PV: O[q][ch] += P[q][k] V[k][ch]
    __builtin_amdgcn_s_setprio(1);
#pragma unroll
    for (int ct = 0; ct < 8; ct++) {
      bf16x8 vb0 = *(const bf16x8*)&lV[cur][(2 * ct + 0) * 512 + l * 8];
      bf16x8 vb1 = *(const bf16x8*)&lV[cur][(2 * ct + 1) * 512 + l * 8];
      oacc[ct] = MFMA32(pa0, vb0, oacc[ct]);
      oacc[ct] = MFMA32(pa1, vb1, oacc[ct]);
    }
    __builtin_amdgcn_s_setprio(0);
  }

  // write partials (unnormalized O + m, l)
  if (hi == 0) {
    Mpart[(size_t)bid * 128 + 32 * w + ql] = mrow;
    Lpart[(size_t)bid * 128 + 32 * w + ql] = lrow;
  }
  float* Ob = Opart + (size_t)bid * 128 * CH;
#pragma unroll
  for (int ct = 0; ct < 8; ct++)
#pragma unroll
    for (int r = 0; r < 16; r++) {
      int row = 32 * w + (r & 3) + 8 * (r >> 2) + 4 * hi;
      Ob[(size_t)row * CH + 32 * ct + ql] = oacc[ct][r];
    }
}

// ---------------------------------------------------------------------------
// Combine S partials -> normalized O, split hi/lo bf16, n-major [MTOT][256]
// grid NQB2*4 = 576 blocks x 32-row quarters (proven v7 form).
// ---------------------------------------------------------------------------
__global__ __launch_bounds__(256) void attn_combine(
    const float* __restrict__ Opart, const float* __restrict__ Mpart,
    const float* __restrict__ Lpart,
    bf16* __restrict__ Oh, bf16* __restrict__ Ol, int S) {
  __shared__ float wgt[8][32];
  __shared__ float invl[32];
  int qb = blockIdx.x >> 2;
  int r0 = (blockIdx.x & 3) * 32;
  int t = threadIdx.x;
  if (t < 32) {
    int row = r0 + t;
    float m = -1e30f;
    for (int s = 0; s < S; s++)
      m = fmaxf(m, Mpart[(size_t)(s * NQB2 + qb) * 128 + row]);
    float lsum = 0.f;
    for (int s = 0; s < S; s++) {
      float wv = __expf(Mpart[(size_t)(s * NQB2 + qb) * 128 + row] - m);
      wgt[s][t] = wv;
      lsum += wv * Lpart[(size_t)(s * NQB2 + qb) * 128 + row];
    }
    invl[t] = 1.0f / lsum;
  }
  __syncthreads();
  int c = t;  // 256 threads = 256 channels
  for (int rr = 0; rr < 32; rr++) {
    int row = r0 + rr;
    float acc = 0.f;
    for (int s = 0; s < S; s++)
      acc += wgt[s][rr] * Opart[((size_t)(s * NQB2 + qb) * 128 + row) * CH + c];
    float y = acc * invl[rr];
    size_t idx = (size_t)(qb * 128 + row) * CH + c;
    bf16 h = (bf16)y;
    Oh[idx] = h;
    Ol[idx] = (bf16)(y - (float)h);
  }
}

// ---------------------------------------------------------------------------
extern "C" void kernel_launch(void* const* d_in, const int* in_sizes, int n_in,
                              void* d_out, int out_size, void* d_ws, size_t ws_size,
                              hipStream_t stream) {
  const float* x  = (const float*)d_in[0];
  const float* fk = (const float*)d_in[1];
  const float* Ws = (const float*)d_in[2];
  const float* g  = (const float*)d_in[3];
  const float* be = (const float*)d_in[4];
  const float* me = (const float*)d_in[5];
  const float* va = (const float*)d_in[6];
  float* out = (float*)d_out;

  char* p = (char*)d_ws;
  bf16* Wh = (bf16*)p; p += (size_t)6 * CH * CH * 2;
  bf16* Wl = (bf16*)p; p += (size_t)6 * CH * CH * 2;
  float* scale = (float*)p; p += (size_t)6 * CH * 4;
  float* bias  = (float*)p; p += (size_t)6 * CH * 4;
  size_t plane = (size_t)MTOT * CH * 2;  // 9,437,184 B per bf16 plane
  bf16* S0h = (bf16*)p; p += plane;      // attn_combine out (hi) -> conv64 A
  bf16* S0l = (bf16*)p; p += plane;      // attn_combine out (lo)
  bf16* Qh  = (bf16*)p; p += plane;
  bf16* Kh  = (bf16*)p; p += plane;
  bf16* Vt  = (bf16*)p; p += plane;   // c-major V, written directly by conv128 omode 3
  char* region = p;

  // Overlays inside `region` (all dead before attn_part writes Opart there):
  bf16* P1h = (bf16*)(region);              // psi1 out (hi)
  bf16* P1l = (bf16*)(region + plane);      // psi1 out (lo)
  bf16* F1h = (bf16*)(region + 2 * plane);  // phi1 out (hi)
  bf16* F1l = (bf16*)(region + 3 * plane);  // phi1 out (lo)

  size_t base_used = (size_t)(region - (char*)d_ws);
  size_t osz = (size_t)NQB2 * 128 * CH * 4;           // 18.9 MB per split
  size_t per_split = osz + 2 * (size_t)NQB2 * 128 * 4;
  long avail = (long)ws_size - (long)base_used;
  int S = 1;
  {
    // S=3 -> grid 432 fully co-resident at 2 blocks/CU; 288 % S == 0 required
    int cand[3] = {3, 2, 1};
    for (int i = 0; i < 3; i++)
      if ((long)cand[i] * (long)per_split <= avail) { S = cand[i]; break; }
  }
  float* Opart = (float*)region;
  float* Mpart = (float*)(region + (size_t)S * osz);
  float* Lpart = Mpart + (size_t)S * NQB2 * 128;

  (void)in_sizes; (void)n_in; (void)out_size;

  prep_weights<<<1536, 256, 0, stream>>>(Ws, g, be, me, va, Wh, Wl, scale, bias);

  auto W = [&](int layer) { return Wh + (size_t)layer * CH * CH; };
  auto Wlo = [&](int layer) { return Wl + (size_t)layer * CH * CH; };

  // mode bit2 = fp32 c-major A input (in-kernel transpose+split):
  //   psi1 reads x, phi1/fdown read fk -- the split_fk kernel is gone.
  ConvJob psi1   {(const bf16*)x,  nullptr, W(0), Wlo(0), scale + 0 * CH, bias + 0 * CH, P1h, P1l, nullptr, 4, 0};
  ConvJob phi1   {(const bf16*)fk, nullptr, W(2), Wlo(2), scale + 2 * CH, bias + 2 * CH, F1h, F1l, nullptr, 4, 0};
  ConvJob fdownA {(const bf16*)fk, nullptr, W(4), Wlo(4), scale + 4 * CH, bias + 4 * CH, Vt, nullptr, nullptr, 7, 0};
  ConvJob fdownB {(const bf16*)fk, nullptr, W(4), Wlo(4), scale + 4 * CH, bias + 4 * CH, Vt, nullptr, nullptr, 7, 144};
  ConvJob psi2   {P1h, P1l, W(1), Wlo(1), scale + 1 * CH, bias + 1 * CH, Qh, nullptr, nullptr, 1, 0};
  ConvJob phi2   {F1h, F1l, W(3), Wlo(3), scale + 3 * CH, bias + 3 * CH, Kh, nullptr, nullptr, 1, 0};

  conv128<<<720, 256, 0, stream>>>(psi1, phi1, fdownA);
  conv128<<<720, 256, 0, stream>>>(psi2, phi2, fdownB);
  attn_part<<<NQB2 * S, 256, 0, stream>>>(Qh, Kh, Vt, Opart, Mpart, Lpart, 288 / S);
  attn_combine<<<NQB2 * 4, 256, 0, stream>>>(Opart, Mpart, Lpart, S0h, S0l, S);
  conv64<<<576, 256, 0, stream>>>(S0h, S0l, W(5), Wlo(5), scale + 5 * CH, bias + 5 * CH, out);
}